// Round 17
// baseline (290.106 us; speedup 1.0000x reference)
//
#include <hip/hip_runtime.h>
#include <hip/hip_bf16.h>

typedef __hip_bfloat16 bf16;
typedef __attribute__((ext_vector_type(8))) short short8;
typedef __attribute__((ext_vector_type(4))) short bfv4;
typedef __attribute__((ext_vector_type(4))) float f32x4;
typedef __attribute__((ext_vector_type(4))) unsigned short us4;

#define LN_EPS 1e-5f

__device__ __forceinline__ float siluf(float x) { return x / (1.f + __expf(-x)); }
__device__ __forceinline__ unsigned short f2bf_bits(float f) {
    bf16 h = __float2bfloat16(f);
    return *reinterpret_cast<unsigned short*>(&h);
}
__device__ __forceinline__ bf16 f2bf(float f) { return __float2bfloat16(f); }
__device__ __forceinline__ float bf2f(bf16 h) { return __bfloat162float(h); }

// async global->LDS, 16B per lane. LDS dest must be wave-uniform base (+lane*16 implicit).
__device__ __forceinline__ void load_lds16(const void* g, void* l) {
    __builtin_amdgcn_global_load_lds((const __attribute__((address_space(1))) void*)g,
                                     (__attribute__((address_space(3))) void*)l, 16, 0, 0);
}

__device__ __forceinline__ f32x4 mfma16(bfv4 a, bfv4 b, f32x4 c) {
    return __builtin_amdgcn_mfma_f32_16x16x16bf16_1k(a, b, c, 0, 0, 0);
}

// explicit RAW drain for global_load_lds before a barrier (rule-#18 class hazard)
__device__ __forceinline__ void drain_and_sync() {
    asm volatile("s_waitcnt vmcnt(0)" ::: "memory");
    __builtin_amdgcn_sched_barrier(0);
    __syncthreads();
}

// counted vmcnt wait (literal), fenced
template <int N>
__device__ __forceinline__ void wait_vmcnt() {
    asm volatile("s_waitcnt vmcnt(%0)" :: "n"(N) : "memory");
}
__device__ __forceinline__ void hard_barrier() {
    __builtin_amdgcn_sched_barrier(0);
    __builtin_amdgcn_s_barrier();
    __builtin_amdgcn_sched_barrier(0);
}
// barrier preceded by lgkmcnt(0): all this wave's ds_reads complete before crossing (WAR safety)
__device__ __forceinline__ void lgkm_barrier() {
    asm volatile("s_waitcnt lgkmcnt(0)" ::: "memory");
    __builtin_amdgcn_sched_barrier(0);
    __builtin_amdgcn_s_barrier();
    __builtin_amdgcn_sched_barrier(0);
}

// fine-phase sync: rendezvous, then wait own ds_reads, then high-prio MFMA
__device__ __forceinline__ void phase_pre() {
    __builtin_amdgcn_sched_barrier(0);
    __builtin_amdgcn_s_barrier();
    asm volatile("s_waitcnt lgkmcnt(0)" ::: "memory");
    __builtin_amdgcn_sched_barrier(0);
    __builtin_amdgcn_s_setprio(1);
}
__device__ __forceinline__ void phase_post() {
    __builtin_amdgcn_s_setprio(0);
    __builtin_amdgcn_sched_barrier(0);
    __builtin_amdgcn_s_barrier();
    __builtin_amdgcn_sched_barrier(0);
}

// XCD-chunked bijective block swizzle (requires nwg % 8 == 0)
__device__ __forceinline__ int xcd_swz(int bid, int nwg) {
    return (bid & 7) * (nwg >> 3) + (bid >> 3);
}

// ---------------- weight transpose+cast: fp32 [K][N] -> bf16 [N][K] ----------------
__global__ __launch_bounds__(256) void transpose_cast(
    const float* __restrict__ src, bf16* __restrict__ dst, int K, int N)
{
    __shared__ float t[32][33];
    const int nb = blockIdx.x << 5, kb = blockIdx.y << 5;
    const int tx = threadIdx.x, ty = threadIdx.y;
#pragma unroll
    for (int i = ty; i < 32; i += 8) t[i][tx] = src[(size_t)(kb + i) * N + nb + tx];
    __syncthreads();
#pragma unroll
    for (int i = ty; i < 32; i += 8) dst[(size_t)(nb + i) * K + kb + tx] = f2bf(t[tx][i]);
}

// three 1024x4096 weight transposes in one launch (z selects tensor)
__global__ __launch_bounds__(256) void transpose_cast3(
    const float* __restrict__ s0, const float* __restrict__ s1, const float* __restrict__ s2,
    bf16* __restrict__ d0, bf16* __restrict__ d1, bf16* __restrict__ d2)
{
    const float* src = (blockIdx.z == 0) ? s0 : (blockIdx.z == 1) ? s1 : s2;
    bf16* dst = (blockIdx.z == 0) ? d0 : (blockIdx.z == 1) ? d1 : d2;
    const int K = 1024, N = 4096;
    __shared__ float t[32][33];
    const int nb = blockIdx.x << 5, kb = blockIdx.y << 5;
    const int tx = threadIdx.x, ty = threadIdx.y;
#pragma unroll
    for (int i = ty; i < 32; i += 8) t[i][tx] = src[(size_t)(kb + i) * N + nb + tx];
    __syncthreads();
#pragma unroll
    for (int i = ty; i < 32; i += 8) dst[(size_t)(nb + i) * K + kb + tx] = f2bf(t[tx][i]);
}

// ---------------- LayerNorm fp32 row (D=1024) -> bf16 ----------------
__global__ __launch_bounds__(256) void ln_cast(
    const float* __restrict__ x, const float* __restrict__ g, const float* __restrict__ be,
    bf16* __restrict__ out)
{
    const int row = blockIdx.x, tid = threadIdx.x;
    const float4 v = ((const float4*)(x + (size_t)row * 1024))[tid];
    float s = v.x + v.y + v.z + v.w;
    float ss = v.x * v.x + v.y * v.y + v.z * v.z + v.w * v.w;
#pragma unroll
    for (int o = 32; o; o >>= 1) { s += __shfl_down(s, o); ss += __shfl_down(ss, o); }
    __shared__ float red[10];
    const int wid = tid >> 6, lane = tid & 63;
    if (lane == 0) { red[wid] = s; red[4 + wid] = ss; }
    __syncthreads();
    if (tid == 0) {
        float S = red[0] + red[1] + red[2] + red[3];
        float SS = red[4] + red[5] + red[6] + red[7];
        float mu = S * (1.f / 1024.f);
        red[8] = mu;
        red[9] = rsqrtf(SS * (1.f / 1024.f) - mu * mu + LN_EPS);
    }
    __syncthreads();
    const float mu = red[8], rstd = red[9];
    const float4 gg = ((const float4*)g)[tid];
    const float4 bb = ((const float4*)be)[tid];
    us4 o;
    o[0] = f2bf_bits((v.x - mu) * rstd * gg.x + bb.x);
    o[1] = f2bf_bits((v.y - mu) * rstd * gg.y + bb.y);
    o[2] = f2bf_bits((v.z - mu) * rstd * gg.z + bb.z);
    o[3] = f2bf_bits((v.w - mu) * rstd * gg.w + bb.w);
    ((us4*)(out + (size_t)row * 1024))[tid] = o;
}

// ---------------- qkuv GEMM: tile 128x256, BK=32, 8 waves (2M x 4N), LDS 48 KB ----------------
// Wave = 64x64 (acc 64 VGPR) -> combined regs ~116 -> 2 blocks/CU (4 waves/SIMD):
// cross-block overlap hides barrier rendezvous + boundary drain.
// 2 phases/K-tile, in-phase distance-1 staging, boundary vmcnt(0).
// Chunk-XOR swizzle for 4-chunk rows: phys = logical ^ (row & 3).
__global__ __launch_bounds__(512) void gemm8(
    const bf16* __restrict__ A, const bf16* __restrict__ BT,
    bf16* __restrict__ outp, int M, int N, int K)
{
    __shared__ __align__(16) bf16 lA[2][128 * 32];
    __shared__ __align__(16) bf16 lB[2][256 * 32];
    const int tid = threadIdx.x;
    const int wid = tid >> 6, lane = tid & 63;
    const int lhi = lane >> 4, llo = lane & 15;
    const int nby = M >> 7;
    const int bid = xcd_swz((int)blockIdx.x, (int)gridDim.x);
    const int by = bid % nby, bx = bid / nby;            // column-major
    const int row0 = by << 7, col0 = bx << 8;
    const int wr = wid >> 2, wc = wid & 3;               // 2M x 4N
    const int wbase = wid << 6;

    auto stage_rows = [&](const bf16* src, int r0, int k0, char* ldsbase, int nit) {
        for (int it = 0; it < nit; ++it) {
            const int p = it * 512 + wbase + lane;
            const int r = p >> 2, pc = p & 3;
            const int lc = pc ^ (r & 3);
            load_lds16(src + (size_t)(r0 + r) * K + k0 + lc * 8,
                       ldsbase + (size_t)(it * 512 + wbase) * 16);
        }
    };
    auto stageA = [&](int t) { stage_rows(A, row0, t << 5, (char*)lA[t & 1], 1); };
    auto stageB = [&](int t) { stage_rows(BT, col0, t << 5, (char*)lB[t & 1], 2); };

    f32x4 acc[4][4] = {};

    stageA(0); stageB(0);
    wait_vmcnt<0>();
    hard_barrier();

    const int KT = K >> 5;
    for (int t = 0; t < KT; ++t) {
        const bool more = (t + 1 < KT);
        const char* lAc = (const char*)lA[t & 1];
        const char* lBc = (const char*)lB[t & 1];

        short8 af[4], b0[2], b1[2];
        auto ldA4 = [&]() {
#pragma unroll
            for (int m = 0; m < 4; ++m) {
                const int ra = wr * 64 + m * 16 + llo;
                af[m] = *(const short8*)(lAc + ra * 64 + ((lhi ^ (ra & 3)) << 4));
            }
        };
        auto ldB2 = [&](short8 bf_[2], int nh) {
#pragma unroll
            for (int n = 0; n < 2; ++n) {
                const int rb = wc * 64 + nh * 32 + n * 16 + llo;
                bf_[n] = *(const short8*)(lBc + rb * 64 + ((lhi ^ (rb & 3)) << 4));
            }
        };

        // P1: n-half 0; stage T_{t+1}
        ldA4(); ldB2(b0, 0);
        if (more) { stageA(t + 1); stageB(t + 1); }
        phase_pre();
#pragma unroll
        for (int m = 0; m < 4; ++m)
#pragma unroll
            for (int n = 0; n < 2; ++n)
                acc[m][n] = __builtin_amdgcn_mfma_f32_16x16x32_bf16(af[m], b0[n], acc[m][n], 0, 0, 0);
        phase_post();
        // P2: n-half 1
        ldB2(b1, 1);
        phase_pre();
#pragma unroll
        for (int m = 0; m < 4; ++m)
#pragma unroll
            for (int n = 0; n < 2; ++n)
                acc[m][2 + n] = __builtin_amdgcn_mfma_f32_16x16x32_bf16(af[m], b1[n], acc[m][2 + n], 0, 0, 0);
        phase_post();

        if (more) { wait_vmcnt<0>(); hard_barrier(); }
    }

    // epilogue: bf16 silu
#pragma unroll
    for (int m = 0; m < 4; ++m) {
        const int rbase = row0 + wr * 64 + m * 16 + lhi * 4;
#pragma unroll
        for (int n = 0; n < 4; ++n) {
            const int c = col0 + wc * 64 + n * 16 + llo;
#pragma unroll
            for (int r = 0; r < 4; ++r) {
                const size_t idx = (size_t)(rbase + r) * N + c;
                outp[idx] = f2bf(siluf(acc[m][n][r]));
            }
        }
    }
}

// ---------------- fused FFN: h1 = silu(A@W1) * (A@W3), tile 128x128, BK=32, LDS 48 KB ----------------
// Wave = 64x32 dual-acc (acc 64 VGPR) -> 2 blocks/CU. Same schedule as gemm8.
__global__ __launch_bounds__(512) void gemm_w13_8(
    const bf16* __restrict__ A, const bf16* __restrict__ B1T, const bf16* __restrict__ B3T,
    bf16* __restrict__ outp, int M, int N, int K)
{
    __shared__ __align__(16) bf16 lA[2][128 * 32];
    __shared__ __align__(16) bf16 lB1[2][128 * 32];
    __shared__ __align__(16) bf16 lB3[2][128 * 32];
    const int tid = threadIdx.x;
    const int wid = tid >> 6, lane = tid & 63;
    const int lhi = lane >> 4, llo = lane & 15;
    const int nby = M >> 7;
    const int bid = xcd_swz((int)blockIdx.x, (int)gridDim.x);
    const int by = bid % nby, bx = bid / nby;            // column-major
    const int row0 = by << 7, col0 = bx << 7;
    const int wr = wid >> 2, wc = wid & 3;               // 2M x 4N
    const int wbase = wid << 6;

    auto stage_rows = [&](const bf16* src, int r0, int k0, char* ldsbase) {
        const int p = wbase + lane;
        const int r = p >> 2, pc = p & 3;
        const int lc = pc ^ (r & 3);
        load_lds16(src + (size_t)(r0 + r) * K + k0 + lc * 8,
                   ldsbase + (size_t)(wbase) * 16);
    };
    auto stageT = [&](int t) {
        const int k0 = t << 5, buf = t & 1;
        stage_rows(A, row0, k0, (char*)lA[buf]);
        stage_rows(B1T, col0, k0, (char*)lB1[buf]);
        stage_rows(B3T, col0, k0, (char*)lB3[buf]);
    };

    f32x4 acc1[4][2] = {}, acc3[4][2] = {};

    stageT(0);
    wait_vmcnt<0>();
    hard_barrier();

    const int KT = K >> 5;
    for (int t = 0; t < KT; ++t) {
        const bool more = (t + 1 < KT);
        const char* lAc = (const char*)lA[t & 1];
        const char* lB1c = (const char*)lB1[t & 1];
        const char* lB3c = (const char*)lB3[t & 1];

        short8 af[4], b1f[2], b3f[2];
#pragma unroll
        for (int m = 0; m < 4; ++m) {
            const int ra = wr * 64 + m * 16 + llo;
            af[m] = *(const short8*)(lAc + ra * 64 + ((lhi ^ (ra & 3)) << 4));
        }
#pragma unroll
        for (int n = 0; n < 2; ++n) {
            const int rb = wc * 32 + n * 16 + llo;
            const int so = ((lhi ^ (rb & 3)) << 4);
            b1f[n] = *(const short8*)(lB1c + rb * 64 + so);
            b3f[n] = *(const short8*)(lB3c + rb * 64 + so);
        }
        if (more) stageT(t + 1);

        // P1: m-half 0 (both accs)
        phase_pre();
#pragma unroll
        for (int m = 0; m < 2; ++m)
#pragma unroll
            for (int n = 0; n < 2; ++n) {
                acc1[m][n] = __builtin_amdgcn_mfma_f32_16x16x32_bf16(af[m], b1f[n], acc1[m][n], 0, 0, 0);
                acc3[m][n] = __builtin_amdgcn_mfma_f32_16x16x32_bf16(af[m], b3f[n], acc3[m][n], 0, 0, 0);
            }
        phase_post();
        // P2: m-half 1
        phase_pre();
#pragma unroll
        for (int m = 2; m < 4; ++m)
#pragma unroll
            for (int n = 0; n < 2; ++n) {
                acc1[m][n] = __builtin_amdgcn_mfma_f32_16x16x32_bf16(af[m], b1f[n], acc1[m][n], 0, 0, 0);
                acc3[m][n] = __builtin_amdgcn_mfma_f32_16x16x32_bf16(af[m], b3f[n], acc3[m][n], 0, 0, 0);
            }
        phase_post();

        if (more) { wait_vmcnt<0>(); hard_barrier(); }
    }

    // epilogue: silu(c1) * c3, wave-local
#pragma unroll
    for (int m = 0; m < 4; ++m) {
        const int rbase = row0 + wr * 64 + m * 16 + lhi * 4;
#pragma unroll
        for (int n = 0; n < 2; ++n) {
            const int c = col0 + wc * 32 + n * 16 + llo;
#pragma unroll
            for (int r = 0; r < 4; ++r) {
                const size_t idx = (size_t)(rbase + r) * N + c;
                outp[idx] = f2bf(siluf(acc1[m][n][r]) * acc3[m][n][r]);
            }
        }
    }
}

// ---------------- 128x64 bf16 GEMM, counted-vmcnt double-buffer (N=1024 GEMMs) ----------------
// ROW-major block order: A-slab L2-resident; right for K-large/N-small shapes (w2).
__global__ __launch_bounds__(256) void gemm_btc(
    const bf16* __restrict__ A, const bf16* __restrict__ BT,
    float* __restrict__ outp, const float* __restrict__ resid,
    int M, int N, int K)
{
    __shared__ __align__(16) bf16 lA[2][128 * 64];
    __shared__ __align__(16) bf16 lB[2][64 * 64];
    const int tid = threadIdx.x;
    const int wid = tid >> 6, lane = tid & 63;
    const int lhi = lane >> 4, llo = lane & 15;
    const int ntx = N >> 6;
    const int bid = xcd_swz((int)blockIdx.x, (int)gridDim.x);
    const int bx = bid % ntx, by = bid / ntx;            // row-major
    const int row0 = by << 7, col0 = bx << 6;
    const int wr = wid >> 1, wc = wid & 1;               // 2M x 2N
    const int wbase = wid << 6;

    auto stage_tile = [&](const bf16* src, int r0, int k0, char* ldsbase, int nit) {
        for (int it = 0; it < nit; ++it) {
            const int p = it * 256 + wbase + lane;
            const int r = p >> 3, pc = p & 7;
            const int lc = pc ^ (r & 7);
            load_lds16(src + (size_t)(r0 + r) * K + k0 + lc * 8,
                       ldsbase + (size_t)(it * 256 + wbase) * 16);
        }
    };
    auto stageT = [&](int t) {
        stage_tile(A, row0, t << 6, (char*)lA[t & 1], 4);
        stage_tile(BT, col0, t << 6, (char*)lB[t & 1], 2);
    };

    f32x4 acc[4][2] = {};

    stageT(0); stageT(1);
    wait_vmcnt<6>();
    hard_barrier();

    const int KT = K >> 6;
    for (int t = 0; t < KT; ++t) {
        const int buf = t & 1;
        const char* lAc = (const char*)lA[buf];
        const char* lBc = (const char*)lB[buf];

        short8 af[4], bfr[2];
        auto ldA = [&](int kk) {
#pragma unroll
            for (int m = 0; m < 4; ++m) {
                const int ra = wr * 64 + m * 16 + llo;
                af[m] = *(const short8*)(lAc + ra * 128 + (((kk * 4 + lhi) ^ (ra & 7)) << 4));
            }
        };
        auto ldB = [&](int kk) {
#pragma unroll
            for (int n = 0; n < 2; ++n) {
                const int rb = wc * 32 + n * 16 + llo;
                bfr[n] = *(const short8*)(lBc + rb * 128 + (((kk * 4 + lhi) ^ (rb & 7)) << 4));
            }
        };

#pragma unroll
        for (int kk = 0; kk < 2; ++kk) {
            ldA(kk); ldB(kk);
            __builtin_amdgcn_s_setprio(1);
#pragma unroll
            for (int m = 0; m < 4; ++m)
#pragma unroll
                for (int n = 0; n < 2; ++n)
                    acc[m][n] = __builtin_amdgcn_mfma_f32_16x16x32_bf16(af[m], bfr[n], acc[m][n], 0, 0, 0);
            __builtin_amdgcn_s_setprio(0);
        }

        lgkm_barrier();
        if (t + 2 < KT) {
            stageT(t + 2);
            wait_vmcnt<6>();
            hard_barrier();
        } else if (t + 1 < KT) {
            wait_vmcnt<0>();
            hard_barrier();
        }
    }

#pragma unroll
    for (int m = 0; m < 4; ++m) {
        const int rbase = row0 + wr * 64 + m * 16 + lhi * 4;
#pragma unroll
        for (int n = 0; n < 2; ++n) {
            const int c = col0 + wc * 32 + n * 16 + llo;
#pragma unroll
            for (int r = 0; r < 4; ++r) {
                const size_t idx = (size_t)(rbase + r) * N + c;
                outp[idx] = resid[idx] + acc[m][n][r];
            }
        }
    }
}

// ---------------- V transpose: qkuv v-quarter [B][L][H*64] -> v_t [B*H][64][L] ----------------
__global__ __launch_bounds__(256) void v_trans(const bf16* __restrict__ qkuv, bf16* __restrict__ v_t)
{
    __shared__ bf16 t[64][65];
    const int bh = blockIdx.y;         // b*16+h
    const int b = bh >> 4, h = bh & 15;
    const int l0 = blockIdx.x << 6;
    const int tx = threadIdx.x, ty = threadIdx.y;
#pragma unroll
    for (int i = ty; i < 64; i += 4)
        t[i][tx] = qkuv[(size_t)(b * 2048 + l0 + i) * 4096 + 2048 + h * 64 + tx];
    __syncthreads();
#pragma unroll
    for (int i = ty; i < 64; i += 4)
        v_t[(size_t)(bh * 64 + i) * 2048 + l0 + tx] = t[tx][i];
}

// ---------------- fused silu-attention + head-LN*u (KVBLK=128, LPT grid) ----------------
__global__ __launch_bounds__(512) void attn_kernel(
    const bf16* __restrict__ qkuv, const bf16* __restrict__ v_t,
    const float* __restrict__ nag, const float* __restrict__ nab,
    bf16* __restrict__ au)
{
    __shared__ __align__(16) bf16 lK[2][128 * 64];
    __shared__ __align__(16) bf16 lV[2][64 * 128];
    const int tid = threadIdx.x;
    const int wid = tid >> 6, lane = tid & 63;
    const int lhi = lane >> 4, llo = lane & 15;
    const int bid = (int)blockIdx.x;
    const int qt = 15 - (bid >> 5);                       // heavy blocks dispatched first
    const int bh = bid & 31;
    const int b = bh >> 4, h = bh & 15;
    const int q0 = qt << 7;
    const bf16* Qb = qkuv + (size_t)b * 2048 * 4096 + h * 64;
    const bf16* Kb = Qb + 1024;
    const bf16* Ub = Qb + 3072;
    const bf16* Vb = v_t + (size_t)bh * 64 * 2048;
    const int wbase = wid << 6;

    auto stage = [&](int kt_s, int buf) {
        const int koff = kt_s << 7;
        char* lKc = (char*)lK[buf];
        char* lVc = (char*)lV[buf];
#pragma unroll
        for (int it = 0; it < 2; ++it) {
            const int p = it * 512 + wbase + lane;
            const int r = p >> 3, pc = p & 7;
            const int lc = pc ^ (r & 7);
            load_lds16(Kb + (size_t)(koff + r) * 4096 + lc * 8, lKc + (it * 512 + wbase) * 16);
        }
#pragma unroll
        for (int it = 0; it < 2; ++it) {
            const int p = it * 512 + wbase + lane;
            const int d = p >> 4, pc = p & 15;
            const int lc = pc ^ (d & 15);
            load_lds16(Vb + (size_t)d * 2048 + koff + lc * 8, lVc + (it * 512 + wbase) * 16);
        }
    };

    // hoist Q B-frags: q = wid*16 + llo, dk = kk*32 + lhi*8
    short8 qb[2];
#pragma unroll
    for (int kk = 0; kk < 2; ++kk)
        qb[kk] = *(const short8*)(Qb + (size_t)(q0 + wid * 16 + llo) * 4096 + kk * 32 + lhi * 8);

    f32x4 acc2[4] = {};

    stage(0, 0);  // prologue prefetch

    for (int kt = 0; kt <= qt; ++kt) {
        const int cur = kt & 1;
        drain_and_sync();                      // staged buf[cur] visible to all waves
        if (kt < qt) stage(kt + 1, cur ^ 1);   // prefetch next tile into other buffer
        const char* lKc = (const char*)lK[cur];
        const char* lVc = (const char*)lV[cur];

        const bool diag = (kt == qt);
#pragma unroll
        for (int m = 0; m < 8; ++m) {
            if (diag && m > wid) break;                    // fully above diagonal
            const int rK = m * 16 + llo;
            const int sw = rK & 7;
            short8 ak0 = *(const short8*)(lKc + rK * 128 + ((lhi ^ sw) << 4));
            short8 ak1 = *(const short8*)(lKc + rK * 128 + (((4 + lhi) ^ sw) << 4));
            f32x4 s = {};
            s = __builtin_amdgcn_mfma_f32_16x16x32_bf16(ak0, qb[0], s, 0, 0, 0);
            s = __builtin_amdgcn_mfma_f32_16x16x32_bf16(ak1, qb[1], s, 0, 0, 0);
            const bool mask = diag && (m == wid);
            bfv4 a16;
#pragma unroll
            for (int r = 0; r < 4; ++r) {
                float xx = s[r] * 0.125f;
                xx = xx * __builtin_amdgcn_rcpf(1.f + __expf(-xx));
                if (mask && (lhi * 4 + r > llo)) xx = 0.f;
                a16[r] = (short)f2bf_bits(xx);
            }
#pragma unroll
            for (int dcol = 0; dcol < 4; ++dcol) {
                const int d = dcol * 16 + llo;
                const int lcV = m * 2 + (lhi >> 1);
                bfv4 bv = *(const bfv4*)(lVc + d * 256 + ((lcV ^ llo) << 4) + (lhi & 1) * 8);
                acc2[dcol] = mfma16(a16, bv, acc2[dcol]);
            }
        }
    }

    // ---- epilogue: LN(d=64) * u ----
#pragma unroll
    for (int r = 0; r < 4; ++r) {
        float vv[4];
        float s = 0.f, ss = 0.f;
#pragma unroll
        for (int dc = 0; dc < 4; ++dc) { vv[dc] = acc2[dc][r]; s += vv[dc]; ss += vv[dc] * vv[dc]; }
#pragma unroll
        for (int o = 1; o < 16; o <<= 1) { s += __shfl_xor(s, o); ss += __shfl_xor(ss, o); }
        const float mu = s * (1.f / 64.f);
        const float rstd = rsqrtf(ss * (1.f / 64.f) - mu * mu + LN_EPS);
        const int q = wid * 16 + lhi * 4 + r;
        const size_t grow = q0 + q;
#pragma unroll
        for (int dc = 0; dc < 4; ++dc) {
            const int c = dc * 16 + llo;
            const float nv = (vv[dc] - mu) * rstd * nag[c] + nab[c];
            const float uu = bf2f(Ub[grow * 4096 + c]);
            au[(size_t)(b * 2048 + grow) * 1024 + h * 64 + c] = f2bf(nv * uu);
        }
    }
}

// ---------------- host launch ----------------
extern "C" void kernel_launch(void* const* d_in, const int* in_sizes, int n_in,
                              void* d_out, int out_size, void* d_ws, size_t ws_size,
                              hipStream_t stream)
{
    const float* x      = (const float*)d_in[0];
    // d_in[1] = attn_mask (tril causal; applied analytically)
    const float* w_qkuv = (const float*)d_in[2];
    const float* w_out  = (const float*)d_in[3];
    const float* w1     = (const float*)d_in[4];
    const float* w2     = (const float*)d_in[5];
    const float* w3     = (const float*)d_in[6];
    const float* ln1g   = (const float*)d_in[7];
    const float* ln1b   = (const float*)d_in[8];
    const float* ln2g   = (const float*)d_in[9];
    const float* ln2b   = (const float*)d_in[10];
    const float* nag    = (const float*)d_in[11];
    const float* nab    = (const float*)d_in[12];
    float* out = (float*)d_out;

    char* ws = (char*)d_ws;
    size_t off = 0;
    auto alloc = [&](size_t bytes) { void* p = ws + off; off += (bytes + 255) & ~(size_t)255; return p; };
    const size_t M = 4096;  // B*L
    bf16* wqkuvT = (bf16*)alloc(4096ull * 1024 * 2);
    bf16* woutT  = (bf16*)alloc(1024ull * 1024 * 2);
    bf16* w1T    = (bf16*)alloc(4096ull * 1024 * 2);
    bf16* w3T    = (bf16*)alloc(4096ull * 1024 * 2);
    bf16* w2T    = (bf16*)alloc(1024ull * 4096 * 2);
    bf16* xn     = (bf16*)alloc(M * 1024 * 2);
    bf16* qkuv   = (bf16*)alloc(M * 4096 * 2);
    bf16* vt     = (bf16*)alloc(32ull * 64 * 2048 * 2);
    bf16* aub    = (bf16*)alloc(M * 1024 * 2);
    float* x2    = (float*)alloc(M * 1024 * 4);
    bf16* xn2    = (bf16*)alloc(M * 1024 * 2);
    bf16* h1     = (bf16*)alloc(M * 4096 * 2);
    (void)ws_size; (void)in_sizes; (void)n_in; (void)out_size;

    dim3 tb(32, 8);
    transpose_cast3<<<dim3(4096 / 32, 1024 / 32, 3), tb, 0, stream>>>(w_qkuv, w1, w3, wqkuvT, w1T, w3T);
    transpose_cast<<<dim3(1024 / 32, 1024 / 32), tb, 0, stream>>>(w_out, woutT, 1024, 1024);
    transpose_cast<<<dim3(1024 / 32, 4096 / 32), tb, 0, stream>>>(w2, w2T, 4096, 1024);

    ln_cast<<<M, 256, 0, stream>>>(x, ln1g, ln1b, xn);

    gemm8<<<dim3((M / 128) * (4096 / 256)), 512, 0, stream>>>(xn, wqkuvT, qkuv, M, 4096, 1024);

    v_trans<<<dim3(2048 / 64, 32), dim3(64, 4), 0, stream>>>(qkuv, vt);

    attn_kernel<<<dim3(512), 512, 0, stream>>>(qkuv, vt, nag, nab, aub);

    gemm_btc<<<dim3((M / 128) * (1024 / 64)), 256, 0, stream>>>(aub, woutT, x2, x, M, 1024, 1024);

    ln_cast<<<M, 256, 0, stream>>>(x2, ln2g, ln2b, xn2);

    gemm_w13_8<<<dim3((M / 128) * (4096 / 128)), 512, 0, stream>>>(xn2, w1T, w3T, h1, M, 4096, 1024);

    gemm_btc<<<dim3((M / 128) * (1024 / 64)), 256, 0, stream>>>(h1, w2T, out, x2, M, 1024, 4096);
}

// Round 18
// 284.196 us; speedup vs baseline: 1.0208x; 1.0208x over previous
//
#include <hip/hip_runtime.h>
#include <hip/hip_bf16.h>

typedef __hip_bfloat16 bf16;
typedef __attribute__((ext_vector_type(8))) short short8;
typedef __attribute__((ext_vector_type(4))) short bfv4;
typedef __attribute__((ext_vector_type(4))) float f32x4;
typedef __attribute__((ext_vector_type(4))) unsigned short us4;

#define LN_EPS 1e-5f

__device__ __forceinline__ float siluf(float x) { return x / (1.f + __expf(-x)); }
__device__ __forceinline__ unsigned short f2bf_bits(float f) {
    bf16 h = __float2bfloat16(f);
    return *reinterpret_cast<unsigned short*>(&h);
}
__device__ __forceinline__ bf16 f2bf(float f) { return __float2bfloat16(f); }
__device__ __forceinline__ float bf2f(bf16 h) { return __bfloat162float(h); }

// async global->LDS, 16B per lane. LDS dest must be wave-uniform base (+lane*16 implicit).
__device__ __forceinline__ void load_lds16(const void* g, void* l) {
    __builtin_amdgcn_global_load_lds((const __attribute__((address_space(1))) void*)g,
                                     (__attribute__((address_space(3))) void*)l, 16, 0, 0);
}

__device__ __forceinline__ f32x4 mfma16(bfv4 a, bfv4 b, f32x4 c) {
    return __builtin_amdgcn_mfma_f32_16x16x16bf16_1k(a, b, c, 0, 0, 0);
}

// explicit RAW drain for global_load_lds before a barrier (rule-#18 class hazard)
__device__ __forceinline__ void drain_and_sync() {
    asm volatile("s_waitcnt vmcnt(0)" ::: "memory");
    __builtin_amdgcn_sched_barrier(0);
    __syncthreads();
}

// counted vmcnt wait (literal), fenced
template <int N>
__device__ __forceinline__ void wait_vmcnt() {
    asm volatile("s_waitcnt vmcnt(%0)" :: "n"(N) : "memory");
}
__device__ __forceinline__ void hard_barrier() {
    __builtin_amdgcn_sched_barrier(0);
    __builtin_amdgcn_s_barrier();
    __builtin_amdgcn_sched_barrier(0);
}
// barrier preceded by lgkmcnt(0): all this wave's ds_reads complete before crossing (WAR safety)
__device__ __forceinline__ void lgkm_barrier() {
    asm volatile("s_waitcnt lgkmcnt(0)" ::: "memory");
    __builtin_amdgcn_sched_barrier(0);
    __builtin_amdgcn_s_barrier();
    __builtin_amdgcn_sched_barrier(0);
}

// fine-phase sync: rendezvous, then wait own ds_reads, then high-prio MFMA
__device__ __forceinline__ void phase_pre() {
    __builtin_amdgcn_sched_barrier(0);
    __builtin_amdgcn_s_barrier();
    asm volatile("s_waitcnt lgkmcnt(0)" ::: "memory");
    __builtin_amdgcn_sched_barrier(0);
    __builtin_amdgcn_s_setprio(1);
}
__device__ __forceinline__ void phase_post() {
    __builtin_amdgcn_s_setprio(0);
    __builtin_amdgcn_sched_barrier(0);
    __builtin_amdgcn_s_barrier();
    __builtin_amdgcn_sched_barrier(0);
}

// XCD-chunked bijective block swizzle (requires nwg % 8 == 0)
__device__ __forceinline__ int xcd_swz(int bid, int nwg) {
    return (bid & 7) * (nwg >> 3) + (bid >> 3);
}

// ---------------- weight transpose+cast: fp32 [K][N] -> bf16 [N][K] ----------------
__global__ __launch_bounds__(256) void transpose_cast(
    const float* __restrict__ src, bf16* __restrict__ dst, int K, int N)
{
    __shared__ float t[32][33];
    const int nb = blockIdx.x << 5, kb = blockIdx.y << 5;
    const int tx = threadIdx.x, ty = threadIdx.y;
#pragma unroll
    for (int i = ty; i < 32; i += 8) t[i][tx] = src[(size_t)(kb + i) * N + nb + tx];
    __syncthreads();
#pragma unroll
    for (int i = ty; i < 32; i += 8) dst[(size_t)(nb + i) * K + kb + tx] = f2bf(t[tx][i]);
}

// three 1024x4096 weight transposes in one launch (z selects tensor)
__global__ __launch_bounds__(256) void transpose_cast3(
    const float* __restrict__ s0, const float* __restrict__ s1, const float* __restrict__ s2,
    bf16* __restrict__ d0, bf16* __restrict__ d1, bf16* __restrict__ d2)
{
    const float* src = (blockIdx.z == 0) ? s0 : (blockIdx.z == 1) ? s1 : s2;
    bf16* dst = (blockIdx.z == 0) ? d0 : (blockIdx.z == 1) ? d1 : d2;
    const int K = 1024, N = 4096;
    __shared__ float t[32][33];
    const int nb = blockIdx.x << 5, kb = blockIdx.y << 5;
    const int tx = threadIdx.x, ty = threadIdx.y;
#pragma unroll
    for (int i = ty; i < 32; i += 8) t[i][tx] = src[(size_t)(kb + i) * N + nb + tx];
    __syncthreads();
#pragma unroll
    for (int i = ty; i < 32; i += 8) dst[(size_t)(nb + i) * K + kb + tx] = f2bf(t[tx][i]);
}

// ---------------- LayerNorm fp32 row (D=1024) -> bf16 ----------------
__global__ __launch_bounds__(256) void ln_cast(
    const float* __restrict__ x, const float* __restrict__ g, const float* __restrict__ be,
    bf16* __restrict__ out)
{
    const int row = blockIdx.x, tid = threadIdx.x;
    const float4 v = ((const float4*)(x + (size_t)row * 1024))[tid];
    float s = v.x + v.y + v.z + v.w;
    float ss = v.x * v.x + v.y * v.y + v.z * v.z + v.w * v.w;
#pragma unroll
    for (int o = 32; o; o >>= 1) { s += __shfl_down(s, o); ss += __shfl_down(ss, o); }
    __shared__ float red[10];
    const int wid = tid >> 6, lane = tid & 63;
    if (lane == 0) { red[wid] = s; red[4 + wid] = ss; }
    __syncthreads();
    if (tid == 0) {
        float S = red[0] + red[1] + red[2] + red[3];
        float SS = red[4] + red[5] + red[6] + red[7];
        float mu = S * (1.f / 1024.f);
        red[8] = mu;
        red[9] = rsqrtf(SS * (1.f / 1024.f) - mu * mu + LN_EPS);
    }
    __syncthreads();
    const float mu = red[8], rstd = red[9];
    const float4 gg = ((const float4*)g)[tid];
    const float4 bb = ((const float4*)be)[tid];
    us4 o;
    o[0] = f2bf_bits((v.x - mu) * rstd * gg.x + bb.x);
    o[1] = f2bf_bits((v.y - mu) * rstd * gg.y + bb.y);
    o[2] = f2bf_bits((v.z - mu) * rstd * gg.z + bb.z);
    o[3] = f2bf_bits((v.w - mu) * rstd * gg.w + bb.w);
    ((us4*)(out + (size_t)row * 1024))[tid] = o;
}

// ---------------- 256x256 bf16 GEMM, 4-phase fine interleave, distance-1 dbuf (R16) ----------------
// Column-major block order (B-panels L2-resident; A reused across bx).
// EPI: 0 = bf16 silu(acc)
template <int EPI>
__global__ __launch_bounds__(512, 2) void gemm8(
    const bf16* __restrict__ A, const bf16* __restrict__ BT,
    bf16* __restrict__ outp, const bf16* __restrict__ mulsrc,
    int M, int N, int K)
{
    __shared__ __align__(16) bf16 lds[2][2][256 * 64];   // [buf][A=0/B=1][row*64+col]
    const int tid = threadIdx.x;
    const int wid = tid >> 6, lane = tid & 63;
    const int lhi = lane >> 4, llo = lane & 15;
    const int nby = M >> 8;
    const int bid = xcd_swz((int)blockIdx.x, (int)gridDim.x);
    const int by = bid % nby, bx = bid / nby;            // column-major
    const int row0 = by << 8, col0 = bx << 8;
    const int wr = wid >> 2, wc = wid & 3;               // 2M x 4N
    const int wbase = wid << 6;

    auto stage_tile = [&](const bf16* src, int r0, int k0, char* ldsbase) {
#pragma unroll
        for (int it = 0; it < 4; ++it) {
            const int p = it * 512 + wbase + lane;       // physical 16B-chunk index
            const int r = p >> 3, pc = p & 7;
            const int lc = pc ^ (r & 7);                 // logical chunk this slot holds
            load_lds16(src + (size_t)(r0 + r) * K + k0 + lc * 8,
                       ldsbase + (size_t)(it * 512 + wbase) * 16);
        }
    };
    auto stageA = [&](int t) { stage_tile(A, row0, t << 6, (char*)lds[t & 1][0]); };
    auto stageB = [&](int t) { stage_tile(BT, col0, t << 6, (char*)lds[t & 1][1]); };

    f32x4 acc[8][4] = {};

    // prologue: T0 only
    stageA(0); stageB(0);
    wait_vmcnt<0>();
    hard_barrier();

    const int KT = K >> 6;
    for (int t = 0; t < KT; ++t) {
        const bool more = (t + 1 < KT);
        const char* lAc = (const char*)lds[t & 1][0];
        const char* lBc = (const char*)lds[t & 1][1];

        short8 a0[2][4], a1[2][4], b0[2][2], b1[2][2];   // [kk][frag]
        auto ldA = [&](short8 af[2][4], int mh) {
#pragma unroll
            for (int kk = 0; kk < 2; ++kk)
#pragma unroll
                for (int m = 0; m < 4; ++m) {
                    const int ra = wr * 128 + mh * 64 + m * 16 + llo;
                    af[kk][m] = *(const short8*)(lAc + ra * 128 + (((kk * 4 + lhi) ^ (ra & 7)) << 4));
                }
        };
        auto ldB = [&](short8 bf_[2][2], int nh) {
#pragma unroll
            for (int kk = 0; kk < 2; ++kk)
#pragma unroll
                for (int n = 0; n < 2; ++n) {
                    const int rb = wc * 64 + nh * 32 + n * 16 + llo;
                    bf_[kk][n] = *(const short8*)(lBc + rb * 128 + (((kk * 4 + lhi) ^ (rb & 7)) << 4));
                }
        };
        auto mfma_q = [&](int mh, int nh, short8 af[2][4], short8 bf_[2][2]) {
#pragma unroll
            for (int kk = 0; kk < 2; ++kk)
#pragma unroll
                for (int m = 0; m < 4; ++m)
#pragma unroll
                    for (int n = 0; n < 2; ++n)
                        acc[mh * 4 + m][nh * 2 + n] =
                            __builtin_amdgcn_mfma_f32_16x16x32_bf16(af[kk][m], bf_[kk][n], acc[mh * 4 + m][nh * 2 + n], 0, 0, 0);
        };

        // P1: quadrant (0,0); stage A(t+1)
        ldA(a0, 0); ldB(b0, 0);
        if (more) stageA(t + 1);
        phase_pre(); mfma_q(0, 0, a0, b0); phase_post();
        // P2: quadrant (0,1); stage B(t+1)
        ldB(b1, 1);
        if (more) stageB(t + 1);
        phase_pre(); mfma_q(0, 1, a0, b1); phase_post();
        // P3: quadrant (1,1)
        ldA(a1, 1);
        phase_pre(); mfma_q(1, 1, a1, b1); phase_post();
        // P4: quadrant (1,0)
        phase_pre(); mfma_q(1, 0, a1, b0); phase_post();

        if (more) { wait_vmcnt<0>(); hard_barrier(); }   // T_{t+1} landed (loads >=2 phases old)
    }

#pragma unroll
    for (int m = 0; m < 8; ++m) {
        const int rbase = row0 + wr * 128 + m * 16 + lhi * 4;
#pragma unroll
        for (int n = 0; n < 4; ++n) {
            const int c = col0 + wc * 64 + n * 16 + llo;
#pragma unroll
            for (int r = 0; r < 4; ++r) {
                const size_t idx = (size_t)(rbase + r) * N + c;
                const float v = acc[m][n][r];
                if constexpr (EPI == 0) outp[idx] = f2bf(siluf(v));
                else                    outp[idx] = f2bf(v * bf2f(mulsrc[idx]));
            }
        }
    }
}

// ---------------- fused FFN: h1 = silu(A@W1) * (A@W3), tile 128x128, BK=32, LDS 48 KB ----------------
// High-occupancy (VGPR 60, 3 blocks/CU) with 2-ROW-PACKED LDS to kill bank conflicts:
// logical row r, k-chunk lc stored at byte (r>>1)*128 + (r&1)*64 + ((lc ^ ((r>>1)&3))<<4).
// Rows are 128B again -> 16-lane frag read spans 8 distinct (r&1, chunk) bank-spans = 2-way (free).
// Staging inverse map: phys slot p -> pr=p>>3, pc=p&7, r=2*pr+(pc>>2), lc=(pc&3)^(pr&3).
__global__ __launch_bounds__(512) void gemm_w13_8(
    const bf16* __restrict__ A, const bf16* __restrict__ B1T, const bf16* __restrict__ B3T,
    bf16* __restrict__ outp, int M, int N, int K)
{
    __shared__ __align__(16) bf16 lA[2][64 * 64];
    __shared__ __align__(16) bf16 lB1[2][64 * 64];
    __shared__ __align__(16) bf16 lB3[2][64 * 64];
    const int tid = threadIdx.x;
    const int wid = tid >> 6, lane = tid & 63;
    const int lhi = lane >> 4, llo = lane & 15;
    const int nby = M >> 7;
    const int bid = xcd_swz((int)blockIdx.x, (int)gridDim.x);
    const int by = bid % nby, bx = bid / nby;            // column-major
    const int row0 = by << 7, col0 = bx << 7;
    const int wr = wid >> 2, wc = wid & 3;               // 2M x 4N
    const int wbase = wid << 6;

    auto stage_rows = [&](const bf16* src, int r0, int k0, char* ldsbase) {
        const int p = wbase + lane;                      // 0..511 phys 16B slots
        const int pr = p >> 3, pc = p & 7;
        const int r = pr * 2 + (pc >> 2);
        const int lc = (pc & 3) ^ (pr & 3);
        load_lds16(src + (size_t)(r0 + r) * K + k0 + lc * 8, ldsbase + p * 16);
    };
    auto stageT = [&](int t) {
        const int k0 = t << 5, buf = t & 1;
        stage_rows(A, row0, k0, (char*)lA[buf]);
        stage_rows(B1T, col0, k0, (char*)lB1[buf]);
        stage_rows(B3T, col0, k0, (char*)lB3[buf]);
    };
    // packed-row read address for logical row r, k-chunk kc
    auto rdaddr = [&](int r, int kc) {
        return (r >> 1) * 128 + (r & 1) * 64 + ((kc ^ ((r >> 1) & 3)) << 4);
    };

    f32x4 acc1[4][2] = {}, acc3[4][2] = {};

    stageT(0);
    wait_vmcnt<0>();
    hard_barrier();

    const int KT = K >> 5;
    for (int t = 0; t < KT; ++t) {
        const bool more = (t + 1 < KT);
        const char* lAc = (const char*)lA[t & 1];
        const char* lB1c = (const char*)lB1[t & 1];
        const char* lB3c = (const char*)lB3[t & 1];

        short8 af[4], b1f[2], b3f[2];
#pragma unroll
        for (int m = 0; m < 4; ++m) {
            const int ra = wr * 64 + m * 16 + llo;
            af[m] = *(const short8*)(lAc + rdaddr(ra, lhi));
        }
#pragma unroll
        for (int n = 0; n < 2; ++n) {
            const int rb = wc * 32 + n * 16 + llo;
            const int so = rdaddr(rb, lhi);
            b1f[n] = *(const short8*)(lB1c + so);
            b3f[n] = *(const short8*)(lB3c + so);
        }
        if (more) stageT(t + 1);

        // P1: m-half 0 (both accs)
        phase_pre();
#pragma unroll
        for (int m = 0; m < 2; ++m)
#pragma unroll
            for (int n = 0; n < 2; ++n) {
                acc1[m][n] = __builtin_amdgcn_mfma_f32_16x16x32_bf16(af[m], b1f[n], acc1[m][n], 0, 0, 0);
                acc3[m][n] = __builtin_amdgcn_mfma_f32_16x16x32_bf16(af[m], b3f[n], acc3[m][n], 0, 0, 0);
            }
        phase_post();
        // P2: m-half 1
        phase_pre();
#pragma unroll
        for (int m = 2; m < 4; ++m)
#pragma unroll
            for (int n = 0; n < 2; ++n) {
                acc1[m][n] = __builtin_amdgcn_mfma_f32_16x16x32_bf16(af[m], b1f[n], acc1[m][n], 0, 0, 0);
                acc3[m][n] = __builtin_amdgcn_mfma_f32_16x16x32_bf16(af[m], b3f[n], acc3[m][n], 0, 0, 0);
            }
        phase_post();

        if (more) { wait_vmcnt<0>(); hard_barrier(); }
    }

    // epilogue: silu(c1) * c3, wave-local
#pragma unroll
    for (int m = 0; m < 4; ++m) {
        const int rbase = row0 + wr * 64 + m * 16 + lhi * 4;
#pragma unroll
        for (int n = 0; n < 2; ++n) {
            const int c = col0 + wc * 32 + n * 16 + llo;
#pragma unroll
            for (int r = 0; r < 4; ++r) {
                const size_t idx = (size_t)(rbase + r) * N + c;
                outp[idx] = f2bf(siluf(acc1[m][n][r]) * acc3[m][n][r]);
            }
        }
    }
}

// ---------------- 128x64 bf16 GEMM, counted-vmcnt double-buffer (N=1024 GEMMs) ----------------
// ROW-major block order: A-slab L2-resident; right for K-large/N-small shapes (w2).
__global__ __launch_bounds__(256) void gemm_btc(
    const bf16* __restrict__ A, const bf16* __restrict__ BT,
    float* __restrict__ outp, const float* __restrict__ resid,
    int M, int N, int K)
{
    __shared__ __align__(16) bf16 lA[2][128 * 64];
    __shared__ __align__(16) bf16 lB[2][64 * 64];
    const int tid = threadIdx.x;
    const int wid = tid >> 6, lane = tid & 63;
    const int lhi = lane >> 4, llo = lane & 15;
    const int ntx = N >> 6;
    const int bid = xcd_swz((int)blockIdx.x, (int)gridDim.x);
    const int bx = bid % ntx, by = bid / ntx;            // row-major
    const int row0 = by << 7, col0 = bx << 6;
    const int wr = wid >> 1, wc = wid & 1;               // 2M x 2N
    const int wbase = wid << 6;

    auto stage_tile = [&](const bf16* src, int r0, int k0, char* ldsbase, int nit) {
        for (int it = 0; it < nit; ++it) {
            const int p = it * 256 + wbase + lane;
            const int r = p >> 3, pc = p & 7;
            const int lc = pc ^ (r & 7);
            load_lds16(src + (size_t)(r0 + r) * K + k0 + lc * 8,
                       ldsbase + (size_t)(it * 256 + wbase) * 16);
        }
    };
    auto stageT = [&](int t) {
        stage_tile(A, row0, t << 6, (char*)lA[t & 1], 4);
        stage_tile(BT, col0, t << 6, (char*)lB[t & 1], 2);
    };

    f32x4 acc[4][2] = {};

    stageT(0); stageT(1);
    wait_vmcnt<6>();
    hard_barrier();

    const int KT = K >> 6;
    for (int t = 0; t < KT; ++t) {
        const int buf = t & 1;
        const char* lAc = (const char*)lA[buf];
        const char* lBc = (const char*)lB[buf];

        short8 af[4], bfr[2];
        auto ldA = [&](int kk) {
#pragma unroll
            for (int m = 0; m < 4; ++m) {
                const int ra = wr * 64 + m * 16 + llo;
                af[m] = *(const short8*)(lAc + ra * 128 + (((kk * 4 + lhi) ^ (ra & 7)) << 4));
            }
        };
        auto ldB = [&](int kk) {
#pragma unroll
            for (int n = 0; n < 2; ++n) {
                const int rb = wc * 32 + n * 16 + llo;
                bfr[n] = *(const short8*)(lBc + rb * 128 + (((kk * 4 + lhi) ^ (rb & 7)) << 4));
            }
        };

#pragma unroll
        for (int kk = 0; kk < 2; ++kk) {
            ldA(kk); ldB(kk);
            __builtin_amdgcn_s_setprio(1);
#pragma unroll
            for (int m = 0; m < 4; ++m)
#pragma unroll
                for (int n = 0; n < 2; ++n)
                    acc[m][n] = __builtin_amdgcn_mfma_f32_16x16x32_bf16(af[m], bfr[n], acc[m][n], 0, 0, 0);
            __builtin_amdgcn_s_setprio(0);
        }

        lgkm_barrier();
        if (t + 2 < KT) {
            stageT(t + 2);
            wait_vmcnt<6>();
            hard_barrier();
        } else if (t + 1 < KT) {
            wait_vmcnt<0>();
            hard_barrier();
        }
    }

#pragma unroll
    for (int m = 0; m < 4; ++m) {
        const int rbase = row0 + wr * 64 + m * 16 + lhi * 4;
#pragma unroll
        for (int n = 0; n < 2; ++n) {
            const int c = col0 + wc * 32 + n * 16 + llo;
#pragma unroll
            for (int r = 0; r < 4; ++r) {
                const size_t idx = (size_t)(rbase + r) * N + c;
                outp[idx] = resid[idx] + acc[m][n][r];
            }
        }
    }
}

// ---------------- V transpose: qkuv v-quarter [B][L][H*64] -> v_t [B*H][64][L] ----------------
__global__ __launch_bounds__(256) void v_trans(const bf16* __restrict__ qkuv, bf16* __restrict__ v_t)
{
    __shared__ bf16 t[64][65];
    const int bh = blockIdx.y;         // b*16+h
    const int b = bh >> 4, h = bh & 15;
    const int l0 = blockIdx.x << 6;
    const int tx = threadIdx.x, ty = threadIdx.y;
#pragma unroll
    for (int i = ty; i < 64; i += 4)
        t[i][tx] = qkuv[(size_t)(b * 2048 + l0 + i) * 4096 + 2048 + h * 64 + tx];
    __syncthreads();
#pragma unroll
    for (int i = ty; i < 64; i += 4)
        v_t[(size_t)(bh * 64 + i) * 2048 + l0 + tx] = t[tx][i];
}

// ---------------- fused silu-attention + head-LN*u (KVBLK=128, LPT grid) ----------------
__global__ __launch_bounds__(512) void attn_kernel(
    const bf16* __restrict__ qkuv, const bf16* __restrict__ v_t,
    const float* __restrict__ nag, const float* __restrict__ nab,
    bf16* __restrict__ au)
{
    __shared__ __align__(16) bf16 lK[2][128 * 64];
    __shared__ __align__(16) bf16 lV[2][64 * 128];
    const int tid = threadIdx.x;
    const int wid = tid >> 6, lane = tid & 63;
    const int lhi = lane >> 4, llo = lane & 15;
    const int bid = (int)blockIdx.x;
    const int qt = 15 - (bid >> 5);                       // heavy blocks dispatched first
    const int bh = bid & 31;
    const int b = bh >> 4, h = bh & 15;
    const int q0 = qt << 7;
    const bf16* Qb = qkuv + (size_t)b * 2048 * 4096 + h * 64;
    const bf16* Kb = Qb + 1024;
    const bf16* Ub = Qb + 3072;
    const bf16* Vb = v_t + (size_t)bh * 64 * 2048;
    const int wbase = wid << 6;

    auto stage = [&](int kt_s, int buf) {
        const int koff = kt_s << 7;
        char* lKc = (char*)lK[buf];
        char* lVc = (char*)lV[buf];
#pragma unroll
        for (int it = 0; it < 2; ++it) {
            const int p = it * 512 + wbase + lane;
            const int r = p >> 3, pc = p & 7;
            const int lc = pc ^ (r & 7);
            load_lds16(Kb + (size_t)(koff + r) * 4096 + lc * 8, lKc + (it * 512 + wbase) * 16);
        }
#pragma unroll
        for (int it = 0; it < 2; ++it) {
            const int p = it * 512 + wbase + lane;
            const int d = p >> 4, pc = p & 15;
            const int lc = pc ^ (d & 15);
            load_lds16(Vb + (size_t)d * 2048 + koff + lc * 8, lVc + (it * 512 + wbase) * 16);
        }
    };

    // hoist Q B-frags: q = wid*16 + llo, dk = kk*32 + lhi*8
    short8 qb[2];
#pragma unroll
    for (int kk = 0; kk < 2; ++kk)
        qb[kk] = *(const short8*)(Qb + (size_t)(q0 + wid * 16 + llo) * 4096 + kk * 32 + lhi * 8);

    f32x4 acc2[4] = {};

    stage(0, 0);  // prologue prefetch

    for (int kt = 0; kt <= qt; ++kt) {
        const int cur = kt & 1;
        drain_and_sync();                      // staged buf[cur] visible to all waves
        if (kt < qt) stage(kt + 1, cur ^ 1);   // prefetch next tile into other buffer
        const char* lKc = (const char*)lK[cur];
        const char* lVc = (const char*)lV[cur];

        const bool diag = (kt == qt);
#pragma unroll
        for (int m = 0; m < 8; ++m) {
            if (diag && m > wid) break;                    // fully above diagonal
            const int rK = m * 16 + llo;
            const int sw = rK & 7;
            short8 ak0 = *(const short8*)(lKc + rK * 128 + ((lhi ^ sw) << 4));
            short8 ak1 = *(const short8*)(lKc + rK * 128 + (((4 + lhi) ^ sw) << 4));
            f32x4 s = {};
            s = __builtin_amdgcn_mfma_f32_16x16x32_bf16(ak0, qb[0], s, 0, 0, 0);
            s = __builtin_amdgcn_mfma_f32_16x16x32_bf16(ak1, qb[1], s, 0, 0, 0);
            const bool mask = diag && (m == wid);
            bfv4 a16;
#pragma unroll
            for (int r = 0; r < 4; ++r) {
                float xx = s[r] * 0.125f;
                xx = xx * __builtin_amdgcn_rcpf(1.f + __expf(-xx));
                if (mask && (lhi * 4 + r > llo)) xx = 0.f;
                a16[r] = (short)f2bf_bits(xx);
            }
#pragma unroll
            for (int dcol = 0; dcol < 4; ++dcol) {
                const int d = dcol * 16 + llo;
                const int lcV = m * 2 + (lhi >> 1);
                bfv4 bv = *(const bfv4*)(lVc + d * 256 + ((lcV ^ llo) << 4) + (lhi & 1) * 8);
                acc2[dcol] = mfma16(a16, bv, acc2[dcol]);
            }
        }
    }

    // ---- epilogue: LN(d=64) * u ----
#pragma unroll
    for (int r = 0; r < 4; ++r) {
        float vv[4];
        float s = 0.f, ss = 0.f;
#pragma unroll
        for (int dc = 0; dc < 4; ++dc) { vv[dc] = acc2[dc][r]; s += vv[dc]; ss += vv[dc] * vv[dc]; }
#pragma unroll
        for (int o = 1; o < 16; o <<= 1) { s += __shfl_xor(s, o); ss += __shfl_xor(ss, o); }
        const float mu = s * (1.f / 64.f);
        const float rstd = rsqrtf(ss * (1.f / 64.f) - mu * mu + LN_EPS);
        const int q = wid * 16 + lhi * 4 + r;
        const size_t grow = q0 + q;
#pragma unroll
        for (int dc = 0; dc < 4; ++dc) {
            const int c = dc * 16 + llo;
            const float nv = (vv[dc] - mu) * rstd * nag[c] + nab[c];
            const float uu = bf2f(Ub[grow * 4096 + c]);
            au[(size_t)(b * 2048 + grow) * 1024 + h * 64 + c] = f2bf(nv * uu);
        }
    }
}

// ---------------- host launch ----------------
extern "C" void kernel_launch(void* const* d_in, const int* in_sizes, int n_in,
                              void* d_out, int out_size, void* d_ws, size_t ws_size,
                              hipStream_t stream)
{
    const float* x      = (const float*)d_in[0];
    // d_in[1] = attn_mask (tril causal; applied analytically)
    const float* w_qkuv = (const float*)d_in[2];
    const float* w_out  = (const float*)d_in[3];
    const float* w1     = (const float*)d_in[4];
    const float* w2     = (const float*)d_in[5];
    const float* w3     = (const float*)d_in[6];
    const float* ln1g   = (const float*)d_in[7];
    const float* ln1b   = (const float*)d_in[8];
    const float* ln2g   = (const float*)d_in[9];
    const float* ln2b   = (const float*)d_in[10];
    const float* nag    = (const float*)d_in[11];
    const float* nab    = (const float*)d_in[12];
    float* out = (float*)d_out;

    char* ws = (char*)d_ws;
    size_t off = 0;
    auto alloc = [&](size_t bytes) { void* p = ws + off; off += (bytes + 255) & ~(size_t)255; return p; };
    const size_t M = 4096;  // B*L
    bf16* wqkuvT = (bf16*)alloc(4096ull * 1024 * 2);
    bf16* woutT  = (bf16*)alloc(1024ull * 1024 * 2);
    bf16* w1T    = (bf16*)alloc(4096ull * 1024 * 2);
    bf16* w3T    = (bf16*)alloc(4096ull * 1024 * 2);
    bf16* w2T    = (bf16*)alloc(1024ull * 4096 * 2);
    bf16* xn     = (bf16*)alloc(M * 1024 * 2);
    bf16* qkuv   = (bf16*)alloc(M * 4096 * 2);
    bf16* vt     = (bf16*)alloc(32ull * 64 * 2048 * 2);
    bf16* aub    = (bf16*)alloc(M * 1024 * 2);
    float* x2    = (float*)alloc(M * 1024 * 4);
    bf16* xn2    = (bf16*)alloc(M * 1024 * 2);
    bf16* h1     = (bf16*)alloc(M * 4096 * 2);
    (void)ws_size; (void)in_sizes; (void)n_in; (void)out_size;

    dim3 tb(32, 8);
    transpose_cast3<<<dim3(4096 / 32, 1024 / 32, 3), tb, 0, stream>>>(w_qkuv, w1, w3, wqkuvT, w1T, w3T);
    transpose_cast<<<dim3(1024 / 32, 1024 / 32), tb, 0, stream>>>(w_out, woutT, 1024, 1024);
    transpose_cast<<<dim3(1024 / 32, 4096 / 32), tb, 0, stream>>>(w2, w2T, 4096, 1024);

    ln_cast<<<M, 256, 0, stream>>>(x, ln1g, ln1b, xn);

    gemm8<0><<<dim3((M / 256) * (4096 / 256)), 512, 0, stream>>>(xn, wqkuvT, qkuv, nullptr, M, 4096, 1024);

    v_trans<<<dim3(2048 / 64, 32), dim3(64, 4), 0, stream>>>(qkuv, vt);

    attn_kernel<<<dim3(512), 512, 0, stream>>>(qkuv, vt, nag, nab, aub);

    gemm_btc<<<dim3((M / 128) * (1024 / 64)), 256, 0, stream>>>(aub, woutT, x2, x, M, 1024, 1024);

    ln_cast<<<M, 256, 0, stream>>>(x2, ln2g, ln2b, xn2);

    gemm_w13_8<<<dim3((M / 128) * (4096 / 128)), 512, 0, stream>>>(xn2, w1T, w3T, h1, M, 4096, 1024);

    gemm_btc<<<dim3((M / 128) * (1024 / 64)), 256, 0, stream>>>(h1, w2T, out, x2, M, 1024, 4096);
}

// Round 19
// 283.821 us; speedup vs baseline: 1.0221x; 1.0013x over previous
//
#include <hip/hip_runtime.h>
#include <hip/hip_bf16.h>

typedef __hip_bfloat16 bf16;
typedef __attribute__((ext_vector_type(8))) short short8;
typedef __attribute__((ext_vector_type(4))) short bfv4;
typedef __attribute__((ext_vector_type(4))) float f32x4;
typedef __attribute__((ext_vector_type(4))) unsigned short us4;

#define LN_EPS 1e-5f

__device__ __forceinline__ float siluf(float x) { return x / (1.f + __expf(-x)); }
__device__ __forceinline__ unsigned short f2bf_bits(float f) {
    bf16 h = __float2bfloat16(f);
    return *reinterpret_cast<unsigned short*>(&h);
}
__device__ __forceinline__ bf16 f2bf(float f) { return __float2bfloat16(f); }
__device__ __forceinline__ float bf2f(bf16 h) { return __bfloat162float(h); }

// async global->LDS, 16B per lane. LDS dest must be wave-uniform base (+lane*16 implicit).
__device__ __forceinline__ void load_lds16(const void* g, void* l) {
    __builtin_amdgcn_global_load_lds((const __attribute__((address_space(1))) void*)g,
                                     (__attribute__((address_space(3))) void*)l, 16, 0, 0);
}

__device__ __forceinline__ f32x4 mfma16(bfv4 a, bfv4 b, f32x4 c) {
    return __builtin_amdgcn_mfma_f32_16x16x16bf16_1k(a, b, c, 0, 0, 0);
}

// explicit RAW drain for global_load_lds before a barrier (rule-#18 class hazard)
__device__ __forceinline__ void drain_and_sync() {
    asm volatile("s_waitcnt vmcnt(0)" ::: "memory");
    __builtin_amdgcn_sched_barrier(0);
    __syncthreads();
}

// counted vmcnt wait (literal), fenced
template <int N>
__device__ __forceinline__ void wait_vmcnt() {
    asm volatile("s_waitcnt vmcnt(%0)" :: "n"(N) : "memory");
}
__device__ __forceinline__ void hard_barrier() {
    __builtin_amdgcn_sched_barrier(0);
    __builtin_amdgcn_s_barrier();
    __builtin_amdgcn_sched_barrier(0);
}
// barrier preceded by lgkmcnt(0): all this wave's ds_reads complete before crossing (WAR safety)
__device__ __forceinline__ void lgkm_barrier() {
    asm volatile("s_waitcnt lgkmcnt(0)" ::: "memory");
    __builtin_amdgcn_sched_barrier(0);
    __builtin_amdgcn_s_barrier();
    __builtin_amdgcn_sched_barrier(0);
}

// fine-phase sync: rendezvous, then wait own ds_reads, then high-prio MFMA
__device__ __forceinline__ void phase_pre() {
    __builtin_amdgcn_sched_barrier(0);
    __builtin_amdgcn_s_barrier();
    asm volatile("s_waitcnt lgkmcnt(0)" ::: "memory");
    __builtin_amdgcn_sched_barrier(0);
    __builtin_amdgcn_s_setprio(1);
}
__device__ __forceinline__ void phase_post() {
    __builtin_amdgcn_s_setprio(0);
    __builtin_amdgcn_sched_barrier(0);
    __builtin_amdgcn_s_barrier();
    __builtin_amdgcn_sched_barrier(0);
}

// XCD-chunked bijective block swizzle (requires nwg % 8 == 0)
__device__ __forceinline__ int xcd_swz(int bid, int nwg) {
    return (bid & 7) * (nwg >> 3) + (bid >> 3);
}

// ---------------- weight transpose+cast: fp32 [K][N] -> bf16 [N][K] ----------------
__global__ __launch_bounds__(256) void transpose_cast(
    const float* __restrict__ src, bf16* __restrict__ dst, int K, int N)
{
    __shared__ float t[32][33];
    const int nb = blockIdx.x << 5, kb = blockIdx.y << 5;
    const int tx = threadIdx.x, ty = threadIdx.y;
#pragma unroll
    for (int i = ty; i < 32; i += 8) t[i][tx] = src[(size_t)(kb + i) * N + nb + tx];
    __syncthreads();
#pragma unroll
    for (int i = ty; i < 32; i += 8) dst[(size_t)(nb + i) * K + kb + tx] = f2bf(t[tx][i]);
}

// three 1024x4096 weight transposes in one launch (z selects tensor)
__global__ __launch_bounds__(256) void transpose_cast3(
    const float* __restrict__ s0, const float* __restrict__ s1, const float* __restrict__ s2,
    bf16* __restrict__ d0, bf16* __restrict__ d1, bf16* __restrict__ d2)
{
    const float* src = (blockIdx.z == 0) ? s0 : (blockIdx.z == 1) ? s1 : s2;
    bf16* dst = (blockIdx.z == 0) ? d0 : (blockIdx.z == 1) ? d1 : d2;
    const int K = 1024, N = 4096;
    __shared__ float t[32][33];
    const int nb = blockIdx.x << 5, kb = blockIdx.y << 5;
    const int tx = threadIdx.x, ty = threadIdx.y;
#pragma unroll
    for (int i = ty; i < 32; i += 8) t[i][tx] = src[(size_t)(kb + i) * N + nb + tx];
    __syncthreads();
#pragma unroll
    for (int i = ty; i < 32; i += 8) dst[(size_t)(nb + i) * K + kb + tx] = f2bf(t[tx][i]);
}

// ---------------- LayerNorm fp32 row (D=1024) -> bf16 ----------------
__global__ __launch_bounds__(256) void ln_cast(
    const float* __restrict__ x, const float* __restrict__ g, const float* __restrict__ be,
    bf16* __restrict__ out)
{
    const int row = blockIdx.x, tid = threadIdx.x;
    const float4 v = ((const float4*)(x + (size_t)row * 1024))[tid];
    float s = v.x + v.y + v.z + v.w;
    float ss = v.x * v.x + v.y * v.y + v.z * v.z + v.w * v.w;
#pragma unroll
    for (int o = 32; o; o >>= 1) { s += __shfl_down(s, o); ss += __shfl_down(ss, o); }
    __shared__ float red[10];
    const int wid = tid >> 6, lane = tid & 63;
    if (lane == 0) { red[wid] = s; red[4 + wid] = ss; }
    __syncthreads();
    if (tid == 0) {
        float S = red[0] + red[1] + red[2] + red[3];
        float SS = red[4] + red[5] + red[6] + red[7];
        float mu = S * (1.f / 1024.f);
        red[8] = mu;
        red[9] = rsqrtf(SS * (1.f / 1024.f) - mu * mu + LN_EPS);
    }
    __syncthreads();
    const float mu = red[8], rstd = red[9];
    const float4 gg = ((const float4*)g)[tid];
    const float4 bb = ((const float4*)be)[tid];
    us4 o;
    o[0] = f2bf_bits((v.x - mu) * rstd * gg.x + bb.x);
    o[1] = f2bf_bits((v.y - mu) * rstd * gg.y + bb.y);
    o[2] = f2bf_bits((v.z - mu) * rstd * gg.z + bb.z);
    o[3] = f2bf_bits((v.w - mu) * rstd * gg.w + bb.w);
    ((us4*)(out + (size_t)row * 1024))[tid] = o;
}

// ---------------- 256x256 bf16 GEMM, 4-phase fine interleave, distance-1 dbuf (R16) ----------------
// Column-major block order (B-panels L2-resident; A reused across bx).
// EPI: 0 = bf16 silu(acc)
template <int EPI>
__global__ __launch_bounds__(512, 2) void gemm8(
    const bf16* __restrict__ A, const bf16* __restrict__ BT,
    bf16* __restrict__ outp, const bf16* __restrict__ mulsrc,
    int M, int N, int K)
{
    __shared__ __align__(16) bf16 lds[2][2][256 * 64];   // [buf][A=0/B=1][row*64+col]
    const int tid = threadIdx.x;
    const int wid = tid >> 6, lane = tid & 63;
    const int lhi = lane >> 4, llo = lane & 15;
    const int nby = M >> 8;
    const int bid = xcd_swz((int)blockIdx.x, (int)gridDim.x);
    const int by = bid % nby, bx = bid / nby;            // column-major
    const int row0 = by << 8, col0 = bx << 8;
    const int wr = wid >> 2, wc = wid & 3;               // 2M x 4N
    const int wbase = wid << 6;

    auto stage_tile = [&](const bf16* src, int r0, int k0, char* ldsbase) {
#pragma unroll
        for (int it = 0; it < 4; ++it) {
            const int p = it * 512 + wbase + lane;       // physical 16B-chunk index
            const int r = p >> 3, pc = p & 7;
            const int lc = pc ^ (r & 7);                 // logical chunk this slot holds
            load_lds16(src + (size_t)(r0 + r) * K + k0 + lc * 8,
                       ldsbase + (size_t)(it * 512 + wbase) * 16);
        }
    };
    auto stageA = [&](int t) { stage_tile(A, row0, t << 6, (char*)lds[t & 1][0]); };
    auto stageB = [&](int t) { stage_tile(BT, col0, t << 6, (char*)lds[t & 1][1]); };

    f32x4 acc[8][4] = {};

    // prologue: T0 only
    stageA(0); stageB(0);
    wait_vmcnt<0>();
    hard_barrier();

    const int KT = K >> 6;
    for (int t = 0; t < KT; ++t) {
        const bool more = (t + 1 < KT);
        const char* lAc = (const char*)lds[t & 1][0];
        const char* lBc = (const char*)lds[t & 1][1];

        short8 a0[2][4], a1[2][4], b0[2][2], b1[2][2];   // [kk][frag]
        auto ldA = [&](short8 af[2][4], int mh) {
#pragma unroll
            for (int kk = 0; kk < 2; ++kk)
#pragma unroll
                for (int m = 0; m < 4; ++m) {
                    const int ra = wr * 128 + mh * 64 + m * 16 + llo;
                    af[kk][m] = *(const short8*)(lAc + ra * 128 + (((kk * 4 + lhi) ^ (ra & 7)) << 4));
                }
        };
        auto ldB = [&](short8 bf_[2][2], int nh) {
#pragma unroll
            for (int kk = 0; kk < 2; ++kk)
#pragma unroll
                for (int n = 0; n < 2; ++n) {
                    const int rb = wc * 64 + nh * 32 + n * 16 + llo;
                    bf_[kk][n] = *(const short8*)(lBc + rb * 128 + (((kk * 4 + lhi) ^ (rb & 7)) << 4));
                }
        };
        auto mfma_q = [&](int mh, int nh, short8 af[2][4], short8 bf_[2][2]) {
#pragma unroll
            for (int kk = 0; kk < 2; ++kk)
#pragma unroll
                for (int m = 0; m < 4; ++m)
#pragma unroll
                    for (int n = 0; n < 2; ++n)
                        acc[mh * 4 + m][nh * 2 + n] =
                            __builtin_amdgcn_mfma_f32_16x16x32_bf16(af[kk][m], bf_[kk][n], acc[mh * 4 + m][nh * 2 + n], 0, 0, 0);
        };

        // P1: quadrant (0,0); stage A(t+1)
        ldA(a0, 0); ldB(b0, 0);
        if (more) stageA(t + 1);
        phase_pre(); mfma_q(0, 0, a0, b0); phase_post();
        // P2: quadrant (0,1); stage B(t+1)
        ldB(b1, 1);
        if (more) stageB(t + 1);
        phase_pre(); mfma_q(0, 1, a0, b1); phase_post();
        // P3: quadrant (1,1)
        ldA(a1, 1);
        phase_pre(); mfma_q(1, 1, a1, b1); phase_post();
        // P4: quadrant (1,0)
        phase_pre(); mfma_q(1, 0, a1, b0); phase_post();

        if (more) { wait_vmcnt<0>(); hard_barrier(); }   // T_{t+1} landed (loads >=2 phases old)
    }

#pragma unroll
    for (int m = 0; m < 8; ++m) {
        const int rbase = row0 + wr * 128 + m * 16 + lhi * 4;
#pragma unroll
        for (int n = 0; n < 4; ++n) {
            const int c = col0 + wc * 64 + n * 16 + llo;
#pragma unroll
            for (int r = 0; r < 4; ++r) {
                const size_t idx = (size_t)(rbase + r) * N + c;
                const float v = acc[m][n][r];
                if constexpr (EPI == 0) outp[idx] = f2bf(siluf(v));
                else                    outp[idx] = f2bf(v * bf2f(mulsrc[idx]));
            }
        }
    }
}

// ---------------- fused FFN: h1 = silu(A@W1) * (A@W3), 4-phase fine interleave (R16) ----------------
// Column-major block order: B1+B3 panels (2 MB) L2-resident.
__global__ __launch_bounds__(512, 2) void gemm_w13_8(
    const bf16* __restrict__ A, const bf16* __restrict__ B1T, const bf16* __restrict__ B3T,
    bf16* __restrict__ outp, int M, int N, int K)
{
    __shared__ __align__(16) bf16 lA[2][256 * 64];
    __shared__ __align__(16) bf16 lB1[2][128 * 64];
    __shared__ __align__(16) bf16 lB3[2][128 * 64];
    const int tid = threadIdx.x;
    const int wid = tid >> 6, lane = tid & 63;
    const int lhi = lane >> 4, llo = lane & 15;
    const int nby = M >> 8;
    const int bid = xcd_swz((int)blockIdx.x, (int)gridDim.x);
    const int by = bid % nby, bx = bid / nby;            // column-major
    const int row0 = by << 8, col0 = bx << 7;
    const int wr = wid >> 2, wc = wid & 3;               // 2M x 4N
    const int wbase = wid << 6;

    auto stage_rows = [&](const bf16* src, int r0, int k0, char* ldsbase, int nit) {
        for (int it = 0; it < nit; ++it) {
            const int p = it * 512 + wbase + lane;
            const int r = p >> 3, pc = p & 7;
            const int lc = pc ^ (r & 7);
            load_lds16(src + (size_t)(r0 + r) * K + k0 + lc * 8,
                       ldsbase + (size_t)(it * 512 + wbase) * 16);
        }
    };
    auto stageA = [&](int t) { stage_rows(A, row0, t << 6, (char*)lA[t & 1], 4); };
    auto stageB = [&](int t) {
        stage_rows(B1T, col0, t << 6, (char*)lB1[t & 1], 2);
        stage_rows(B3T, col0, t << 6, (char*)lB3[t & 1], 2);
    };

    f32x4 acc1[8][2] = {}, acc3[8][2] = {};

    stageA(0); stageB(0);
    wait_vmcnt<0>();
    hard_barrier();

    const int KT = K >> 6;
    for (int t = 0; t < KT; ++t) {
        const bool more = (t + 1 < KT);
        const char* lAc = (const char*)lA[t & 1];
        const char* lB1c = (const char*)lB1[t & 1];
        const char* lB3c = (const char*)lB3[t & 1];

        short8 b1f[2], b3f[2];                           // current-kk B frags
        auto ldA4 = [&](short8 af[4], int mh, int kk) {
#pragma unroll
            for (int m = 0; m < 4; ++m) {
                const int ra = wr * 128 + mh * 64 + m * 16 + llo;
                af[m] = *(const short8*)(lAc + ra * 128 + (((kk * 4 + lhi) ^ (ra & 7)) << 4));
            }
        };
        auto ldBk = [&](int kk) {
#pragma unroll
            for (int n = 0; n < 2; ++n) {
                const int rb = wc * 32 + n * 16 + llo;
                const int so = (((kk * 4 + lhi) ^ (rb & 7)) << 4);
                b1f[n] = *(const short8*)(lB1c + rb * 128 + so);
                b3f[n] = *(const short8*)(lB3c + rb * 128 + so);
            }
        };
        auto mfma_p = [&](short8 af[4], int mh) {
#pragma unroll
            for (int m = 0; m < 4; ++m)
#pragma unroll
                for (int n = 0; n < 2; ++n) {
                    acc1[mh * 4 + m][n] = __builtin_amdgcn_mfma_f32_16x16x32_bf16(af[m], b1f[n], acc1[mh * 4 + m][n], 0, 0, 0);
                    acc3[mh * 4 + m][n] = __builtin_amdgcn_mfma_f32_16x16x32_bf16(af[m], b3f[n], acc3[mh * 4 + m][n], 0, 0, 0);
                }
        };

        short8 af[4];
        // P1: (mh0, kk0); stage A(t+1)
        ldA4(af, 0, 0); ldBk(0);
        if (more) stageA(t + 1);
        phase_pre(); mfma_p(af, 0); phase_post();
        // P2: (mh1, kk0); stage B(t+1)
        ldA4(af, 1, 0);
        if (more) stageB(t + 1);
        phase_pre(); mfma_p(af, 1); phase_post();
        // P3: (mh0, kk1)
        ldA4(af, 0, 1); ldBk(1);
        phase_pre(); mfma_p(af, 0); phase_post();
        // P4: (mh1, kk1)
        ldA4(af, 1, 1);
        phase_pre(); mfma_p(af, 1); phase_post();

        if (more) { wait_vmcnt<0>(); hard_barrier(); }
    }

    // epilogue: silu(c1) * c3, wave-local
#pragma unroll
    for (int m = 0; m < 8; ++m) {
        const int rbase = row0 + wr * 128 + m * 16 + lhi * 4;
#pragma unroll
        for (int n = 0; n < 2; ++n) {
            const int c = col0 + wc * 32 + n * 16 + llo;
#pragma unroll
            for (int r = 0; r < 4; ++r) {
                const size_t idx = (size_t)(rbase + r) * N + c;
                outp[idx] = f2bf(siluf(acc1[m][n][r]) * acc3[m][n][r]);
            }
        }
    }
}

// ---------------- 128x64 bf16 GEMM, counted-vmcnt double-buffer (N=1024 GEMMs) ----------------
// ROW-major block order: A-slab L2-resident; right for K-large/N-small shapes (w2).
__global__ __launch_bounds__(256) void gemm_btc(
    const bf16* __restrict__ A, const bf16* __restrict__ BT,
    float* __restrict__ outp, const float* __restrict__ resid,
    int M, int N, int K)
{
    __shared__ __align__(16) bf16 lA[2][128 * 64];
    __shared__ __align__(16) bf16 lB[2][64 * 64];
    const int tid = threadIdx.x;
    const int wid = tid >> 6, lane = tid & 63;
    const int lhi = lane >> 4, llo = lane & 15;
    const int ntx = N >> 6;
    const int bid = xcd_swz((int)blockIdx.x, (int)gridDim.x);
    const int bx = bid % ntx, by = bid / ntx;            // row-major
    const int row0 = by << 7, col0 = bx << 6;
    const int wr = wid >> 1, wc = wid & 1;               // 2M x 2N
    const int wbase = wid << 6;

    auto stage_tile = [&](const bf16* src, int r0, int k0, char* ldsbase, int nit) {
        for (int it = 0; it < nit; ++it) {
            const int p = it * 256 + wbase + lane;
            const int r = p >> 3, pc = p & 7;
            const int lc = pc ^ (r & 7);
            load_lds16(src + (size_t)(r0 + r) * K + k0 + lc * 8,
                       ldsbase + (size_t)(it * 256 + wbase) * 16);
        }
    };
    auto stageT = [&](int t) {
        stage_tile(A, row0, t << 6, (char*)lA[t & 1], 4);
        stage_tile(BT, col0, t << 6, (char*)lB[t & 1], 2);
    };

    f32x4 acc[4][2] = {};

    stageT(0); stageT(1);
    wait_vmcnt<6>();
    hard_barrier();

    const int KT = K >> 6;
    for (int t = 0; t < KT; ++t) {
        const int buf = t & 1;
        const char* lAc = (const char*)lA[buf];
        const char* lBc = (const char*)lB[buf];

        short8 af[4], bfr[2];
        auto ldA = [&](int kk) {
#pragma unroll
            for (int m = 0; m < 4; ++m) {
                const int ra = wr * 64 + m * 16 + llo;
                af[m] = *(const short8*)(lAc + ra * 128 + (((kk * 4 + lhi) ^ (ra & 7)) << 4));
            }
        };
        auto ldB = [&](int kk) {
#pragma unroll
            for (int n = 0; n < 2; ++n) {
                const int rb = wc * 32 + n * 16 + llo;
                bfr[n] = *(const short8*)(lBc + rb * 128 + (((kk * 4 + lhi) ^ (rb & 7)) << 4));
            }
        };

#pragma unroll
        for (int kk = 0; kk < 2; ++kk) {
            ldA(kk); ldB(kk);
            __builtin_amdgcn_s_setprio(1);
#pragma unroll
            for (int m = 0; m < 4; ++m)
#pragma unroll
                for (int n = 0; n < 2; ++n)
                    acc[m][n] = __builtin_amdgcn_mfma_f32_16x16x32_bf16(af[m], bfr[n], acc[m][n], 0, 0, 0);
            __builtin_amdgcn_s_setprio(0);
        }

        lgkm_barrier();
        if (t + 2 < KT) {
            stageT(t + 2);
            wait_vmcnt<6>();
            hard_barrier();
        } else if (t + 1 < KT) {
            wait_vmcnt<0>();
            hard_barrier();
        }
    }

#pragma unroll
    for (int m = 0; m < 4; ++m) {
        const int rbase = row0 + wr * 64 + m * 16 + lhi * 4;
#pragma unroll
        for (int n = 0; n < 2; ++n) {
            const int c = col0 + wc * 32 + n * 16 + llo;
#pragma unroll
            for (int r = 0; r < 4; ++r) {
                const size_t idx = (size_t)(rbase + r) * N + c;
                outp[idx] = resid[idx] + acc[m][n][r];
            }
        }
    }
}

// ---------------- V transpose: qkuv v-quarter [B][L][H*64] -> v_t [B*H][64][L] ----------------
__global__ __launch_bounds__(256) void v_trans(const bf16* __restrict__ qkuv, bf16* __restrict__ v_t)
{
    __shared__ bf16 t[64][65];
    const int bh = blockIdx.y;         // b*16+h
    const int b = bh >> 4, h = bh & 15;
    const int l0 = blockIdx.x << 6;
    const int tx = threadIdx.x, ty = threadIdx.y;
#pragma unroll
    for (int i = ty; i < 64; i += 4)
        t[i][tx] = qkuv[(size_t)(b * 2048 + l0 + i) * 4096 + 2048 + h * 64 + tx];
    __syncthreads();
#pragma unroll
    for (int i = ty; i < 64; i += 4)
        v_t[(size_t)(bh * 64 + i) * 2048 + l0 + tx] = t[tx][i];
}

// ---------------- fused silu-attention + head-LN*u (KVBLK=128, LPT + XCD-local grid) ----------------
// 512 threads = 8 waves, each wave owns 16 q rows of a 128-row q-tile.
// Grid mapping gets BOTH load balance and KV locality: with round-robin xcd = bid&7,
//   slot = bid>>3; qt = 15 - (slot>>2); bh = (xcd<<2) | (slot&3)
// -> first 32 dispatched blocks are all qt=15 (LPT), and each XCD serves only 4 fixed
//    bh's (KV working set 4 x 512 KB = 2 MB, L2-resident). Bijective by construction.
__global__ __launch_bounds__(512) void attn_kernel(
    const bf16* __restrict__ qkuv, const bf16* __restrict__ v_t,
    const float* __restrict__ nag, const float* __restrict__ nab,
    bf16* __restrict__ au)
{
    __shared__ __align__(16) bf16 lK[2][128 * 64];
    __shared__ __align__(16) bf16 lV[2][64 * 128];
    const int tid = threadIdx.x;
    const int wid = tid >> 6, lane = tid & 63;
    const int lhi = lane >> 4, llo = lane & 15;
    const int bid = (int)blockIdx.x;
    const int xcd = bid & 7, slot = bid >> 3;
    const int qt = 15 - (slot >> 2);                      // heavy blocks dispatched first
    const int bh = (xcd << 2) | (slot & 3);               // 4 bh's per XCD (KV L2-resident)
    const int b = bh >> 4, h = bh & 15;
    const int q0 = qt << 7;
    const bf16* Qb = qkuv + (size_t)b * 2048 * 4096 + h * 64;
    const bf16* Kb = Qb + 1024;
    const bf16* Ub = Qb + 3072;
    const bf16* Vb = v_t + (size_t)bh * 64 * 2048;
    const int wbase = wid << 6;

    auto stage = [&](int kt_s, int buf) {
        const int koff = kt_s << 7;
        char* lKc = (char*)lK[buf];
        char* lVc = (char*)lV[buf];
#pragma unroll
        for (int it = 0; it < 2; ++it) {
            const int p = it * 512 + wbase + lane;
            const int r = p >> 3, pc = p & 7;
            const int lc = pc ^ (r & 7);
            load_lds16(Kb + (size_t)(koff + r) * 4096 + lc * 8, lKc + (it * 512 + wbase) * 16);
        }
#pragma unroll
        for (int it = 0; it < 2; ++it) {
            const int p = it * 512 + wbase + lane;
            const int d = p >> 4, pc = p & 15;
            const int lc = pc ^ (d & 15);
            load_lds16(Vb + (size_t)d * 2048 + koff + lc * 8, lVc + (it * 512 + wbase) * 16);
        }
    };

    // hoist Q B-frags: q = wid*16 + llo, dk = kk*32 + lhi*8
    short8 qb[2];
#pragma unroll
    for (int kk = 0; kk < 2; ++kk)
        qb[kk] = *(const short8*)(Qb + (size_t)(q0 + wid * 16 + llo) * 4096 + kk * 32 + lhi * 8);

    f32x4 acc2[4] = {};

    stage(0, 0);  // prologue prefetch

    for (int kt = 0; kt <= qt; ++kt) {
        const int cur = kt & 1;
        drain_and_sync();                      // staged buf[cur] visible to all waves
        if (kt < qt) stage(kt + 1, cur ^ 1);   // prefetch next tile into other buffer
        const char* lKc = (const char*)lK[cur];
        const char* lVc = (const char*)lV[cur];

        const bool diag = (kt == qt);
#pragma unroll
        for (int m = 0; m < 8; ++m) {
            if (diag && m > wid) break;                    // fully above diagonal
            const int rK = m * 16 + llo;
            const int sw = rK & 7;
            short8 ak0 = *(const short8*)(lKc + rK * 128 + ((lhi ^ sw) << 4));
            short8 ak1 = *(const short8*)(lKc + rK * 128 + (((4 + lhi) ^ sw) << 4));
            f32x4 s = {};
            s = __builtin_amdgcn_mfma_f32_16x16x32_bf16(ak0, qb[0], s, 0, 0, 0);
            s = __builtin_amdgcn_mfma_f32_16x16x32_bf16(ak1, qb[1], s, 0, 0, 0);
            const bool mask = diag && (m == wid);
            bfv4 a16;
#pragma unroll
            for (int r = 0; r < 4; ++r) {
                float xx = s[r] * 0.125f;
                xx = xx * __builtin_amdgcn_rcpf(1.f + __expf(-xx));
                if (mask && (lhi * 4 + r > llo)) xx = 0.f;
                a16[r] = (short)f2bf_bits(xx);
            }
#pragma unroll
            for (int dcol = 0; dcol < 4; ++dcol) {
                const int d = dcol * 16 + llo;
                const int lcV = m * 2 + (lhi >> 1);
                bfv4 bv = *(const bfv4*)(lVc + d * 256 + ((lcV ^ llo) << 4) + (lhi & 1) * 8);
                acc2[dcol] = mfma16(a16, bv, acc2[dcol]);
            }
        }
    }

    // ---- epilogue: LN(d=64) * u ----
#pragma unroll
    for (int r = 0; r < 4; ++r) {
        float vv[4];
        float s = 0.f, ss = 0.f;
#pragma unroll
        for (int dc = 0; dc < 4; ++dc) { vv[dc] = acc2[dc][r]; s += vv[dc]; ss += vv[dc] * vv[dc]; }
#pragma unroll
        for (int o = 1; o < 16; o <<= 1) { s += __shfl_xor(s, o); ss += __shfl_xor(ss, o); }
        const float mu = s * (1.f / 64.f);
        const float rstd = rsqrtf(ss * (1.f / 64.f) - mu * mu + LN_EPS);
        const int q = wid * 16 + lhi * 4 + r;
        const size_t grow = q0 + q;
#pragma unroll
        for (int dc = 0; dc < 4; ++dc) {
            const int c = dc * 16 + llo;
            const float nv = (vv[dc] - mu) * rstd * nag[c] + nab[c];
            const float uu = bf2f(Ub[grow * 4096 + c]);
            au[(size_t)(b * 2048 + grow) * 1024 + h * 64 + c] = f2bf(nv * uu);
        }
    }
}

// ---------------- host launch ----------------
extern "C" void kernel_launch(void* const* d_in, const int* in_sizes, int n_in,
                              void* d_out, int out_size, void* d_ws, size_t ws_size,
                              hipStream_t stream)
{
    const float* x      = (const float*)d_in[0];
    // d_in[1] = attn_mask (tril causal; applied analytically)
    const float* w_qkuv = (const float*)d_in[2];
    const float* w_out  = (const float*)d_in[3];
    const float* w1     = (const float*)d_in[4];
    const float* w2     = (const float*)d_in[5];
    const float* w3     = (const float*)d_in[6];
    const float* ln1g   = (const float*)d_in[7];
    const float* ln1b   = (const float*)d_in[8];
    const float* ln2g   = (const float*)d_in[9];
    const float* ln2b   = (const float*)d_in[10];
    const float* nag    = (const float*)d_in[11];
    const float* nab    = (const float*)d_in[12];
    float* out = (float*)d_out;

    char* ws = (char*)d_ws;
    size_t off = 0;
    auto alloc = [&](size_t bytes) { void* p = ws + off; off += (bytes + 255) & ~(size_t)255; return p; };
    const size_t M = 4096;  // B*L
    bf16* wqkuvT = (bf16*)alloc(4096ull * 1024 * 2);
    bf16* woutT  = (bf16*)alloc(1024ull * 1024 * 2);
    bf16* w1T    = (bf16*)alloc(4096ull * 1024 * 2);
    bf16* w3T    = (bf16*)alloc(4096ull * 1024 * 2);
    bf16* w2T    = (bf16*)alloc(1024ull * 4096 * 2);
    bf16* xn     = (bf16*)alloc(M * 1024 * 2);
    bf16* qkuv   = (bf16*)alloc(M * 4096 * 2);
    bf16* vt     = (bf16*)alloc(32ull * 64 * 2048 * 2);
    bf16* aub    = (bf16*)alloc(M * 1024 * 2);
    float* x2    = (float*)alloc(M * 1024 * 4);
    bf16* xn2    = (bf16*)alloc(M * 1024 * 2);
    bf16* h1     = (bf16*)alloc(M * 4096 * 2);
    (void)ws_size; (void)in_sizes; (void)n_in; (void)out_size;

    dim3 tb(32, 8);
    transpose_cast3<<<dim3(4096 / 32, 1024 / 32, 3), tb, 0, stream>>>(w_qkuv, w1, w3, wqkuvT, w1T, w3T);
    transpose_cast<<<dim3(1024 / 32, 1024 / 32), tb, 0, stream>>>(w_out, woutT, 1024, 1024);
    transpose_cast<<<dim3(1024 / 32, 4096 / 32), tb, 0, stream>>>(w2, w2T, 4096, 1024);

    ln_cast<<<M, 256, 0, stream>>>(x, ln1g, ln1b, xn);

    gemm8<0><<<dim3((M / 256) * (4096 / 256)), 512, 0, stream>>>(xn, wqkuvT, qkuv, nullptr, M, 4096, 1024);

    v_trans<<<dim3(2048 / 64, 32), dim3(64, 4), 0, stream>>>(qkuv, vt);

    attn_kernel<<<dim3(512), 512, 0, stream>>>(qkuv, vt, nag, nab, aub);

    gemm_btc<<<dim3((M / 128) * (1024 / 64)), 256, 0, stream>>>(aub, woutT, x2, x, M, 1024, 1024);

    ln_cast<<<M, 256, 0, stream>>>(x2, ln2g, ln2b, xn2);

    gemm_w13_8<<<dim3((M / 256) * (4096 / 128)), 512, 0, stream>>>(xn2, w1T, w3T, h1, M, 4096, 1024);

    gemm_btc<<<dim3((M / 128) * (1024 / 64)), 256, 0, stream>>>(h1, w2T, out, x2, M, 1024, 4096);
}

// Round 20
// 280.871 us; speedup vs baseline: 1.0329x; 1.0105x over previous
//
#include <hip/hip_runtime.h>
#include <hip/hip_bf16.h>

typedef __hip_bfloat16 bf16;
typedef __attribute__((ext_vector_type(8))) short short8;
typedef __attribute__((ext_vector_type(4))) short bfv4;
typedef __attribute__((ext_vector_type(4))) float f32x4;
typedef __attribute__((ext_vector_type(4))) unsigned short us4;

#define LN_EPS 1e-5f

__device__ __forceinline__ float siluf(float x) { return x / (1.f + __expf(-x)); }
__device__ __forceinline__ unsigned short f2bf_bits(float f) {
    bf16 h = __float2bfloat16(f);
    return *reinterpret_cast<unsigned short*>(&h);
}
__device__ __forceinline__ bf16 f2bf(float f) { return __float2bfloat16(f); }
__device__ __forceinline__ float bf2f(bf16 h) { return __bfloat162float(h); }

// async global->LDS, 16B per lane. LDS dest must be wave-uniform base (+lane*16 implicit).
__device__ __forceinline__ void load_lds16(const void* g, void* l) {
    __builtin_amdgcn_global_load_lds((const __attribute__((address_space(1))) void*)g,
                                     (__attribute__((address_space(3))) void*)l, 16, 0, 0);
}

__device__ __forceinline__ f32x4 mfma16(bfv4 a, bfv4 b, f32x4 c) {
    return __builtin_amdgcn_mfma_f32_16x16x16bf16_1k(a, b, c, 0, 0, 0);
}

// explicit RAW drain for global_load_lds before a barrier (rule-#18 class hazard)
__device__ __forceinline__ void drain_and_sync() {
    asm volatile("s_waitcnt vmcnt(0)" ::: "memory");
    __builtin_amdgcn_sched_barrier(0);
    __syncthreads();
}

// counted vmcnt wait (literal), fenced
template <int N>
__device__ __forceinline__ void wait_vmcnt() {
    asm volatile("s_waitcnt vmcnt(%0)" :: "n"(N) : "memory");
}
__device__ __forceinline__ void hard_barrier() {
    __builtin_amdgcn_sched_barrier(0);
    __builtin_amdgcn_s_barrier();
    __builtin_amdgcn_sched_barrier(0);
}
// barrier preceded by lgkmcnt(0): all this wave's ds_reads complete before crossing (WAR safety)
__device__ __forceinline__ void lgkm_barrier() {
    asm volatile("s_waitcnt lgkmcnt(0)" ::: "memory");
    __builtin_amdgcn_sched_barrier(0);
    __builtin_amdgcn_s_barrier();
    __builtin_amdgcn_sched_barrier(0);
}

// fine-phase sync: rendezvous, then wait own ds_reads, then high-prio MFMA
__device__ __forceinline__ void phase_pre() {
    __builtin_amdgcn_sched_barrier(0);
    __builtin_amdgcn_s_barrier();
    asm volatile("s_waitcnt lgkmcnt(0)" ::: "memory");
    __builtin_amdgcn_sched_barrier(0);
    __builtin_amdgcn_s_setprio(1);
}
__device__ __forceinline__ void phase_post() {
    __builtin_amdgcn_s_setprio(0);
    __builtin_amdgcn_sched_barrier(0);
    __builtin_amdgcn_s_barrier();
    __builtin_amdgcn_sched_barrier(0);
}

// XCD-chunked bijective block swizzle (requires nwg % 8 == 0)
__device__ __forceinline__ int xcd_swz(int bid, int nwg) {
    return (bid & 7) * (nwg >> 3) + (bid >> 3);
}

// ---------------- weight transpose+cast: fp32 [K][N] -> bf16 [N][K] ----------------
__global__ __launch_bounds__(256) void transpose_cast(
    const float* __restrict__ src, bf16* __restrict__ dst, int K, int N)
{
    __shared__ float t[32][33];
    const int nb = blockIdx.x << 5, kb = blockIdx.y << 5;
    const int tx = threadIdx.x, ty = threadIdx.y;
#pragma unroll
    for (int i = ty; i < 32; i += 8) t[i][tx] = src[(size_t)(kb + i) * N + nb + tx];
    __syncthreads();
#pragma unroll
    for (int i = ty; i < 32; i += 8) dst[(size_t)(nb + i) * K + kb + tx] = f2bf(t[tx][i]);
}

// three 1024x4096 weight transposes in one launch (z selects tensor)
__global__ __launch_bounds__(256) void transpose_cast3(
    const float* __restrict__ s0, const float* __restrict__ s1, const float* __restrict__ s2,
    bf16* __restrict__ d0, bf16* __restrict__ d1, bf16* __restrict__ d2)
{
    const float* src = (blockIdx.z == 0) ? s0 : (blockIdx.z == 1) ? s1 : s2;
    bf16* dst = (blockIdx.z == 0) ? d0 : (blockIdx.z == 1) ? d1 : d2;
    const int K = 1024, N = 4096;
    __shared__ float t[32][33];
    const int nb = blockIdx.x << 5, kb = blockIdx.y << 5;
    const int tx = threadIdx.x, ty = threadIdx.y;
#pragma unroll
    for (int i = ty; i < 32; i += 8) t[i][tx] = src[(size_t)(kb + i) * N + nb + tx];
    __syncthreads();
#pragma unroll
    for (int i = ty; i < 32; i += 8) dst[(size_t)(nb + i) * K + kb + tx] = f2bf(t[tx][i]);
}

// ---------------- LayerNorm fp32 row (D=1024) -> bf16 ----------------
__global__ __launch_bounds__(256) void ln_cast(
    const float* __restrict__ x, const float* __restrict__ g, const float* __restrict__ be,
    bf16* __restrict__ out)
{
    const int row = blockIdx.x, tid = threadIdx.x;
    const float4 v = ((const float4*)(x + (size_t)row * 1024))[tid];
    float s = v.x + v.y + v.z + v.w;
    float ss = v.x * v.x + v.y * v.y + v.z * v.z + v.w * v.w;
#pragma unroll
    for (int o = 32; o; o >>= 1) { s += __shfl_down(s, o); ss += __shfl_down(ss, o); }
    __shared__ float red[10];
    const int wid = tid >> 6, lane = tid & 63;
    if (lane == 0) { red[wid] = s; red[4 + wid] = ss; }
    __syncthreads();
    if (tid == 0) {
        float S = red[0] + red[1] + red[2] + red[3];
        float SS = red[4] + red[5] + red[6] + red[7];
        float mu = S * (1.f / 1024.f);
        red[8] = mu;
        red[9] = rsqrtf(SS * (1.f / 1024.f) - mu * mu + LN_EPS);
    }
    __syncthreads();
    const float mu = red[8], rstd = red[9];
    const float4 gg = ((const float4*)g)[tid];
    const float4 bb = ((const float4*)be)[tid];
    us4 o;
    o[0] = f2bf_bits((v.x - mu) * rstd * gg.x + bb.x);
    o[1] = f2bf_bits((v.y - mu) * rstd * gg.y + bb.y);
    o[2] = f2bf_bits((v.z - mu) * rstd * gg.z + bb.z);
    o[3] = f2bf_bits((v.w - mu) * rstd * gg.w + bb.w);
    ((us4*)(out + (size_t)row * 1024))[tid] = o;
}

// ---------------- 256x256 bf16 GEMM, 4-phase fine interleave, distance-1 dbuf ----------------
// Column-major block order (B-panels L2-resident; A reused across bx).
// EPI: 0 = bf16 silu(acc)
template <int EPI>
__global__ __launch_bounds__(512, 2) void gemm8(
    const bf16* __restrict__ A, const bf16* __restrict__ BT,
    bf16* __restrict__ outp, const bf16* __restrict__ mulsrc,
    int M, int N, int K)
{
    __shared__ __align__(16) bf16 lds[2][2][256 * 64];   // [buf][A=0/B=1][row*64+col]
    const int tid = threadIdx.x;
    const int wid = tid >> 6, lane = tid & 63;
    const int lhi = lane >> 4, llo = lane & 15;
    const int nby = M >> 8;
    const int bid = xcd_swz((int)blockIdx.x, (int)gridDim.x);
    const int by = bid % nby, bx = bid / nby;            // column-major
    const int row0 = by << 8, col0 = bx << 8;
    const int wr = wid >> 2, wc = wid & 3;               // 2M x 4N
    const int wbase = wid << 6;

    auto stage_tile = [&](const bf16* src, int r0, int k0, char* ldsbase) {
#pragma unroll
        for (int it = 0; it < 4; ++it) {
            const int p = it * 512 + wbase + lane;       // physical 16B-chunk index
            const int r = p >> 3, pc = p & 7;
            const int lc = pc ^ (r & 7);                 // logical chunk this slot holds
            load_lds16(src + (size_t)(r0 + r) * K + k0 + lc * 8,
                       ldsbase + (size_t)(it * 512 + wbase) * 16);
        }
    };
    auto stageA = [&](int t) { stage_tile(A, row0, t << 6, (char*)lds[t & 1][0]); };
    auto stageB = [&](int t) { stage_tile(BT, col0, t << 6, (char*)lds[t & 1][1]); };

    f32x4 acc[8][4] = {};

    // prologue: T0 only
    stageA(0); stageB(0);
    wait_vmcnt<0>();
    hard_barrier();

    const int KT = K >> 6;
    for (int t = 0; t < KT; ++t) {
        const bool more = (t + 1 < KT);
        const char* lAc = (const char*)lds[t & 1][0];
        const char* lBc = (const char*)lds[t & 1][1];

        short8 a0[2][4], a1[2][4], b0[2][2], b1[2][2];   // [kk][frag]
        auto ldA = [&](short8 af[2][4], int mh) {
#pragma unroll
            for (int kk = 0; kk < 2; ++kk)
#pragma unroll
                for (int m = 0; m < 4; ++m) {
                    const int ra = wr * 128 + mh * 64 + m * 16 + llo;
                    af[kk][m] = *(const short8*)(lAc + ra * 128 + (((kk * 4 + lhi) ^ (ra & 7)) << 4));
                }
        };
        auto ldB = [&](short8 bf_[2][2], int nh) {
#pragma unroll
            for (int kk = 0; kk < 2; ++kk)
#pragma unroll
                for (int n = 0; n < 2; ++n) {
                    const int rb = wc * 64 + nh * 32 + n * 16 + llo;
                    bf_[kk][n] = *(const short8*)(lBc + rb * 128 + (((kk * 4 + lhi) ^ (rb & 7)) << 4));
                }
        };
        auto mfma_q = [&](int mh, int nh, short8 af[2][4], short8 bf_[2][2]) {
#pragma unroll
            for (int kk = 0; kk < 2; ++kk)
#pragma unroll
                for (int m = 0; m < 4; ++m)
#pragma unroll
                    for (int n = 0; n < 2; ++n)
                        acc[mh * 4 + m][nh * 2 + n] =
                            __builtin_amdgcn_mfma_f32_16x16x32_bf16(af[kk][m], bf_[kk][n], acc[mh * 4 + m][nh * 2 + n], 0, 0, 0);
        };

        // P1: quadrant (0,0); stage A(t+1)
        ldA(a0, 0); ldB(b0, 0);
        if (more) stageA(t + 1);
        phase_pre(); mfma_q(0, 0, a0, b0); phase_post();
        // P2: quadrant (0,1); stage B(t+1)
        ldB(b1, 1);
        if (more) stageB(t + 1);
        phase_pre(); mfma_q(0, 1, a0, b1); phase_post();
        // P3: quadrant (1,1)
        ldA(a1, 1);
        phase_pre(); mfma_q(1, 1, a1, b1); phase_post();
        // P4: quadrant (1,0)
        phase_pre(); mfma_q(1, 0, a1, b0); phase_post();

        if (more) { wait_vmcnt<0>(); hard_barrier(); }   // T_{t+1} landed (loads >=2 phases old)
    }

#pragma unroll
    for (int m = 0; m < 8; ++m) {
        const int rbase = row0 + wr * 128 + m * 16 + lhi * 4;
#pragma unroll
        for (int n = 0; n < 4; ++n) {
            const int c = col0 + wc * 64 + n * 16 + llo;
#pragma unroll
            for (int r = 0; r < 4; ++r) {
                const size_t idx = (size_t)(rbase + r) * N + c;
                const float v = acc[m][n][r];
                if constexpr (EPI == 0) outp[idx] = f2bf(siluf(v));
                else                    outp[idx] = f2bf(v * bf2f(mulsrc[idx]));
            }
        }
    }
}

// ---------------- fused FFN: h1 = silu(A@W1) * (A@W3), 4-phase fine interleave ----------------
// Column-major block order: B1+B3 panels (2 MB) L2-resident.
__global__ __launch_bounds__(512, 2) void gemm_w13_8(
    const bf16* __restrict__ A, const bf16* __restrict__ B1T, const bf16* __restrict__ B3T,
    bf16* __restrict__ outp, int M, int N, int K)
{
    __shared__ __align__(16) bf16 lA[2][256 * 64];
    __shared__ __align__(16) bf16 lB1[2][128 * 64];
    __shared__ __align__(16) bf16 lB3[2][128 * 64];
    const int tid = threadIdx.x;
    const int wid = tid >> 6, lane = tid & 63;
    const int lhi = lane >> 4, llo = lane & 15;
    const int nby = M >> 8;
    const int bid = xcd_swz((int)blockIdx.x, (int)gridDim.x);
    const int by = bid % nby, bx = bid / nby;            // column-major
    const int row0 = by << 8, col0 = bx << 7;
    const int wr = wid >> 2, wc = wid & 3;               // 2M x 4N
    const int wbase = wid << 6;

    auto stage_rows = [&](const bf16* src, int r0, int k0, char* ldsbase, int nit) {
        for (int it = 0; it < nit; ++it) {
            const int p = it * 512 + wbase + lane;
            const int r = p >> 3, pc = p & 7;
            const int lc = pc ^ (r & 7);
            load_lds16(src + (size_t)(r0 + r) * K + k0 + lc * 8,
                       ldsbase + (size_t)(it * 512 + wbase) * 16);
        }
    };
    auto stageA = [&](int t) { stage_rows(A, row0, t << 6, (char*)lA[t & 1], 4); };
    auto stageB = [&](int t) {
        stage_rows(B1T, col0, t << 6, (char*)lB1[t & 1], 2);
        stage_rows(B3T, col0, t << 6, (char*)lB3[t & 1], 2);
    };

    f32x4 acc1[8][2] = {}, acc3[8][2] = {};

    stageA(0); stageB(0);
    wait_vmcnt<0>();
    hard_barrier();

    const int KT = K >> 6;
    for (int t = 0; t < KT; ++t) {
        const bool more = (t + 1 < KT);
        const char* lAc = (const char*)lA[t & 1];
        const char* lB1c = (const char*)lB1[t & 1];
        const char* lB3c = (const char*)lB3[t & 1];

        short8 b1f[2], b3f[2];                           // current-kk B frags
        auto ldA4 = [&](short8 af[4], int mh, int kk) {
#pragma unroll
            for (int m = 0; m < 4; ++m) {
                const int ra = wr * 128 + mh * 64 + m * 16 + llo;
                af[m] = *(const short8*)(lAc + ra * 128 + (((kk * 4 + lhi) ^ (ra & 7)) << 4));
            }
        };
        auto ldBk = [&](int kk) {
#pragma unroll
            for (int n = 0; n < 2; ++n) {
                const int rb = wc * 32 + n * 16 + llo;
                const int so = (((kk * 4 + lhi) ^ (rb & 7)) << 4);
                b1f[n] = *(const short8*)(lB1c + rb * 128 + so);
                b3f[n] = *(const short8*)(lB3c + rb * 128 + so);
            }
        };
        auto mfma_p = [&](short8 af[4], int mh) {
#pragma unroll
            for (int m = 0; m < 4; ++m)
#pragma unroll
                for (int n = 0; n < 2; ++n) {
                    acc1[mh * 4 + m][n] = __builtin_amdgcn_mfma_f32_16x16x32_bf16(af[m], b1f[n], acc1[mh * 4 + m][n], 0, 0, 0);
                    acc3[mh * 4 + m][n] = __builtin_amdgcn_mfma_f32_16x16x32_bf16(af[m], b3f[n], acc3[mh * 4 + m][n], 0, 0, 0);
                }
        };

        short8 af[4];
        // P1: (mh0, kk0); stage A(t+1)
        ldA4(af, 0, 0); ldBk(0);
        if (more) stageA(t + 1);
        phase_pre(); mfma_p(af, 0); phase_post();
        // P2: (mh1, kk0); stage B(t+1)
        ldA4(af, 1, 0);
        if (more) stageB(t + 1);
        phase_pre(); mfma_p(af, 1); phase_post();
        // P3: (mh0, kk1)
        ldA4(af, 0, 1); ldBk(1);
        phase_pre(); mfma_p(af, 0); phase_post();
        // P4: (mh1, kk1)
        ldA4(af, 1, 1);
        phase_pre(); mfma_p(af, 1); phase_post();

        if (more) { wait_vmcnt<0>(); hard_barrier(); }
    }

    // epilogue: silu(c1) * c3, wave-local
#pragma unroll
    for (int m = 0; m < 8; ++m) {
        const int rbase = row0 + wr * 128 + m * 16 + lhi * 4;
#pragma unroll
        for (int n = 0; n < 2; ++n) {
            const int c = col0 + wc * 32 + n * 16 + llo;
#pragma unroll
            for (int r = 0; r < 4; ++r) {
                const size_t idx = (size_t)(rbase + r) * N + c;
                outp[idx] = f2bf(siluf(acc1[m][n][r]) * acc3[m][n][r]);
            }
        }
    }
}

// ---------------- 128x64 bf16 GEMM, counted-vmcnt double-buffer (N=1024 GEMMs) ----------------
// ROW-major block order: A-slab L2-resident; right for K-large/N-small shapes (w2).
__global__ __launch_bounds__(256) void gemm_btc(
    const bf16* __restrict__ A, const bf16* __restrict__ BT,
    float* __restrict__ outp, const float* __restrict__ resid,
    int M, int N, int K)
{
    __shared__ __align__(16) bf16 lA[2][128 * 64];
    __shared__ __align__(16) bf16 lB[2][64 * 64];
    const int tid = threadIdx.x;
    const int wid = tid >> 6, lane = tid & 63;
    const int lhi = lane >> 4, llo = lane & 15;
    const int ntx = N >> 6;
    const int bid = xcd_swz((int)blockIdx.x, (int)gridDim.x);
    const int bx = bid % ntx, by = bid / ntx;            // row-major
    const int row0 = by << 7, col0 = bx << 6;
    const int wr = wid >> 1, wc = wid & 1;               // 2M x 2N
    const int wbase = wid << 6;

    auto stage_tile = [&](const bf16* src, int r0, int k0, char* ldsbase, int nit) {
        for (int it = 0; it < nit; ++it) {
            const int p = it * 256 + wbase + lane;
            const int r = p >> 3, pc = p & 7;
            const int lc = pc ^ (r & 7);
            load_lds16(src + (size_t)(r0 + r) * K + k0 + lc * 8,
                       ldsbase + (size_t)(it * 256 + wbase) * 16);
        }
    };
    auto stageT = [&](int t) {
        stage_tile(A, row0, t << 6, (char*)lA[t & 1], 4);
        stage_tile(BT, col0, t << 6, (char*)lB[t & 1], 2);
    };

    f32x4 acc[4][2] = {};

    stageT(0); stageT(1);
    wait_vmcnt<6>();
    hard_barrier();

    const int KT = K >> 6;
    for (int t = 0; t < KT; ++t) {
        const int buf = t & 1;
        const char* lAc = (const char*)lA[buf];
        const char* lBc = (const char*)lB[buf];

        short8 af[4], bfr[2];
        auto ldA = [&](int kk) {
#pragma unroll
            for (int m = 0; m < 4; ++m) {
                const int ra = wr * 64 + m * 16 + llo;
                af[m] = *(const short8*)(lAc + ra * 128 + (((kk * 4 + lhi) ^ (ra & 7)) << 4));
            }
        };
        auto ldB = [&](int kk) {
#pragma unroll
            for (int n = 0; n < 2; ++n) {
                const int rb = wc * 32 + n * 16 + llo;
                bfr[n] = *(const short8*)(lBc + rb * 128 + (((kk * 4 + lhi) ^ (rb & 7)) << 4));
            }
        };

#pragma unroll
        for (int kk = 0; kk < 2; ++kk) {
            ldA(kk); ldB(kk);
            __builtin_amdgcn_s_setprio(1);
#pragma unroll
            for (int m = 0; m < 4; ++m)
#pragma unroll
                for (int n = 0; n < 2; ++n)
                    acc[m][n] = __builtin_amdgcn_mfma_f32_16x16x32_bf16(af[m], bfr[n], acc[m][n], 0, 0, 0);
            __builtin_amdgcn_s_setprio(0);
        }

        lgkm_barrier();
        if (t + 2 < KT) {
            stageT(t + 2);
            wait_vmcnt<6>();
            hard_barrier();
        } else if (t + 1 < KT) {
            wait_vmcnt<0>();
            hard_barrier();
        }
    }

#pragma unroll
    for (int m = 0; m < 4; ++m) {
        const int rbase = row0 + wr * 64 + m * 16 + lhi * 4;
#pragma unroll
        for (int n = 0; n < 2; ++n) {
            const int c = col0 + wc * 32 + n * 16 + llo;
#pragma unroll
            for (int r = 0; r < 4; ++r) {
                const size_t idx = (size_t)(rbase + r) * N + c;
                outp[idx] = resid[idx] + acc[m][n][r];
            }
        }
    }
}

// ---------------- V transpose: qkuv v-quarter [B][L][H*64] -> v_t [B*H][64][L] ----------------
__global__ __launch_bounds__(256) void v_trans(const bf16* __restrict__ qkuv, bf16* __restrict__ v_t)
{
    __shared__ bf16 t[64][65];
    const int bh = blockIdx.y;         // b*16+h
    const int b = bh >> 4, h = bh & 15;
    const int l0 = blockIdx.x << 6;
    const int tx = threadIdx.x, ty = threadIdx.y;
#pragma unroll
    for (int i = ty; i < 64; i += 4)
        t[i][tx] = qkuv[(size_t)(b * 2048 + l0 + i) * 4096 + 2048 + h * 64 + tx];
    __syncthreads();
#pragma unroll
    for (int i = ty; i < 64; i += 4)
        v_t[(size_t)(bh * 64 + i) * 2048 + l0 + tx] = t[tx][i];
}

// ---------------- fused silu-attention + head-LN*u (KVBLK=128, LPT grid) ----------------
// 512 threads = 8 waves, each wave owns 16 q rows of a 128-row q-tile.
// LPT dispatch: qt = 15 - (bid>>5), bh = bid&31 -> heavy blocks dispatched first.
__global__ __launch_bounds__(512) void attn_kernel(
    const bf16* __restrict__ qkuv, const bf16* __restrict__ v_t,
    const float* __restrict__ nag, const float* __restrict__ nab,
    bf16* __restrict__ au)
{
    __shared__ __align__(16) bf16 lK[2][128 * 64];
    __shared__ __align__(16) bf16 lV[2][64 * 128];
    const int tid = threadIdx.x;
    const int wid = tid >> 6, lane = tid & 63;
    const int lhi = lane >> 4, llo = lane & 15;
    const int bid = (int)blockIdx.x;
    const int qt = 15 - (bid >> 5);                       // heavy blocks dispatched first
    const int bh = bid & 31;
    const int b = bh >> 4, h = bh & 15;
    const int q0 = qt << 7;
    const bf16* Qb = qkuv + (size_t)b * 2048 * 4096 + h * 64;
    const bf16* Kb = Qb + 1024;
    const bf16* Ub = Qb + 3072;
    const bf16* Vb = v_t + (size_t)bh * 64 * 2048;
    const int wbase = wid << 6;

    auto stage = [&](int kt_s, int buf) {
        const int koff = kt_s << 7;
        char* lKc = (char*)lK[buf];
        char* lVc = (char*)lV[buf];
#pragma unroll
        for (int it = 0; it < 2; ++it) {
            const int p = it * 512 + wbase + lane;
            const int r = p >> 3, pc = p & 7;
            const int lc = pc ^ (r & 7);
            load_lds16(Kb + (size_t)(koff + r) * 4096 + lc * 8, lKc + (it * 512 + wbase) * 16);
        }
#pragma unroll
        for (int it = 0; it < 2; ++it) {
            const int p = it * 512 + wbase + lane;
            const int d = p >> 4, pc = p & 15;
            const int lc = pc ^ (d & 15);
            load_lds16(Vb + (size_t)d * 2048 + koff + lc * 8, lVc + (it * 512 + wbase) * 16);
        }
    };

    // hoist Q B-frags: q = wid*16 + llo, dk = kk*32 + lhi*8
    short8 qb[2];
#pragma unroll
    for (int kk = 0; kk < 2; ++kk)
        qb[kk] = *(const short8*)(Qb + (size_t)(q0 + wid * 16 + llo) * 4096 + kk * 32 + lhi * 8);

    f32x4 acc2[4] = {};

    stage(0, 0);  // prologue prefetch

    for (int kt = 0; kt <= qt; ++kt) {
        const int cur = kt & 1;
        drain_and_sync();                      // staged buf[cur] visible to all waves
        if (kt < qt) stage(kt + 1, cur ^ 1);   // prefetch next tile into other buffer
        const char* lKc = (const char*)lK[cur];
        const char* lVc = (const char*)lV[cur];

        const bool diag = (kt == qt);
#pragma unroll
        for (int m = 0; m < 8; ++m) {
            if (diag && m > wid) break;                    // fully above diagonal
            const int rK = m * 16 + llo;
            const int sw = rK & 7;
            short8 ak0 = *(const short8*)(lKc + rK * 128 + ((lhi ^ sw) << 4));
            short8 ak1 = *(const short8*)(lKc + rK * 128 + (((4 + lhi) ^ sw) << 4));
            f32x4 s = {};
            s = __builtin_amdgcn_mfma_f32_16x16x32_bf16(ak0, qb[0], s, 0, 0, 0);
            s = __builtin_amdgcn_mfma_f32_16x16x32_bf16(ak1, qb[1], s, 0, 0, 0);
            const bool mask = diag && (m == wid);
            bfv4 a16;
#pragma unroll
            for (int r = 0; r < 4; ++r) {
                float xx = s[r] * 0.125f;
                xx = xx * __builtin_amdgcn_rcpf(1.f + __expf(-xx));
                if (mask && (lhi * 4 + r > llo)) xx = 0.f;
                a16[r] = (short)f2bf_bits(xx);
            }
#pragma unroll
            for (int dcol = 0; dcol < 4; ++dcol) {
                const int d = dcol * 16 + llo;
                const int lcV = m * 2 + (lhi >> 1);
                bfv4 bv = *(const bfv4*)(lVc + d * 256 + ((lcV ^ llo) << 4) + (lhi & 1) * 8);
                acc2[dcol] = mfma16(a16, bv, acc2[dcol]);
            }
        }
    }

    // ---- epilogue: LN(d=64) * u ----
#pragma unroll
    for (int r = 0; r < 4; ++r) {
        float vv[4];
        float s = 0.f, ss = 0.f;
#pragma unroll
        for (int dc = 0; dc < 4; ++dc) { vv[dc] = acc2[dc][r]; s += vv[dc]; ss += vv[dc] * vv[dc]; }
#pragma unroll
        for (int o = 1; o < 16; o <<= 1) { s += __shfl_xor(s, o); ss += __shfl_xor(ss, o); }
        const float mu = s * (1.f / 64.f);
        const float rstd = rsqrtf(ss * (1.f / 64.f) - mu * mu + LN_EPS);
        const int q = wid * 16 + lhi * 4 + r;
        const size_t grow = q0 + q;
#pragma unroll
        for (int dc = 0; dc < 4; ++dc) {
            const int c = dc * 16 + llo;
            const float nv = (vv[dc] - mu) * rstd * nag[c] + nab[c];
            const float uu = bf2f(Ub[grow * 4096 + c]);
            au[(size_t)(b * 2048 + grow) * 1024 + h * 64 + c] = f2bf(nv * uu);
        }
    }
}

// ---------------- host launch ----------------
extern "C" void kernel_launch(void* const* d_in, const int* in_sizes, int n_in,
                              void* d_out, int out_size, void* d_ws, size_t ws_size,
                              hipStream_t stream)
{
    const float* x      = (const float*)d_in[0];
    // d_in[1] = attn_mask (tril causal; applied analytically)
    const float* w_qkuv = (const float*)d_in[2];
    const float* w_out  = (const float*)d_in[3];
    const float* w1     = (const float*)d_in[4];
    const float* w2     = (const float*)d_in[5];
    const float* w3     = (const float*)d_in[6];
    const float* ln1g   = (const float*)d_in[7];
    const float* ln1b   = (const float*)d_in[8];
    const float* ln2g   = (const float*)d_in[9];
    const float* ln2b   = (const float*)d_in[10];
    const float* nag    = (const float*)d_in[11];
    const float* nab    = (const float*)d_in[12];
    float* out = (float*)d_out;

    char* ws = (char*)d_ws;
    size_t off = 0;
    auto alloc = [&](size_t bytes) { void* p = ws + off; off += (bytes + 255) & ~(size_t)255; return p; };
    const size_t M = 4096;  // B*L
    bf16* wqkuvT = (bf16*)alloc(4096ull * 1024 * 2);
    bf16* woutT  = (bf16*)alloc(1024ull * 1024 * 2);
    bf16* w1T    = (bf16*)alloc(4096ull * 1024 * 2);
    bf16* w3T    = (bf16*)alloc(4096ull * 1024 * 2);
    bf16* w2T    = (bf16*)alloc(1024ull * 4096 * 2);
    bf16* xn     = (bf16*)alloc(M * 1024 * 2);
    bf16* qkuv   = (bf16*)alloc(M * 4096 * 2);
    bf16* vt     = (bf16*)alloc(32ull * 64 * 2048 * 2);
    bf16* aub    = (bf16*)alloc(M * 1024 * 2);
    float* x2    = (float*)alloc(M * 1024 * 4);
    bf16* xn2    = (bf16*)alloc(M * 1024 * 2);
    bf16* h1     = (bf16*)alloc(M * 4096 * 2);
    (void)ws_size; (void)in_sizes; (void)n_in; (void)out_size;

    dim3 tb(32, 8);
    transpose_cast3<<<dim3(4096 / 32, 1024 / 32, 3), tb, 0, stream>>>(w_qkuv, w1, w3, wqkuvT, w1T, w3T);
    transpose_cast<<<dim3(1024 / 32, 1024 / 32), tb, 0, stream>>>(w_out, woutT, 1024, 1024);
    transpose_cast<<<dim3(1024 / 32, 4096 / 32), tb, 0, stream>>>(w2, w2T, 4096, 1024);

    ln_cast<<<M, 256, 0, stream>>>(x, ln1g, ln1b, xn);

    gemm8<0><<<dim3((M / 256) * (4096 / 256)), 512, 0, stream>>>(xn, wqkuvT, qkuv, nullptr, M, 4096, 1024);

    v_trans<<<dim3(2048 / 64, 32), dim3(64, 4), 0, stream>>>(qkuv, vt);

    attn_kernel<<<dim3(512), 512, 0, stream>>>(qkuv, vt, nag, nab, aub);

    gemm_btc<<<dim3((M / 128) * (1024 / 64)), 256, 0, stream>>>(aub, woutT, x2, x, M, 1024, 1024);

    ln_cast<<<M, 256, 0, stream>>>(x2, ln2g, ln2b, xn2);

    gemm_w13_8<<<dim3((M / 256) * (4096 / 128)), 512, 0, stream>>>(xn2, w1T, w3T, h1, M, 4096, 1024);

    gemm_btc<<<dim3((M / 128) * (1024 / 64)), 256, 0, stream>>>(h1, w2T, out, x2, M, 1024, 4096);
}

// Round 21
// 276.693 us; speedup vs baseline: 1.0485x; 1.0151x over previous
//
#include <hip/hip_runtime.h>
#include <hip/hip_bf16.h>

typedef __hip_bfloat16 bf16;
typedef __attribute__((ext_vector_type(8))) short short8;
typedef __attribute__((ext_vector_type(4))) short bfv4;
typedef __attribute__((ext_vector_type(4))) float f32x4;
typedef __attribute__((ext_vector_type(4))) unsigned short us4;

#define LN_EPS 1e-5f

__device__ __forceinline__ float siluf(float x) { return x / (1.f + __expf(-x)); }
__device__ __forceinline__ unsigned short f2bf_bits(float f) {
    bf16 h = __float2bfloat16(f);
    return *reinterpret_cast<unsigned short*>(&h);
}
__device__ __forceinline__ bf16 f2bf(float f) { return __float2bfloat16(f); }
__device__ __forceinline__ float bf2f(bf16 h) { return __bfloat162float(h); }

// async global->LDS, 16B per lane. LDS dest must be wave-uniform base (+lane*16 implicit).
__device__ __forceinline__ void load_lds16(const void* g, void* l) {
    __builtin_amdgcn_global_load_lds((const __attribute__((address_space(1))) void*)g,
                                     (__attribute__((address_space(3))) void*)l, 16, 0, 0);
}

__device__ __forceinline__ f32x4 mfma16(bfv4 a, bfv4 b, f32x4 c) {
    return __builtin_amdgcn_mfma_f32_16x16x16bf16_1k(a, b, c, 0, 0, 0);
}

// explicit RAW drain for global_load_lds before a barrier (rule-#18 class hazard)
__device__ __forceinline__ void drain_and_sync() {
    asm volatile("s_waitcnt vmcnt(0)" ::: "memory");
    __builtin_amdgcn_sched_barrier(0);
    __syncthreads();
}

// counted vmcnt wait (literal), fenced
template <int N>
__device__ __forceinline__ void wait_vmcnt() {
    asm volatile("s_waitcnt vmcnt(%0)" :: "n"(N) : "memory");
}
__device__ __forceinline__ void hard_barrier() {
    __builtin_amdgcn_sched_barrier(0);
    __builtin_amdgcn_s_barrier();
    __builtin_amdgcn_sched_barrier(0);
}
// barrier preceded by lgkmcnt(0): all this wave's ds_reads complete before crossing (WAR safety)
__device__ __forceinline__ void lgkm_barrier() {
    asm volatile("s_waitcnt lgkmcnt(0)" ::: "memory");
    __builtin_amdgcn_sched_barrier(0);
    __builtin_amdgcn_s_barrier();
    __builtin_amdgcn_sched_barrier(0);
}

// fine-phase sync: rendezvous, then wait own ds_reads, then high-prio MFMA
__device__ __forceinline__ void phase_pre() {
    __builtin_amdgcn_sched_barrier(0);
    __builtin_amdgcn_s_barrier();
    asm volatile("s_waitcnt lgkmcnt(0)" ::: "memory");
    __builtin_amdgcn_sched_barrier(0);
    __builtin_amdgcn_s_setprio(1);
}
__device__ __forceinline__ void phase_post() {
    __builtin_amdgcn_s_setprio(0);
    __builtin_amdgcn_sched_barrier(0);
    __builtin_amdgcn_s_barrier();
    __builtin_amdgcn_sched_barrier(0);
}

// XCD-chunked bijective block swizzle (requires nwg % 8 == 0)
__device__ __forceinline__ int xcd_swz(int bid, int nwg) {
    return (bid & 7) * (nwg >> 3) + (bid >> 3);
}

// ---------------- ALL five weight transposes in ONE launch (flat grid, zero waste) ----------------
// ranges: [0,12288) z0-2 = w_qkuv/w1/w3 (K=1024,N=4096, 128x32 tiles);
//         [12288,16384) w2 (K=4096,N=1024, 32x128); [16384,17408) w_out (K=1024,N=1024, 32x32)
__global__ __launch_bounds__(256) void transpose_all(
    const float* __restrict__ s0, const float* __restrict__ s1, const float* __restrict__ s2,
    const float* __restrict__ s3, const float* __restrict__ s4,
    bf16* __restrict__ d0, bf16* __restrict__ d1, bf16* __restrict__ d2,
    bf16* __restrict__ d3, bf16* __restrict__ d4)
{
    const int bid = (int)blockIdx.x;
    const float* src; bf16* dst; int K, N, nb, kb;
    if (bid < 12288) {
        const int z = bid >> 12, idx = bid & 4095;
        src = (z == 0) ? s0 : (z == 1) ? s1 : s2;
        dst = (z == 0) ? d0 : (z == 1) ? d1 : d2;
        K = 1024; N = 4096;
        nb = (idx & 127) << 5; kb = (idx >> 7) << 5;
    } else if (bid < 16384) {
        const int idx = bid - 12288;
        src = s3; dst = d3; K = 4096; N = 1024;
        nb = (idx & 31) << 5; kb = (idx >> 5) << 5;
    } else {
        const int idx = bid - 16384;
        src = s4; dst = d4; K = 1024; N = 1024;
        nb = (idx & 31) << 5; kb = (idx >> 5) << 5;
    }
    __shared__ float t[32][33];
    const int tx = threadIdx.x, ty = threadIdx.y;
#pragma unroll
    for (int i = ty; i < 32; i += 8) t[i][tx] = src[(size_t)(kb + i) * N + nb + tx];
    __syncthreads();
#pragma unroll
    for (int i = ty; i < 32; i += 8) dst[(size_t)(nb + i) * K + kb + tx] = f2bf(t[tx][i]);
}

// ---------------- LayerNorm fp32 row (D=1024) -> bf16 ----------------
__global__ __launch_bounds__(256) void ln_cast(
    const float* __restrict__ x, const float* __restrict__ g, const float* __restrict__ be,
    bf16* __restrict__ out)
{
    const int row = blockIdx.x, tid = threadIdx.x;
    const float4 v = ((const float4*)(x + (size_t)row * 1024))[tid];
    float s = v.x + v.y + v.z + v.w;
    float ss = v.x * v.x + v.y * v.y + v.z * v.z + v.w * v.w;
#pragma unroll
    for (int o = 32; o; o >>= 1) { s += __shfl_down(s, o); ss += __shfl_down(ss, o); }
    __shared__ float red[10];
    const int wid = tid >> 6, lane = tid & 63;
    if (lane == 0) { red[wid] = s; red[4 + wid] = ss; }
    __syncthreads();
    if (tid == 0) {
        float S = red[0] + red[1] + red[2] + red[3];
        float SS = red[4] + red[5] + red[6] + red[7];
        float mu = S * (1.f / 1024.f);
        red[8] = mu;
        red[9] = rsqrtf(SS * (1.f / 1024.f) - mu * mu + LN_EPS);
    }
    __syncthreads();
    const float mu = red[8], rstd = red[9];
    const float4 gg = ((const float4*)g)[tid];
    const float4 bb = ((const float4*)be)[tid];
    us4 o;
    o[0] = f2bf_bits((v.x - mu) * rstd * gg.x + bb.x);
    o[1] = f2bf_bits((v.y - mu) * rstd * gg.y + bb.y);
    o[2] = f2bf_bits((v.z - mu) * rstd * gg.z + bb.z);
    o[3] = f2bf_bits((v.w - mu) * rstd * gg.w + bb.w);
    ((us4*)(out + (size_t)row * 1024))[tid] = o;
}

// ---------------- 256x256 bf16 GEMM, 4-phase fine interleave, distance-1 dbuf ----------------
// Column-major block order (B-panels L2-resident; A reused across bx).
// EPI: 0 = bf16 silu(acc)
template <int EPI>
__global__ __launch_bounds__(512, 2) void gemm8(
    const bf16* __restrict__ A, const bf16* __restrict__ BT,
    bf16* __restrict__ outp, const bf16* __restrict__ mulsrc,
    int M, int N, int K)
{
    __shared__ __align__(16) bf16 lds[2][2][256 * 64];   // [buf][A=0/B=1][row*64+col]
    const int tid = threadIdx.x;
    const int wid = tid >> 6, lane = tid & 63;
    const int lhi = lane >> 4, llo = lane & 15;
    const int nby = M >> 8;
    const int bid = xcd_swz((int)blockIdx.x, (int)gridDim.x);
    const int by = bid % nby, bx = bid / nby;            // column-major
    const int row0 = by << 8, col0 = bx << 8;
    const int wr = wid >> 2, wc = wid & 3;               // 2M x 4N
    const int wbase = wid << 6;

    auto stage_tile = [&](const bf16* src, int r0, int k0, char* ldsbase) {
#pragma unroll
        for (int it = 0; it < 4; ++it) {
            const int p = it * 512 + wbase + lane;       // physical 16B-chunk index
            const int r = p >> 3, pc = p & 7;
            const int lc = pc ^ (r & 7);                 // logical chunk this slot holds
            load_lds16(src + (size_t)(r0 + r) * K + k0 + lc * 8,
                       ldsbase + (size_t)(it * 512 + wbase) * 16);
        }
    };
    auto stageA = [&](int t) { stage_tile(A, row0, t << 6, (char*)lds[t & 1][0]); };
    auto stageB = [&](int t) { stage_tile(BT, col0, t << 6, (char*)lds[t & 1][1]); };

    f32x4 acc[8][4] = {};

    // prologue: T0 only
    stageA(0); stageB(0);
    wait_vmcnt<0>();
    hard_barrier();

    const int KT = K >> 6;
    for (int t = 0; t < KT; ++t) {
        const bool more = (t + 1 < KT);
        const char* lAc = (const char*)lds[t & 1][0];
        const char* lBc = (const char*)lds[t & 1][1];

        short8 a0[2][4], a1[2][4], b0[2][2], b1[2][2];   // [kk][frag]
        auto ldA = [&](short8 af[2][4], int mh) {
#pragma unroll
            for (int kk = 0; kk < 2; ++kk)
#pragma unroll
                for (int m = 0; m < 4; ++m) {
                    const int ra = wr * 128 + mh * 64 + m * 16 + llo;
                    af[kk][m] = *(const short8*)(lAc + ra * 128 + (((kk * 4 + lhi) ^ (ra & 7)) << 4));
                }
        };
        auto ldB = [&](short8 bf_[2][2], int nh) {
#pragma unroll
            for (int kk = 0; kk < 2; ++kk)
#pragma unroll
                for (int n = 0; n < 2; ++n) {
                    const int rb = wc * 64 + nh * 32 + n * 16 + llo;
                    bf_[kk][n] = *(const short8*)(lBc + rb * 128 + (((kk * 4 + lhi) ^ (rb & 7)) << 4));
                }
        };
        auto mfma_q = [&](int mh, int nh, short8 af[2][4], short8 bf_[2][2]) {
#pragma unroll
            for (int kk = 0; kk < 2; ++kk)
#pragma unroll
                for (int m = 0; m < 4; ++m)
#pragma unroll
                    for (int n = 0; n < 2; ++n)
                        acc[mh * 4 + m][nh * 2 + n] =
                            __builtin_amdgcn_mfma_f32_16x16x32_bf16(af[kk][m], bf_[kk][n], acc[mh * 4 + m][nh * 2 + n], 0, 0, 0);
        };

        // P1: quadrant (0,0); stage A(t+1)
        ldA(a0, 0); ldB(b0, 0);
        if (more) stageA(t + 1);
        phase_pre(); mfma_q(0, 0, a0, b0); phase_post();
        // P2: quadrant (0,1); stage B(t+1)
        ldB(b1, 1);
        if (more) stageB(t + 1);
        phase_pre(); mfma_q(0, 1, a0, b1); phase_post();
        // P3: quadrant (1,1)
        ldA(a1, 1);
        phase_pre(); mfma_q(1, 1, a1, b1); phase_post();
        // P4: quadrant (1,0)
        phase_pre(); mfma_q(1, 0, a1, b0); phase_post();

        if (more) { wait_vmcnt<0>(); hard_barrier(); }   // T_{t+1} landed (loads >=2 phases old)
    }

#pragma unroll
    for (int m = 0; m < 8; ++m) {
        const int rbase = row0 + wr * 128 + m * 16 + lhi * 4;
#pragma unroll
        for (int n = 0; n < 4; ++n) {
            const int c = col0 + wc * 64 + n * 16 + llo;
#pragma unroll
            for (int r = 0; r < 4; ++r) {
                const size_t idx = (size_t)(rbase + r) * N + c;
                const float v = acc[m][n][r];
                if constexpr (EPI == 0) outp[idx] = f2bf(siluf(v));
                else                    outp[idx] = f2bf(v * bf2f(mulsrc[idx]));
            }
        }
    }
}

// ---------------- fused FFN: h1 = silu(A@W1) * (A@W3), 4-phase fine interleave ----------------
// Column-major block order: B1+B3 panels (2 MB) L2-resident.
__global__ __launch_bounds__(512, 2) void gemm_w13_8(
    const bf16* __restrict__ A, const bf16* __restrict__ B1T, const bf16* __restrict__ B3T,
    bf16* __restrict__ outp, int M, int N, int K)
{
    __shared__ __align__(16) bf16 lA[2][256 * 64];
    __shared__ __align__(16) bf16 lB1[2][128 * 64];
    __shared__ __align__(16) bf16 lB3[2][128 * 64];
    const int tid = threadIdx.x;
    const int wid = tid >> 6, lane = tid & 63;
    const int lhi = lane >> 4, llo = lane & 15;
    const int nby = M >> 8;
    const int bid = xcd_swz((int)blockIdx.x, (int)gridDim.x);
    const int by = bid % nby, bx = bid / nby;            // column-major
    const int row0 = by << 8, col0 = bx << 7;
    const int wr = wid >> 2, wc = wid & 3;               // 2M x 4N
    const int wbase = wid << 6;

    auto stage_rows = [&](const bf16* src, int r0, int k0, char* ldsbase, int nit) {
        for (int it = 0; it < nit; ++it) {
            const int p = it * 512 + wbase + lane;
            const int r = p >> 3, pc = p & 7;
            const int lc = pc ^ (r & 7);
            load_lds16(src + (size_t)(r0 + r) * K + k0 + lc * 8,
                       ldsbase + (size_t)(it * 512 + wbase) * 16);
        }
    };
    auto stageA = [&](int t) { stage_rows(A, row0, t << 6, (char*)lA[t & 1], 4); };
    auto stageB = [&](int t) {
        stage_rows(B1T, col0, t << 6, (char*)lB1[t & 1], 2);
        stage_rows(B3T, col0, t << 6, (char*)lB3[t & 1], 2);
    };

    f32x4 acc1[8][2] = {}, acc3[8][2] = {};

    stageA(0); stageB(0);
    wait_vmcnt<0>();
    hard_barrier();

    const int KT = K >> 6;
    for (int t = 0; t < KT; ++t) {
        const bool more = (t + 1 < KT);
        const char* lAc = (const char*)lA[t & 1];
        const char* lB1c = (const char*)lB1[t & 1];
        const char* lB3c = (const char*)lB3[t & 1];

        short8 b1f[2], b3f[2];                           // current-kk B frags
        auto ldA4 = [&](short8 af[4], int mh, int kk) {
#pragma unroll
            for (int m = 0; m < 4; ++m) {
                const int ra = wr * 128 + mh * 64 + m * 16 + llo;
                af[m] = *(const short8*)(lAc + ra * 128 + (((kk * 4 + lhi) ^ (ra & 7)) << 4));
            }
        };
        auto ldBk = [&](int kk) {
#pragma unroll
            for (int n = 0; n < 2; ++n) {
                const int rb = wc * 32 + n * 16 + llo;
                const int so = (((kk * 4 + lhi) ^ (rb & 7)) << 4);
                b1f[n] = *(const short8*)(lB1c + rb * 128 + so);
                b3f[n] = *(const short8*)(lB3c + rb * 128 + so);
            }
        };
        auto mfma_p = [&](short8 af[4], int mh) {
#pragma unroll
            for (int m = 0; m < 4; ++m)
#pragma unroll
                for (int n = 0; n < 2; ++n) {
                    acc1[mh * 4 + m][n] = __builtin_amdgcn_mfma_f32_16x16x32_bf16(af[m], b1f[n], acc1[mh * 4 + m][n], 0, 0, 0);
                    acc3[mh * 4 + m][n] = __builtin_amdgcn_mfma_f32_16x16x32_bf16(af[m], b3f[n], acc3[mh * 4 + m][n], 0, 0, 0);
                }
        };

        short8 af[4];
        // P1: (mh0, kk0); stage A(t+1)
        ldA4(af, 0, 0); ldBk(0);
        if (more) stageA(t + 1);
        phase_pre(); mfma_p(af, 0); phase_post();
        // P2: (mh1, kk0); stage B(t+1)
        ldA4(af, 1, 0);
        if (more) stageB(t + 1);
        phase_pre(); mfma_p(af, 1); phase_post();
        // P3: (mh0, kk1)
        ldA4(af, 0, 1); ldBk(1);
        phase_pre(); mfma_p(af, 0); phase_post();
        // P4: (mh1, kk1)
        ldA4(af, 1, 1);
        phase_pre(); mfma_p(af, 1); phase_post();

        if (more) { wait_vmcnt<0>(); hard_barrier(); }
    }

    // epilogue: silu(c1) * c3, wave-local
#pragma unroll
    for (int m = 0; m < 8; ++m) {
        const int rbase = row0 + wr * 128 + m * 16 + lhi * 4;
#pragma unroll
        for (int n = 0; n < 2; ++n) {
            const int c = col0 + wc * 32 + n * 16 + llo;
#pragma unroll
            for (int r = 0; r < 4; ++r) {
                const size_t idx = (size_t)(rbase + r) * N + c;
                outp[idx] = f2bf(siluf(acc1[m][n][r]) * acc3[m][n][r]);
            }
        }
    }
}

// ---------------- 128x64 bf16 GEMM, counted-vmcnt double-buffer (N=1024 GEMMs) ----------------
// ROW-major block order: A-slab L2-resident; right for K-large/N-small shapes (w2).
__global__ __launch_bounds__(256) void gemm_btc(
    const bf16* __restrict__ A, const bf16* __restrict__ BT,
    float* __restrict__ outp, const float* __restrict__ resid,
    int M, int N, int K)
{
    __shared__ __align__(16) bf16 lA[2][128 * 64];
    __shared__ __align__(16) bf16 lB[2][64 * 64];
    const int tid = threadIdx.x;
    const int wid = tid >> 6, lane = tid & 63;
    const int lhi = lane >> 4, llo = lane & 15;
    const int ntx = N >> 6;
    const int bid = xcd_swz((int)blockIdx.x, (int)gridDim.x);
    const int bx = bid % ntx, by = bid / ntx;            // row-major
    const int row0 = by << 7, col0 = bx << 6;
    const int wr = wid >> 1, wc = wid & 1;               // 2M x 2N
    const int wbase = wid << 6;

    auto stage_tile = [&](const bf16* src, int r0, int k0, char* ldsbase, int nit) {
        for (int it = 0; it < nit; ++it) {
            const int p = it * 256 + wbase + lane;
            const int r = p >> 3, pc = p & 7;
            const int lc = pc ^ (r & 7);
            load_lds16(src + (size_t)(r0 + r) * K + k0 + lc * 8,
                       ldsbase + (size_t)(it * 256 + wbase) * 16);
        }
    };
    auto stageT = [&](int t) {
        stage_tile(A, row0, t << 6, (char*)lA[t & 1], 4);
        stage_tile(BT, col0, t << 6, (char*)lB[t & 1], 2);
    };

    f32x4 acc[4][2] = {};

    stageT(0); stageT(1);
    wait_vmcnt<6>();
    hard_barrier();

    const int KT = K >> 6;
    for (int t = 0; t < KT; ++t) {
        const int buf = t & 1;
        const char* lAc = (const char*)lA[buf];
        const char* lBc = (const char*)lB[buf];

        short8 af[4], bfr[2];
        auto ldA = [&](int kk) {
#pragma unroll
            for (int m = 0; m < 4; ++m) {
                const int ra = wr * 64 + m * 16 + llo;
                af[m] = *(const short8*)(lAc + ra * 128 + (((kk * 4 + lhi) ^ (ra & 7)) << 4));
            }
        };
        auto ldB = [&](int kk) {
#pragma unroll
            for (int n = 0; n < 2; ++n) {
                const int rb = wc * 32 + n * 16 + llo;
                bfr[n] = *(const short8*)(lBc + rb * 128 + (((kk * 4 + lhi) ^ (rb & 7)) << 4));
            }
        };

#pragma unroll
        for (int kk = 0; kk < 2; ++kk) {
            ldA(kk); ldB(kk);
            __builtin_amdgcn_s_setprio(1);
#pragma unroll
            for (int m = 0; m < 4; ++m)
#pragma unroll
                for (int n = 0; n < 2; ++n)
                    acc[m][n] = __builtin_amdgcn_mfma_f32_16x16x32_bf16(af[m], bfr[n], acc[m][n], 0, 0, 0);
            __builtin_amdgcn_s_setprio(0);
        }

        lgkm_barrier();
        if (t + 2 < KT) {
            stageT(t + 2);
            wait_vmcnt<6>();
            hard_barrier();
        } else if (t + 1 < KT) {
            wait_vmcnt<0>();
            hard_barrier();
        }
    }

#pragma unroll
    for (int m = 0; m < 4; ++m) {
        const int rbase = row0 + wr * 64 + m * 16 + lhi * 4;
#pragma unroll
        for (int n = 0; n < 2; ++n) {
            const int c = col0 + wc * 32 + n * 16 + llo;
#pragma unroll
            for (int r = 0; r < 4; ++r) {
                const size_t idx = (size_t)(rbase + r) * N + c;
                outp[idx] = resid[idx] + acc[m][n][r];
            }
        }
    }
}

// ---------------- V transpose: qkuv v-quarter [B][L][H*64] -> v_t [B*H][64][L] ----------------
__global__ __launch_bounds__(256) void v_trans(const bf16* __restrict__ qkuv, bf16* __restrict__ v_t)
{
    __shared__ bf16 t[64][65];
    const int bh = blockIdx.y;         // b*16+h
    const int b = bh >> 4, h = bh & 15;
    const int l0 = blockIdx.x << 6;
    const int tx = threadIdx.x, ty = threadIdx.y;
#pragma unroll
    for (int i = ty; i < 64; i += 4)
        t[i][tx] = qkuv[(size_t)(b * 2048 + l0 + i) * 4096 + 2048 + h * 64 + tx];
    __syncthreads();
#pragma unroll
    for (int i = ty; i < 64; i += 4)
        v_t[(size_t)(bh * 64 + i) * 2048 + l0 + tx] = t[tx][i];
}

// ---------------- fused silu-attention + head-LN*u (KVBLK=128, LPT grid) ----------------
// 512 threads = 8 waves, each wave owns 16 q rows of a 128-row q-tile.
// LPT dispatch: qt = 15 - (bid>>5), bh = bid&31 -> heavy blocks dispatched first.
__global__ __launch_bounds__(512) void attn_kernel(
    const bf16* __restrict__ qkuv, const bf16* __restrict__ v_t,
    const float* __restrict__ nag, const float* __restrict__ nab,
    bf16* __restrict__ au)
{
    __shared__ __align__(16) bf16 lK[2][128 * 64];
    __shared__ __align__(16) bf16 lV[2][64 * 128];
    const int tid = threadIdx.x;
    const int wid = tid >> 6, lane = tid & 63;
    const int lhi = lane >> 4, llo = lane & 15;
    const int bid = (int)blockIdx.x;
    const int qt = 15 - (bid >> 5);                       // heavy blocks dispatched first
    const int bh = bid & 31;
    const int b = bh >> 4, h = bh & 15;
    const int q0 = qt << 7;
    const bf16* Qb = qkuv + (size_t)b * 2048 * 4096 + h * 64;
    const bf16* Kb = Qb + 1024;
    const bf16* Ub = Qb + 3072;
    const bf16* Vb = v_t + (size_t)bh * 64 * 2048;
    const int wbase = wid << 6;

    auto stage = [&](int kt_s, int buf) {
        const int koff = kt_s << 7;
        char* lKc = (char*)lK[buf];
        char* lVc = (char*)lV[buf];
#pragma unroll
        for (int it = 0; it < 2; ++it) {
            const int p = it * 512 + wbase + lane;
            const int r = p >> 3, pc = p & 7;
            const int lc = pc ^ (r & 7);
            load_lds16(Kb + (size_t)(koff + r) * 4096 + lc * 8, lKc + (it * 512 + wbase) * 16);
        }
#pragma unroll
        for (int it = 0; it < 2; ++it) {
            const int p = it * 512 + wbase + lane;
            const int d = p >> 4, pc = p & 15;
            const int lc = pc ^ (d & 15);
            load_lds16(Vb + (size_t)d * 2048 + koff + lc * 8, lVc + (it * 512 + wbase) * 16);
        }
    };

    // hoist Q B-frags: q = wid*16 + llo, dk = kk*32 + lhi*8
    short8 qb[2];
#pragma unroll
    for (int kk = 0; kk < 2; ++kk)
        qb[kk] = *(const short8*)(Qb + (size_t)(q0 + wid * 16 + llo) * 4096 + kk * 32 + lhi * 8);

    f32x4 acc2[4] = {};

    stage(0, 0);  // prologue prefetch

    for (int kt = 0; kt <= qt; ++kt) {
        const int cur = kt & 1;
        drain_and_sync();                      // staged buf[cur] visible to all waves
        if (kt < qt) stage(kt + 1, cur ^ 1);   // prefetch next tile into other buffer
        const char* lKc = (const char*)lK[cur];
        const char* lVc = (const char*)lV[cur];

        const bool diag = (kt == qt);
#pragma unroll
        for (int m = 0; m < 8; ++m) {
            if (diag && m > wid) break;                    // fully above diagonal
            const int rK = m * 16 + llo;
            const int sw = rK & 7;
            short8 ak0 = *(const short8*)(lKc + rK * 128 + ((lhi ^ sw) << 4));
            short8 ak1 = *(const short8*)(lKc + rK * 128 + (((4 + lhi) ^ sw) << 4));
            f32x4 s = {};
            s = __builtin_amdgcn_mfma_f32_16x16x32_bf16(ak0, qb[0], s, 0, 0, 0);
            s = __builtin_amdgcn_mfma_f32_16x16x32_bf16(ak1, qb[1], s, 0, 0, 0);
            const bool mask = diag && (m == wid);
            bfv4 a16;
#pragma unroll
            for (int r = 0; r < 4; ++r) {
                float xx = s[r] * 0.125f;
                xx = xx * __builtin_amdgcn_rcpf(1.f + __expf(-xx));
                if (mask && (lhi * 4 + r > llo)) xx = 0.f;
                a16[r] = (short)f2bf_bits(xx);
            }
#pragma unroll
            for (int dcol = 0; dcol < 4; ++dcol) {
                const int d = dcol * 16 + llo;
                const int lcV = m * 2 + (lhi >> 1);
                bfv4 bv = *(const bfv4*)(lVc + d * 256 + ((lcV ^ llo) << 4) + (lhi & 1) * 8);
                acc2[dcol] = mfma16(a16, bv, acc2[dcol]);
            }
        }
    }

    // ---- epilogue: LN(d=64) * u ----
#pragma unroll
    for (int r = 0; r < 4; ++r) {
        float vv[4];
        float s = 0.f, ss = 0.f;
#pragma unroll
        for (int dc = 0; dc < 4; ++dc) { vv[dc] = acc2[dc][r]; s += vv[dc]; ss += vv[dc] * vv[dc]; }
#pragma unroll
        for (int o = 1; o < 16; o <<= 1) { s += __shfl_xor(s, o); ss += __shfl_xor(ss, o); }
        const float mu = s * (1.f / 64.f);
        const float rstd = rsqrtf(ss * (1.f / 64.f) - mu * mu + LN_EPS);
        const int q = wid * 16 + lhi * 4 + r;
        const size_t grow = q0 + q;
#pragma unroll
        for (int dc = 0; dc < 4; ++dc) {
            const int c = dc * 16 + llo;
            const float nv = (vv[dc] - mu) * rstd * nag[c] + nab[c];
            const float uu = bf2f(Ub[grow * 4096 + c]);
            au[(size_t)(b * 2048 + grow) * 1024 + h * 64 + c] = f2bf(nv * uu);
        }
    }
}

// ---------------- host launch ----------------
extern "C" void kernel_launch(void* const* d_in, const int* in_sizes, int n_in,
                              void* d_out, int out_size, void* d_ws, size_t ws_size,
                              hipStream_t stream)
{
    const float* x      = (const float*)d_in[0];
    // d_in[1] = attn_mask (tril causal; applied analytically)
    const float* w_qkuv = (const float*)d_in[2];
    const float* w_out  = (const float*)d_in[3];
    const float* w1     = (const float*)d_in[4];
    const float* w2     = (const float*)d_in[5];
    const float* w3     = (const float*)d_in[6];
    const float* ln1g   = (const float*)d_in[7];
    const float* ln1b   = (const float*)d_in[8];
    const float* ln2g   = (const float*)d_in[9];
    const float* ln2b   = (const float*)d_in[10];
    const float* nag    = (const float*)d_in[11];
    const float* nab    = (const float*)d_in[12];
    float* out = (float*)d_out;

    char* ws = (char*)d_ws;
    size_t off = 0;
    auto alloc = [&](size_t bytes) { void* p = ws + off; off += (bytes + 255) & ~(size_t)255; return p; };
    const size_t M = 4096;  // B*L
    bf16* wqkuvT = (bf16*)alloc(4096ull * 1024 * 2);
    bf16* woutT  = (bf16*)alloc(1024ull * 1024 * 2);
    bf16* w1T    = (bf16*)alloc(4096ull * 1024 * 2);
    bf16* w3T    = (bf16*)alloc(4096ull * 1024 * 2);
    bf16* w2T    = (bf16*)alloc(1024ull * 4096 * 2);
    bf16* xn     = (bf16*)alloc(M * 1024 * 2);
    bf16* qkuv   = (bf16*)alloc(M * 4096 * 2);
    bf16* vt     = (bf16*)alloc(32ull * 64 * 2048 * 2);
    bf16* aub    = (bf16*)alloc(M * 1024 * 2);
    float* x2    = (float*)alloc(M * 1024 * 4);
    bf16* xn2    = (bf16*)alloc(M * 1024 * 2);
    bf16* h1     = (bf16*)alloc(M * 4096 * 2);
    (void)ws_size; (void)in_sizes; (void)n_in; (void)out_size;

    dim3 tb(32, 8);
    transpose_all<<<dim3(17408), tb, 0, stream>>>(w_qkuv, w1, w3, w2, w_out,
                                                  wqkuvT, w1T, w3T, w2T, woutT);

    ln_cast<<<M, 256, 0, stream>>>(x, ln1g, ln1b, xn);

    gemm8<0><<<dim3((M / 256) * (4096 / 256)), 512, 0, stream>>>(xn, wqkuvT, qkuv, nullptr, M, 4096, 1024);

    v_trans<<<dim3(2048 / 64, 32), dim3(64, 4), 0, stream>>>(qkuv, vt);

    attn_kernel<<<dim3(512), 512, 0, stream>>>(qkuv, vt, nag, nab, aub);

    gemm_btc<<<dim3((M / 128) * (1024 / 64)), 256, 0, stream>>>(aub, woutT, x2, x, M, 1024, 1024);

    ln_cast<<<M, 256, 0, stream>>>(x2, ln2g, ln2b, xn2);

    gemm_w13_8<<<dim3((M / 256) * (4096 / 128)), 512, 0, stream>>>(xn2, w1T, w3T, h1, M, 4096, 1024);

    gemm_btc<<<dim3((M / 128) * (1024 / 64)), 256, 0, stream>>>(h1, w2T, out, x2, M, 1024, 4096);
}

// Round 22
// 274.392 us; speedup vs baseline: 1.0573x; 1.0084x over previous
//
#include <hip/hip_runtime.h>
#include <hip/hip_bf16.h>

typedef __hip_bfloat16 bf16;
typedef __attribute__((ext_vector_type(8))) short short8;
typedef __attribute__((ext_vector_type(4))) short bfv4;
typedef __attribute__((ext_vector_type(4))) float f32x4;
typedef __attribute__((ext_vector_type(4))) unsigned short us4;

#define LN_EPS 1e-5f

__device__ __forceinline__ float siluf(float x) { return x / (1.f + __expf(-x)); }
__device__ __forceinline__ unsigned short f2bf_bits(float f) {
    bf16 h = __float2bfloat16(f);
    return *reinterpret_cast<unsigned short*>(&h);
}
__device__ __forceinline__ bf16 f2bf(float f) { return __float2bfloat16(f); }
__device__ __forceinline__ float bf2f(bf16 h) { return __bfloat162float(h); }

// async global->LDS, 16B per lane. LDS dest must be wave-uniform base (+lane*16 implicit).
__device__ __forceinline__ void load_lds16(const void* g, void* l) {
    __builtin_amdgcn_global_load_lds((const __attribute__((address_space(1))) void*)g,
                                     (__attribute__((address_space(3))) void*)l, 16, 0, 0);
}

__device__ __forceinline__ f32x4 mfma16(bfv4 a, bfv4 b, f32x4 c) {
    return __builtin_amdgcn_mfma_f32_16x16x16bf16_1k(a, b, c, 0, 0, 0);
}

// explicit RAW drain for global_load_lds before a barrier (rule-#18 class hazard)
__device__ __forceinline__ void drain_and_sync() {
    asm volatile("s_waitcnt vmcnt(0)" ::: "memory");
    __builtin_amdgcn_sched_barrier(0);
    __syncthreads();
}

// counted vmcnt wait (literal), fenced
template <int N>
__device__ __forceinline__ void wait_vmcnt() {
    asm volatile("s_waitcnt vmcnt(%0)" :: "n"(N) : "memory");
}
__device__ __forceinline__ void hard_barrier() {
    __builtin_amdgcn_sched_barrier(0);
    __builtin_amdgcn_s_barrier();
    __builtin_amdgcn_sched_barrier(0);
}
// barrier preceded by lgkmcnt(0): all this wave's ds_reads complete before crossing (WAR safety)
__device__ __forceinline__ void lgkm_barrier() {
    asm volatile("s_waitcnt lgkmcnt(0)" ::: "memory");
    __builtin_amdgcn_sched_barrier(0);
    __builtin_amdgcn_s_barrier();
    __builtin_amdgcn_sched_barrier(0);
}

// fine-phase sync: rendezvous, then wait own ds_reads, then high-prio MFMA
__device__ __forceinline__ void phase_pre() {
    __builtin_amdgcn_sched_barrier(0);
    __builtin_amdgcn_s_barrier();
    asm volatile("s_waitcnt lgkmcnt(0)" ::: "memory");
    __builtin_amdgcn_sched_barrier(0);
    __builtin_amdgcn_s_setprio(1);
}
__device__ __forceinline__ void phase_post() {
    __builtin_amdgcn_s_setprio(0);
    __builtin_amdgcn_sched_barrier(0);
    __builtin_amdgcn_s_barrier();
    __builtin_amdgcn_sched_barrier(0);
}

// XCD-chunked bijective block swizzle (requires nwg % 8 == 0)
__device__ __forceinline__ int xcd_swz(int bid, int nwg) {
    return (bid & 7) * (nwg >> 3) + (bid >> 3);
}

// ---------------- ALL five weight transposes in ONE launch (flat grid, zero waste) ----------------
// ranges: [0,12288) z0-2 = w_qkuv/w1/w3 (K=1024,N=4096, 128x32 tiles);
//         [12288,16384) w2 (K=4096,N=1024, 32x128); [16384,17408) w_out (K=1024,N=1024, 32x32)
__global__ __launch_bounds__(256) void transpose_all(
    const float* __restrict__ s0, const float* __restrict__ s1, const float* __restrict__ s2,
    const float* __restrict__ s3, const float* __restrict__ s4,
    bf16* __restrict__ d0, bf16* __restrict__ d1, bf16* __restrict__ d2,
    bf16* __restrict__ d3, bf16* __restrict__ d4)
{
    const int bid = (int)blockIdx.x;
    const float* src; bf16* dst; int K, N, nb, kb;
    if (bid < 12288) {
        const int z = bid >> 12, idx = bid & 4095;
        src = (z == 0) ? s0 : (z == 1) ? s1 : s2;
        dst = (z == 0) ? d0 : (z == 1) ? d1 : d2;
        K = 1024; N = 4096;
        nb = (idx & 127) << 5; kb = (idx >> 7) << 5;
    } else if (bid < 16384) {
        const int idx = bid - 12288;
        src = s3; dst = d3; K = 4096; N = 1024;
        nb = (idx & 31) << 5; kb = (idx >> 5) << 5;
    } else {
        const int idx = bid - 16384;
        src = s4; dst = d4; K = 1024; N = 1024;
        nb = (idx & 31) << 5; kb = (idx >> 5) << 5;
    }
    __shared__ float t[32][33];
    const int tx = threadIdx.x, ty = threadIdx.y;
#pragma unroll
    for (int i = ty; i < 32; i += 8) t[i][tx] = src[(size_t)(kb + i) * N + nb + tx];
    __syncthreads();
#pragma unroll
    for (int i = ty; i < 32; i += 8) dst[(size_t)(nb + i) * K + kb + tx] = f2bf(t[tx][i]);
}

// ---------------- LayerNorm fp32 row (D=1024) -> bf16 ----------------
__global__ __launch_bounds__(256) void ln_cast(
    const float* __restrict__ x, const float* __restrict__ g, const float* __restrict__ be,
    bf16* __restrict__ out)
{
    const int row = blockIdx.x, tid = threadIdx.x;
    const float4 v = ((const float4*)(x + (size_t)row * 1024))[tid];
    float s = v.x + v.y + v.z + v.w;
    float ss = v.x * v.x + v.y * v.y + v.z * v.z + v.w * v.w;
#pragma unroll
    for (int o = 32; o; o >>= 1) { s += __shfl_down(s, o); ss += __shfl_down(ss, o); }
    __shared__ float red[10];
    const int wid = tid >> 6, lane = tid & 63;
    if (lane == 0) { red[wid] = s; red[4 + wid] = ss; }
    __syncthreads();
    if (tid == 0) {
        float S = red[0] + red[1] + red[2] + red[3];
        float SS = red[4] + red[5] + red[6] + red[7];
        float mu = S * (1.f / 1024.f);
        red[8] = mu;
        red[9] = rsqrtf(SS * (1.f / 1024.f) - mu * mu + LN_EPS);
    }
    __syncthreads();
    const float mu = red[8], rstd = red[9];
    const float4 gg = ((const float4*)g)[tid];
    const float4 bb = ((const float4*)be)[tid];
    us4 o;
    o[0] = f2bf_bits((v.x - mu) * rstd * gg.x + bb.x);
    o[1] = f2bf_bits((v.y - mu) * rstd * gg.y + bb.y);
    o[2] = f2bf_bits((v.z - mu) * rstd * gg.z + bb.z);
    o[3] = f2bf_bits((v.w - mu) * rstd * gg.w + bb.w);
    ((us4*)(out + (size_t)row * 1024))[tid] = o;
}

// ---------------- 256x256 bf16 GEMM, 4-phase fine interleave, distance-1 dbuf ----------------
// Column-major block order (B-panels L2-resident; A reused across bx).
// EPI: 0 = bf16 silu(acc)
template <int EPI>
__global__ __launch_bounds__(512, 2) void gemm8(
    const bf16* __restrict__ A, const bf16* __restrict__ BT,
    bf16* __restrict__ outp, const bf16* __restrict__ mulsrc,
    int M, int N, int K)
{
    __shared__ __align__(16) bf16 lds[2][2][256 * 64];   // [buf][A=0/B=1][row*64+col]
    const int tid = threadIdx.x;
    const int wid = tid >> 6, lane = tid & 63;
    const int lhi = lane >> 4, llo = lane & 15;
    const int nby = M >> 8;
    const int bid = xcd_swz((int)blockIdx.x, (int)gridDim.x);
    const int by = bid % nby, bx = bid / nby;            // column-major
    const int row0 = by << 8, col0 = bx << 8;
    const int wr = wid >> 2, wc = wid & 3;               // 2M x 4N
    const int wbase = wid << 6;

    auto stage_tile = [&](const bf16* src, int r0, int k0, char* ldsbase) {
#pragma unroll
        for (int it = 0; it < 4; ++it) {
            const int p = it * 512 + wbase + lane;       // physical 16B-chunk index
            const int r = p >> 3, pc = p & 7;
            const int lc = pc ^ (r & 7);                 // logical chunk this slot holds
            load_lds16(src + (size_t)(r0 + r) * K + k0 + lc * 8,
                       ldsbase + (size_t)(it * 512 + wbase) * 16);
        }
    };
    auto stageA = [&](int t) { stage_tile(A, row0, t << 6, (char*)lds[t & 1][0]); };
    auto stageB = [&](int t) { stage_tile(BT, col0, t << 6, (char*)lds[t & 1][1]); };

    f32x4 acc[8][4] = {};

    // prologue: T0 only
    stageA(0); stageB(0);
    wait_vmcnt<0>();
    hard_barrier();

    const int KT = K >> 6;
    for (int t = 0; t < KT; ++t) {
        const bool more = (t + 1 < KT);
        const char* lAc = (const char*)lds[t & 1][0];
        const char* lBc = (const char*)lds[t & 1][1];

        short8 a0[2][4], a1[2][4], b0[2][2], b1[2][2];   // [kk][frag]
        auto ldA = [&](short8 af[2][4], int mh) {
#pragma unroll
            for (int kk = 0; kk < 2; ++kk)
#pragma unroll
                for (int m = 0; m < 4; ++m) {
                    const int ra = wr * 128 + mh * 64 + m * 16 + llo;
                    af[kk][m] = *(const short8*)(lAc + ra * 128 + (((kk * 4 + lhi) ^ (ra & 7)) << 4));
                }
        };
        auto ldB = [&](short8 bf_[2][2], int nh) {
#pragma unroll
            for (int kk = 0; kk < 2; ++kk)
#pragma unroll
                for (int n = 0; n < 2; ++n) {
                    const int rb = wc * 64 + nh * 32 + n * 16 + llo;
                    bf_[kk][n] = *(const short8*)(lBc + rb * 128 + (((kk * 4 + lhi) ^ (rb & 7)) << 4));
                }
        };
        auto mfma_q = [&](int mh, int nh, short8 af[2][4], short8 bf_[2][2]) {
#pragma unroll
            for (int kk = 0; kk < 2; ++kk)
#pragma unroll
                for (int m = 0; m < 4; ++m)
#pragma unroll
                    for (int n = 0; n < 2; ++n)
                        acc[mh * 4 + m][nh * 2 + n] =
                            __builtin_amdgcn_mfma_f32_16x16x32_bf16(af[kk][m], bf_[kk][n], acc[mh * 4 + m][nh * 2 + n], 0, 0, 0);
        };

        // P1: quadrant (0,0); stage A(t+1)
        ldA(a0, 0); ldB(b0, 0);
        if (more) stageA(t + 1);
        phase_pre(); mfma_q(0, 0, a0, b0); phase_post();
        // P2: quadrant (0,1); stage B(t+1)
        ldB(b1, 1);
        if (more) stageB(t + 1);
        phase_pre(); mfma_q(0, 1, a0, b1); phase_post();
        // P3: quadrant (1,1)
        ldA(a1, 1);
        phase_pre(); mfma_q(1, 1, a1, b1); phase_post();
        // P4: quadrant (1,0)
        phase_pre(); mfma_q(1, 0, a1, b0); phase_post();

        if (more) { wait_vmcnt<0>(); hard_barrier(); }   // T_{t+1} landed (loads >=2 phases old)
    }

#pragma unroll
    for (int m = 0; m < 8; ++m) {
        const int rbase = row0 + wr * 128 + m * 16 + lhi * 4;
#pragma unroll
        for (int n = 0; n < 4; ++n) {
            const int c = col0 + wc * 64 + n * 16 + llo;
#pragma unroll
            for (int r = 0; r < 4; ++r) {
                const size_t idx = (size_t)(rbase + r) * N + c;
                const float v = acc[m][n][r];
                if constexpr (EPI == 0) outp[idx] = f2bf(siluf(v));
                else                    outp[idx] = f2bf(v * bf2f(mulsrc[idx]));
            }
        }
    }
}

// ---------------- fused FFN: h1 = silu(A@W1) * (A@W3), 4-phase fine interleave ----------------
// Column-major block order: B1+B3 panels (2 MB) L2-resident.
__global__ __launch_bounds__(512, 2) void gemm_w13_8(
    const bf16* __restrict__ A, const bf16* __restrict__ B1T, const bf16* __restrict__ B3T,
    bf16* __restrict__ outp, int M, int N, int K)
{
    __shared__ __align__(16) bf16 lA[2][256 * 64];
    __shared__ __align__(16) bf16 lB1[2][128 * 64];
    __shared__ __align__(16) bf16 lB3[2][128 * 64];
    const int tid = threadIdx.x;
    const int wid = tid >> 6, lane = tid & 63;
    const int lhi = lane >> 4, llo = lane & 15;
    const int nby = M >> 8;
    const int bid = xcd_swz((int)blockIdx.x, (int)gridDim.x);
    const int by = bid % nby, bx = bid / nby;            // column-major
    const int row0 = by << 8, col0 = bx << 7;
    const int wr = wid >> 2, wc = wid & 3;               // 2M x 4N
    const int wbase = wid << 6;

    auto stage_rows = [&](const bf16* src, int r0, int k0, char* ldsbase, int nit) {
        for (int it = 0; it < nit; ++it) {
            const int p = it * 512 + wbase + lane;
            const int r = p >> 3, pc = p & 7;
            const int lc = pc ^ (r & 7);
            load_lds16(src + (size_t)(r0 + r) * K + k0 + lc * 8,
                       ldsbase + (size_t)(it * 512 + wbase) * 16);
        }
    };
    auto stageA = [&](int t) { stage_rows(A, row0, t << 6, (char*)lA[t & 1], 4); };
    auto stageB = [&](int t) {
        stage_rows(B1T, col0, t << 6, (char*)lB1[t & 1], 2);
        stage_rows(B3T, col0, t << 6, (char*)lB3[t & 1], 2);
    };

    f32x4 acc1[8][2] = {}, acc3[8][2] = {};

    stageA(0); stageB(0);
    wait_vmcnt<0>();
    hard_barrier();

    const int KT = K >> 6;
    for (int t = 0; t < KT; ++t) {
        const bool more = (t + 1 < KT);
        const char* lAc = (const char*)lA[t & 1];
        const char* lB1c = (const char*)lB1[t & 1];
        const char* lB3c = (const char*)lB3[t & 1];

        short8 b1f[2], b3f[2];                           // current-kk B frags
        auto ldA4 = [&](short8 af[4], int mh, int kk) {
#pragma unroll
            for (int m = 0; m < 4; ++m) {
                const int ra = wr * 128 + mh * 64 + m * 16 + llo;
                af[m] = *(const short8*)(lAc + ra * 128 + (((kk * 4 + lhi) ^ (ra & 7)) << 4));
            }
        };
        auto ldBk = [&](int kk) {
#pragma unroll
            for (int n = 0; n < 2; ++n) {
                const int rb = wc * 32 + n * 16 + llo;
                const int so = (((kk * 4 + lhi) ^ (rb & 7)) << 4);
                b1f[n] = *(const short8*)(lB1c + rb * 128 + so);
                b3f[n] = *(const short8*)(lB3c + rb * 128 + so);
            }
        };
        auto mfma_p = [&](short8 af[4], int mh) {
#pragma unroll
            for (int m = 0; m < 4; ++m)
#pragma unroll
                for (int n = 0; n < 2; ++n) {
                    acc1[mh * 4 + m][n] = __builtin_amdgcn_mfma_f32_16x16x32_bf16(af[m], b1f[n], acc1[mh * 4 + m][n], 0, 0, 0);
                    acc3[mh * 4 + m][n] = __builtin_amdgcn_mfma_f32_16x16x32_bf16(af[m], b3f[n], acc3[mh * 4 + m][n], 0, 0, 0);
                }
        };

        short8 af[4];
        // P1: (mh0, kk0); stage A(t+1)
        ldA4(af, 0, 0); ldBk(0);
        if (more) stageA(t + 1);
        phase_pre(); mfma_p(af, 0); phase_post();
        // P2: (mh1, kk0); stage B(t+1)
        ldA4(af, 1, 0);
        if (more) stageB(t + 1);
        phase_pre(); mfma_p(af, 1); phase_post();
        // P3: (mh0, kk1)
        ldA4(af, 0, 1); ldBk(1);
        phase_pre(); mfma_p(af, 0); phase_post();
        // P4: (mh1, kk1)
        ldA4(af, 1, 1);
        phase_pre(); mfma_p(af, 1); phase_post();

        if (more) { wait_vmcnt<0>(); hard_barrier(); }
    }

    // epilogue: silu(c1) * c3, wave-local
#pragma unroll
    for (int m = 0; m < 8; ++m) {
        const int rbase = row0 + wr * 128 + m * 16 + lhi * 4;
#pragma unroll
        for (int n = 0; n < 2; ++n) {
            const int c = col0 + wc * 32 + n * 16 + llo;
#pragma unroll
            for (int r = 0; r < 4; ++r) {
                const size_t idx = (size_t)(rbase + r) * N + c;
                outp[idx] = f2bf(siluf(acc1[m][n][r]) * acc3[m][n][r]);
            }
        }
    }
}

// ---------------- 128x64 bf16 GEMM, 2-phase fine interleave, distance-1 dbuf (N=1024) ----------------
// ROW-major block order: A-slab L2-resident (right for K-large/N-small: w2).
// Per K-tile: P1 = {ldA/ldB(kk0) || stage T_{t+1} -> barrier; lgkm(0); 8 MFMA; barrier},
// P2 = same for kk1; boundary vmcnt(0)+barrier (loads 2 phases old; 2 blocks/CU overlap).
// Same distance-1 ledger as gemm8 (stage targets buf^1; prior reads drained by P-phase lgkm+barrier).
__global__ __launch_bounds__(256) void gemm_btc(
    const bf16* __restrict__ A, const bf16* __restrict__ BT,
    float* __restrict__ outp, const float* __restrict__ resid,
    int M, int N, int K)
{
    __shared__ __align__(16) bf16 lA[2][128 * 64];
    __shared__ __align__(16) bf16 lB[2][64 * 64];
    const int tid = threadIdx.x;
    const int wid = tid >> 6, lane = tid & 63;
    const int lhi = lane >> 4, llo = lane & 15;
    const int ntx = N >> 6;
    const int bid = xcd_swz((int)blockIdx.x, (int)gridDim.x);
    const int bx = bid % ntx, by = bid / ntx;            // row-major
    const int row0 = by << 7, col0 = bx << 6;
    const int wr = wid >> 1, wc = wid & 1;               // 2M x 2N
    const int wbase = wid << 6;

    auto stage_tile = [&](const bf16* src, int r0, int k0, char* ldsbase, int nit) {
        for (int it = 0; it < nit; ++it) {
            const int p = it * 256 + wbase + lane;
            const int r = p >> 3, pc = p & 7;
            const int lc = pc ^ (r & 7);
            load_lds16(src + (size_t)(r0 + r) * K + k0 + lc * 8,
                       ldsbase + (size_t)(it * 256 + wbase) * 16);
        }
    };
    auto stageT = [&](int t) {
        stage_tile(A, row0, t << 6, (char*)lA[t & 1], 4);
        stage_tile(BT, col0, t << 6, (char*)lB[t & 1], 2);
    };

    f32x4 acc[4][2] = {};

    stageT(0);
    wait_vmcnt<0>();
    hard_barrier();

    const int KT = K >> 6;
    for (int t = 0; t < KT; ++t) {
        const bool more = (t + 1 < KT);
        const int buf = t & 1;
        const char* lAc = (const char*)lA[buf];
        const char* lBc = (const char*)lB[buf];

        short8 af[4], bfr[2];
        auto ldA = [&](int kk) {
#pragma unroll
            for (int m = 0; m < 4; ++m) {
                const int ra = wr * 64 + m * 16 + llo;
                af[m] = *(const short8*)(lAc + ra * 128 + (((kk * 4 + lhi) ^ (ra & 7)) << 4));
            }
        };
        auto ldB = [&](int kk) {
#pragma unroll
            for (int n = 0; n < 2; ++n) {
                const int rb = wc * 32 + n * 16 + llo;
                bfr[n] = *(const short8*)(lBc + rb * 128 + (((kk * 4 + lhi) ^ (rb & 7)) << 4));
            }
        };
        auto mfma8 = [&]() {
#pragma unroll
            for (int m = 0; m < 4; ++m)
#pragma unroll
                for (int n = 0; n < 2; ++n)
                    acc[m][n] = __builtin_amdgcn_mfma_f32_16x16x32_bf16(af[m], bfr[n], acc[m][n], 0, 0, 0);
        };

        // P1: kk0; stage T_{t+1} into buf^1
        ldA(0); ldB(0);
        if (more) stageT(t + 1);
        phase_pre(); mfma8(); phase_post();
        // P2: kk1
        ldA(1); ldB(1);
        phase_pre(); mfma8(); phase_post();

        if (more) { wait_vmcnt<0>(); hard_barrier(); }   // T_{t+1} landed
    }

#pragma unroll
    for (int m = 0; m < 4; ++m) {
        const int rbase = row0 + wr * 64 + m * 16 + lhi * 4;
#pragma unroll
        for (int n = 0; n < 2; ++n) {
            const int c = col0 + wc * 32 + n * 16 + llo;
#pragma unroll
            for (int r = 0; r < 4; ++r) {
                const size_t idx = (size_t)(rbase + r) * N + c;
                outp[idx] = resid[idx] + acc[m][n][r];
            }
        }
    }
}

// ---------------- V transpose: qkuv v-quarter [B][L][H*64] -> v_t [B*H][64][L] ----------------
__global__ __launch_bounds__(256) void v_trans(const bf16* __restrict__ qkuv, bf16* __restrict__ v_t)
{
    __shared__ bf16 t[64][65];
    const int bh = blockIdx.y;         // b*16+h
    const int b = bh >> 4, h = bh & 15;
    const int l0 = blockIdx.x << 6;
    const int tx = threadIdx.x, ty = threadIdx.y;
#pragma unroll
    for (int i = ty; i < 64; i += 4)
        t[i][tx] = qkuv[(size_t)(b * 2048 + l0 + i) * 4096 + 2048 + h * 64 + tx];
    __syncthreads();
#pragma unroll
    for (int i = ty; i < 64; i += 4)
        v_t[(size_t)(bh * 64 + i) * 2048 + l0 + tx] = t[tx][i];
}

// ---------------- fused silu-attention + head-LN*u (KVBLK=128, LPT grid) ----------------
// 512 threads = 8 waves, each wave owns 16 q rows of a 128-row q-tile.
// LPT dispatch: qt = 15 - (bid>>5), bh = bid&31 -> heavy blocks dispatched first.
__global__ __launch_bounds__(512) void attn_kernel(
    const bf16* __restrict__ qkuv, const bf16* __restrict__ v_t,
    const float* __restrict__ nag, const float* __restrict__ nab,
    bf16* __restrict__ au)
{
    __shared__ __align__(16) bf16 lK[2][128 * 64];
    __shared__ __align__(16) bf16 lV[2][64 * 128];
    const int tid = threadIdx.x;
    const int wid = tid >> 6, lane = tid & 63;
    const int lhi = lane >> 4, llo = lane & 15;
    const int bid = (int)blockIdx.x;
    const int qt = 15 - (bid >> 5);                       // heavy blocks dispatched first
    const int bh = bid & 31;
    const int b = bh >> 4, h = bh & 15;
    const int q0 = qt << 7;
    const bf16* Qb = qkuv + (size_t)b * 2048 * 4096 + h * 64;
    const bf16* Kb = Qb + 1024;
    const bf16* Ub = Qb + 3072;
    const bf16* Vb = v_t + (size_t)bh * 64 * 2048;
    const int wbase = wid << 6;

    auto stage = [&](int kt_s, int buf) {
        const int koff = kt_s << 7;
        char* lKc = (char*)lK[buf];
        char* lVc = (char*)lV[buf];
#pragma unroll
        for (int it = 0; it < 2; ++it) {
            const int p = it * 512 + wbase + lane;
            const int r = p >> 3, pc = p & 7;
            const int lc = pc ^ (r & 7);
            load_lds16(Kb + (size_t)(koff + r) * 4096 + lc * 8, lKc + (it * 512 + wbase) * 16);
        }
#pragma unroll
        for (int it = 0; it < 2; ++it) {
            const int p = it * 512 + wbase + lane;
            const int d = p >> 4, pc = p & 15;
            const int lc = pc ^ (d & 15);
            load_lds16(Vb + (size_t)d * 2048 + koff + lc * 8, lVc + (it * 512 + wbase) * 16);
        }
    };

    // hoist Q B-frags: q = wid*16 + llo, dk = kk*32 + lhi*8
    short8 qb[2];
#pragma unroll
    for (int kk = 0; kk < 2; ++kk)
        qb[kk] = *(const short8*)(Qb + (size_t)(q0 + wid * 16 + llo) * 4096 + kk * 32 + lhi * 8);

    f32x4 acc2[4] = {};

    stage(0, 0);  // prologue prefetch

    for (int kt = 0; kt <= qt; ++kt) {
        const int cur = kt & 1;
        drain_and_sync();                      // staged buf[cur] visible to all waves
        if (kt < qt) stage(kt + 1, cur ^ 1);   // prefetch next tile into other buffer
        const char* lKc = (const char*)lK[cur];
        const char* lVc = (const char*)lV[cur];

        const bool diag = (kt == qt);
#pragma unroll
        for (int m = 0; m < 8; ++m) {
            if (diag && m > wid) break;                    // fully above diagonal
            const int rK = m * 16 + llo;
            const int sw = rK & 7;
            short8 ak0 = *(const short8*)(lKc + rK * 128 + ((lhi ^ sw) << 4));
            short8 ak1 = *(const short8*)(lKc + rK * 128 + (((4 + lhi) ^ sw) << 4));
            f32x4 s = {};
            s = __builtin_amdgcn_mfma_f32_16x16x32_bf16(ak0, qb[0], s, 0, 0, 0);
            s = __builtin_amdgcn_mfma_f32_16x16x32_bf16(ak1, qb[1], s, 0, 0, 0);
            const bool mask = diag && (m == wid);
            bfv4 a16;
#pragma unroll
            for (int r = 0; r < 4; ++r) {
                float xx = s[r] * 0.125f;
                xx = xx * __builtin_amdgcn_rcpf(1.f + __expf(-xx));
                if (mask && (lhi * 4 + r > llo)) xx = 0.f;
                a16[r] = (short)f2bf_bits(xx);
            }
#pragma unroll
            for (int dcol = 0; dcol < 4; ++dcol) {
                const int d = dcol * 16 + llo;
                const int lcV = m * 2 + (lhi >> 1);
                bfv4 bv = *(const bfv4*)(lVc + d * 256 + ((lcV ^ llo) << 4) + (lhi & 1) * 8);
                acc2[dcol] = mfma16(a16, bv, acc2[dcol]);
            }
        }
    }

    // ---- epilogue: LN(d=64) * u ----
#pragma unroll
    for (int r = 0; r < 4; ++r) {
        float vv[4];
        float s = 0.f, ss = 0.f;
#pragma unroll
        for (int dc = 0; dc < 4; ++dc) { vv[dc] = acc2[dc][r]; s += vv[dc]; ss += vv[dc] * vv[dc]; }
#pragma unroll
        for (int o = 1; o < 16; o <<= 1) { s += __shfl_xor(s, o); ss += __shfl_xor(ss, o); }
        const float mu = s * (1.f / 64.f);
        const float rstd = rsqrtf(ss * (1.f / 64.f) - mu * mu + LN_EPS);
        const int q = wid * 16 + lhi * 4 + r;
        const size_t grow = q0 + q;
#pragma unroll
        for (int dc = 0; dc < 4; ++dc) {
            const int c = dc * 16 + llo;
            const float nv = (vv[dc] - mu) * rstd * nag[c] + nab[c];
            const float uu = bf2f(Ub[grow * 4096 + c]);
            au[(size_t)(b * 2048 + grow) * 1024 + h * 64 + c] = f2bf(nv * uu);
        }
    }
}

// ---------------- host launch ----------------
extern "C" void kernel_launch(void* const* d_in, const int* in_sizes, int n_in,
                              void* d_out, int out_size, void* d_ws, size_t ws_size,
                              hipStream_t stream)
{
    const float* x      = (const float*)d_in[0];
    // d_in[1] = attn_mask (tril causal; applied analytically)
    const float* w_qkuv = (const float*)d_in[2];
    const float* w_out  = (const float*)d_in[3];
    const float* w1     = (const float*)d_in[4];
    const float* w2     = (const float*)d_in[5];
    const float* w3     = (const float*)d_in[6];
    const float* ln1g   = (const float*)d_in[7];
    const float* ln1b   = (const float*)d_in[8];
    const float* ln2g   = (const float*)d_in[9];
    const float* ln2b   = (const float*)d_in[10];
    const float* nag    = (const float*)d_in[11];
    const float* nab    = (const float*)d_in[12];
    float* out = (float*)d_out;

    char* ws = (char*)d_ws;
    size_t off = 0;
    auto alloc = [&](size_t bytes) { void* p = ws + off; off += (bytes + 255) & ~(size_t)255; return p; };
    const size_t M = 4096;  // B*L
    bf16* wqkuvT = (bf16*)alloc(4096ull * 1024 * 2);
    bf16* woutT  = (bf16*)alloc(1024ull * 1024 * 2);
    bf16* w1T    = (bf16*)alloc(4096ull * 1024 * 2);
    bf16* w3T    = (bf16*)alloc(4096ull * 1024 * 2);
    bf16* w2T    = (bf16*)alloc(1024ull * 4096 * 2);
    bf16* xn     = (bf16*)alloc(M * 1024 * 2);
    bf16* qkuv   = (bf16*)alloc(M * 4096 * 2);
    bf16* vt     = (bf16*)alloc(32ull * 64 * 2048 * 2);
    bf16* aub    = (bf16*)alloc(M * 1024 * 2);
    float* x2    = (float*)alloc(M * 1024 * 4);
    bf16* xn2    = (bf16*)alloc(M * 1024 * 2);
    bf16* h1     = (bf16*)alloc(M * 4096 * 2);
    (void)ws_size; (void)in_sizes; (void)n_in; (void)out_size;

    dim3 tb(32, 8);
    transpose_all<<<dim3(17408), tb, 0, stream>>>(w_qkuv, w1, w3, w2, w_out,
                                                  wqkuvT, w1T, w3T, w2T, woutT);

    ln_cast<<<M, 256, 0, stream>>>(x, ln1g, ln1b, xn);

    gemm8<0><<<dim3((M / 256) * (4096 / 256)), 512, 0, stream>>>(xn, wqkuvT, qkuv, nullptr, M, 4096, 1024);

    v_trans<<<dim3(2048 / 64, 32), dim3(64, 4), 0, stream>>>(qkuv, vt);

    attn_kernel<<<dim3(512), 512, 0, stream>>>(qkuv, vt, nag, nab, aub);

    gemm_btc<<<dim3((M / 128) * (1024 / 64)), 256, 0, stream>>>(aub, woutT, x2, x, M, 1024, 1024);

    ln_cast<<<M, 256, 0, stream>>>(x2, ln2g, ln2b, xn2);

    gemm_w13_8<<<dim3((M / 256) * (4096 / 128)), 512, 0, stream>>>(xn2, w1T, w3T, h1, M, 4096, 1024);

    gemm_btc<<<dim3((M / 128) * (1024 / 64)), 256, 0, stream>>>(h1, w2T, out, x2, M, 1024, 4096);
}

// Round 23
// 267.494 us; speedup vs baseline: 1.0845x; 1.0258x over previous
//
#include <hip/hip_runtime.h>
#include <hip/hip_bf16.h>

typedef __hip_bfloat16 bf16;
typedef __attribute__((ext_vector_type(8))) short short8;
typedef __attribute__((ext_vector_type(4))) short bfv4;
typedef __attribute__((ext_vector_type(4))) float f32x4;
typedef __attribute__((ext_vector_type(4))) unsigned short us4;

#define LN_EPS 1e-5f

__device__ __forceinline__ float siluf(float x) { return x / (1.f + __expf(-x)); }
__device__ __forceinline__ unsigned short f2bf_bits(float f) {
    bf16 h = __float2bfloat16(f);
    return *reinterpret_cast<unsigned short*>(&h);
}
__device__ __forceinline__ bf16 f2bf(float f) { return __float2bfloat16(f); }
__device__ __forceinline__ float bf2f(bf16 h) { return __bfloat162float(h); }

// async global->LDS, 16B per lane. LDS dest must be wave-uniform base (+lane*16 implicit).
__device__ __forceinline__ void load_lds16(const void* g, void* l) {
    __builtin_amdgcn_global_load_lds((const __attribute__((address_space(1))) void*)g,
                                     (__attribute__((address_space(3))) void*)l, 16, 0, 0);
}

__device__ __forceinline__ f32x4 mfma16(bfv4 a, bfv4 b, f32x4 c) {
    return __builtin_amdgcn_mfma_f32_16x16x16bf16_1k(a, b, c, 0, 0, 0);
}

// explicit RAW drain for global_load_lds before a barrier (rule-#18 class hazard)
__device__ __forceinline__ void drain_and_sync() {
    asm volatile("s_waitcnt vmcnt(0)" ::: "memory");
    __builtin_amdgcn_sched_barrier(0);
    __syncthreads();
}

// counted vmcnt wait (literal), fenced
template <int N>
__device__ __forceinline__ void wait_vmcnt() {
    asm volatile("s_waitcnt vmcnt(%0)" :: "n"(N) : "memory");
}
__device__ __forceinline__ void hard_barrier() {
    __builtin_amdgcn_sched_barrier(0);
    __builtin_amdgcn_s_barrier();
    __builtin_amdgcn_sched_barrier(0);
}
// barrier preceded by lgkmcnt(0): all this wave's ds_reads complete before crossing (WAR safety)
__device__ __forceinline__ void lgkm_barrier() {
    asm volatile("s_waitcnt lgkmcnt(0)" ::: "memory");
    __builtin_amdgcn_sched_barrier(0);
    __builtin_amdgcn_s_barrier();
    __builtin_amdgcn_sched_barrier(0);
}

// fine-phase sync: rendezvous, then wait own ds_reads, then high-prio MFMA
__device__ __forceinline__ void phase_pre() {
    __builtin_amdgcn_sched_barrier(0);
    __builtin_amdgcn_s_barrier();
    asm volatile("s_waitcnt lgkmcnt(0)" ::: "memory");
    __builtin_amdgcn_sched_barrier(0);
    __builtin_amdgcn_s_setprio(1);
}
__device__ __forceinline__ void phase_post() {
    __builtin_amdgcn_s_setprio(0);
    __builtin_amdgcn_sched_barrier(0);
    __builtin_amdgcn_s_barrier();
    __builtin_amdgcn_sched_barrier(0);
}

// XCD-chunked bijective block swizzle (requires nwg % 8 == 0)
__device__ __forceinline__ int xcd_swz(int bid, int nwg) {
    return (bid & 7) * (nwg >> 3) + (bid >> 3);
}

// ---------------- prep: five weight transposes + LN1 in ONE launch (flat grid) ----------------
// ranges: [0,12288) z0-2 = w_qkuv/w1/w3 (K=1024,N=4096); [12288,16384) w2 (K=4096,N=1024);
//         [16384,17408) w_out (K=1024,N=1024); [17408,21504) LN rows of x -> xn
__global__ __launch_bounds__(256) void prep_all(
    const float* __restrict__ s0, const float* __restrict__ s1, const float* __restrict__ s2,
    const float* __restrict__ s3, const float* __restrict__ s4,
    bf16* __restrict__ d0, bf16* __restrict__ d1, bf16* __restrict__ d2,
    bf16* __restrict__ d3, bf16* __restrict__ d4,
    const float* __restrict__ x, const float* __restrict__ g, const float* __restrict__ be,
    bf16* __restrict__ xout)
{
    __shared__ float t[32][33];
    __shared__ float red[10];
    const int bid = (int)blockIdx.x;
    const int tx = threadIdx.x, ty = threadIdx.y;

    if (bid >= 17408) {
        // ---- LayerNorm row (D=1024) -> bf16 ----
        const int row = bid - 17408;
        const int tid = ty * 32 + tx;
        const float4 v = ((const float4*)(x + (size_t)row * 1024))[tid];
        float s = v.x + v.y + v.z + v.w;
        float ss = v.x * v.x + v.y * v.y + v.z * v.z + v.w * v.w;
#pragma unroll
        for (int o = 32; o; o >>= 1) { s += __shfl_down(s, o); ss += __shfl_down(ss, o); }
        const int wid = tid >> 6, lane = tid & 63;
        if (lane == 0) { red[wid] = s; red[4 + wid] = ss; }
        __syncthreads();
        if (tid == 0) {
            float S = red[0] + red[1] + red[2] + red[3];
            float SS = red[4] + red[5] + red[6] + red[7];
            float mu = S * (1.f / 1024.f);
            red[8] = mu;
            red[9] = rsqrtf(SS * (1.f / 1024.f) - mu * mu + LN_EPS);
        }
        __syncthreads();
        const float mu = red[8], rstd = red[9];
        const float4 gg = ((const float4*)g)[tid];
        const float4 bb = ((const float4*)be)[tid];
        us4 o;
        o[0] = f2bf_bits((v.x - mu) * rstd * gg.x + bb.x);
        o[1] = f2bf_bits((v.y - mu) * rstd * gg.y + bb.y);
        o[2] = f2bf_bits((v.z - mu) * rstd * gg.z + bb.z);
        o[3] = f2bf_bits((v.w - mu) * rstd * gg.w + bb.w);
        ((us4*)(xout + (size_t)row * 1024))[tid] = o;
        return;
    }

    // ---- weight transpose+cast: fp32 [K][N] -> bf16 [N][K] ----
    const float* src; bf16* dst; int K, N, nb, kb;
    if (bid < 12288) {
        const int z = bid >> 12, idx = bid & 4095;
        src = (z == 0) ? s0 : (z == 1) ? s1 : s2;
        dst = (z == 0) ? d0 : (z == 1) ? d1 : d2;
        K = 1024; N = 4096;
        nb = (idx & 127) << 5; kb = (idx >> 7) << 5;
    } else if (bid < 16384) {
        const int idx = bid - 12288;
        src = s3; dst = d3; K = 4096; N = 1024;
        nb = (idx & 31) << 5; kb = (idx >> 5) << 5;
    } else {
        const int idx = bid - 16384;
        src = s4; dst = d4; K = 1024; N = 1024;
        nb = (idx & 31) << 5; kb = (idx >> 5) << 5;
    }
#pragma unroll
    for (int i = ty; i < 32; i += 8) t[i][tx] = src[(size_t)(kb + i) * N + nb + tx];
    __syncthreads();
#pragma unroll
    for (int i = ty; i < 32; i += 8) dst[(size_t)(nb + i) * K + kb + tx] = f2bf(t[tx][i]);
}

// ---------------- LayerNorm fp32 row (D=1024) -> bf16 (standalone, for LN2) ----------------
__global__ __launch_bounds__(256) void ln_cast(
    const float* __restrict__ x, const float* __restrict__ g, const float* __restrict__ be,
    bf16* __restrict__ out)
{
    const int row = blockIdx.x, tid = threadIdx.x;
    const float4 v = ((const float4*)(x + (size_t)row * 1024))[tid];
    float s = v.x + v.y + v.z + v.w;
    float ss = v.x * v.x + v.y * v.y + v.z * v.z + v.w * v.w;
#pragma unroll
    for (int o = 32; o; o >>= 1) { s += __shfl_down(s, o); ss += __shfl_down(ss, o); }
    __shared__ float red[10];
    const int wid = tid >> 6, lane = tid & 63;
    if (lane == 0) { red[wid] = s; red[4 + wid] = ss; }
    __syncthreads();
    if (tid == 0) {
        float S = red[0] + red[1] + red[2] + red[3];
        float SS = red[4] + red[5] + red[6] + red[7];
        float mu = S * (1.f / 1024.f);
        red[8] = mu;
        red[9] = rsqrtf(SS * (1.f / 1024.f) - mu * mu + LN_EPS);
    }
    __syncthreads();
    const float mu = red[8], rstd = red[9];
    const float4 gg = ((const float4*)g)[tid];
    const float4 bb = ((const float4*)be)[tid];
    us4 o;
    o[0] = f2bf_bits((v.x - mu) * rstd * gg.x + bb.x);
    o[1] = f2bf_bits((v.y - mu) * rstd * gg.y + bb.y);
    o[2] = f2bf_bits((v.z - mu) * rstd * gg.z + bb.z);
    o[3] = f2bf_bits((v.w - mu) * rstd * gg.w + bb.w);
    ((us4*)(out + (size_t)row * 1024))[tid] = o;
}

// ---------------- 256x256 bf16 GEMM, 4-phase fine interleave, distance-1 dbuf ----------------
// Column-major block order (B-panels L2-resident; A reused across bx).
// EPI: 0 = bf16 silu(acc)
template <int EPI>
__global__ __launch_bounds__(512, 2) void gemm8(
    const bf16* __restrict__ A, const bf16* __restrict__ BT,
    bf16* __restrict__ outp, const bf16* __restrict__ mulsrc,
    int M, int N, int K)
{
    __shared__ __align__(16) bf16 lds[2][2][256 * 64];   // [buf][A=0/B=1][row*64+col]
    const int tid = threadIdx.x;
    const int wid = tid >> 6, lane = tid & 63;
    const int lhi = lane >> 4, llo = lane & 15;
    const int nby = M >> 8;
    const int bid = xcd_swz((int)blockIdx.x, (int)gridDim.x);
    const int by = bid % nby, bx = bid / nby;            // column-major
    const int row0 = by << 8, col0 = bx << 8;
    const int wr = wid >> 2, wc = wid & 3;               // 2M x 4N
    const int wbase = wid << 6;

    auto stage_tile = [&](const bf16* src, int r0, int k0, char* ldsbase) {
#pragma unroll
        for (int it = 0; it < 4; ++it) {
            const int p = it * 512 + wbase + lane;       // physical 16B-chunk index
            const int r = p >> 3, pc = p & 7;
            const int lc = pc ^ (r & 7);                 // logical chunk this slot holds
            load_lds16(src + (size_t)(r0 + r) * K + k0 + lc * 8,
                       ldsbase + (size_t)(it * 512 + wbase) * 16);
        }
    };
    auto stageA = [&](int t) { stage_tile(A, row0, t << 6, (char*)lds[t & 1][0]); };
    auto stageB = [&](int t) { stage_tile(BT, col0, t << 6, (char*)lds[t & 1][1]); };

    f32x4 acc[8][4] = {};

    // prologue: T0 only
    stageA(0); stageB(0);
    wait_vmcnt<0>();
    hard_barrier();

    const int KT = K >> 6;
    for (int t = 0; t < KT; ++t) {
        const bool more = (t + 1 < KT);
        const char* lAc = (const char*)lds[t & 1][0];
        const char* lBc = (const char*)lds[t & 1][1];

        short8 a0[2][4], a1[2][4], b0[2][2], b1[2][2];   // [kk][frag]
        auto ldA = [&](short8 af[2][4], int mh) {
#pragma unroll
            for (int kk = 0; kk < 2; ++kk)
#pragma unroll
                for (int m = 0; m < 4; ++m) {
                    const int ra = wr * 128 + mh * 64 + m * 16 + llo;
                    af[kk][m] = *(const short8*)(lAc + ra * 128 + (((kk * 4 + lhi) ^ (ra & 7)) << 4));
                }
        };
        auto ldB = [&](short8 bf_[2][2], int nh) {
#pragma unroll
            for (int kk = 0; kk < 2; ++kk)
#pragma unroll
                for (int n = 0; n < 2; ++n) {
                    const int rb = wc * 64 + nh * 32 + n * 16 + llo;
                    bf_[kk][n] = *(const short8*)(lBc + rb * 128 + (((kk * 4 + lhi) ^ (rb & 7)) << 4));
                }
        };
        auto mfma_q = [&](int mh, int nh, short8 af[2][4], short8 bf_[2][2]) {
#pragma unroll
            for (int kk = 0; kk < 2; ++kk)
#pragma unroll
                for (int m = 0; m < 4; ++m)
#pragma unroll
                    for (int n = 0; n < 2; ++n)
                        acc[mh * 4 + m][nh * 2 + n] =
                            __builtin_amdgcn_mfma_f32_16x16x32_bf16(af[kk][m], bf_[kk][n], acc[mh * 4 + m][nh * 2 + n], 0, 0, 0);
        };

        // P1: quadrant (0,0); stage A(t+1)
        ldA(a0, 0); ldB(b0, 0);
        if (more) stageA(t + 1);
        phase_pre(); mfma_q(0, 0, a0, b0); phase_post();
        // P2: quadrant (0,1); stage B(t+1)
        ldB(b1, 1);
        if (more) stageB(t + 1);
        phase_pre(); mfma_q(0, 1, a0, b1); phase_post();
        // P3: quadrant (1,1)
        ldA(a1, 1);
        phase_pre(); mfma_q(1, 1, a1, b1); phase_post();
        // P4: quadrant (1,0)
        phase_pre(); mfma_q(1, 0, a1, b0); phase_post();

        if (more) { wait_vmcnt<0>(); hard_barrier(); }   // T_{t+1} landed (loads >=2 phases old)
    }

#pragma unroll
    for (int m = 0; m < 8; ++m) {
        const int rbase = row0 + wr * 128 + m * 16 + lhi * 4;
#pragma unroll
        for (int n = 0; n < 4; ++n) {
            const int c = col0 + wc * 64 + n * 16 + llo;
#pragma unroll
            for (int r = 0; r < 4; ++r) {
                const size_t idx = (size_t)(rbase + r) * N + c;
                const float v = acc[m][n][r];
                if constexpr (EPI == 0) outp[idx] = f2bf(siluf(v));
                else                    outp[idx] = f2bf(v * bf2f(mulsrc[idx]));
            }
        }
    }
}

// ---------------- fused FFN: h1 = silu(A@W1) * (A@W3), 4-phase fine interleave ----------------
// Column-major block order: B1+B3 panels (2 MB) L2-resident.
__global__ __launch_bounds__(512, 2) void gemm_w13_8(
    const bf16* __restrict__ A, const bf16* __restrict__ B1T, const bf16* __restrict__ B3T,
    bf16* __restrict__ outp, int M, int N, int K)
{
    __shared__ __align__(16) bf16 lA[2][256 * 64];
    __shared__ __align__(16) bf16 lB1[2][128 * 64];
    __shared__ __align__(16) bf16 lB3[2][128 * 64];
    const int tid = threadIdx.x;
    const int wid = tid >> 6, lane = tid & 63;
    const int lhi = lane >> 4, llo = lane & 15;
    const int nby = M >> 8;
    const int bid = xcd_swz((int)blockIdx.x, (int)gridDim.x);
    const int by = bid % nby, bx = bid / nby;            // column-major
    const int row0 = by << 8, col0 = bx << 7;
    const int wr = wid >> 2, wc = wid & 3;               // 2M x 4N
    const int wbase = wid << 6;

    auto stage_rows = [&](const bf16* src, int r0, int k0, char* ldsbase, int nit) {
        for (int it = 0; it < nit; ++it) {
            const int p = it * 512 + wbase + lane;
            const int r = p >> 3, pc = p & 7;
            const int lc = pc ^ (r & 7);
            load_lds16(src + (size_t)(r0 + r) * K + k0 + lc * 8,
                       ldsbase + (size_t)(it * 512 + wbase) * 16);
        }
    };
    auto stageA = [&](int t) { stage_rows(A, row0, t << 6, (char*)lA[t & 1], 4); };
    auto stageB = [&](int t) {
        stage_rows(B1T, col0, t << 6, (char*)lB1[t & 1], 2);
        stage_rows(B3T, col0, t << 6, (char*)lB3[t & 1], 2);
    };

    f32x4 acc1[8][2] = {}, acc3[8][2] = {};

    stageA(0); stageB(0);
    wait_vmcnt<0>();
    hard_barrier();

    const int KT = K >> 6;
    for (int t = 0; t < KT; ++t) {
        const bool more = (t + 1 < KT);
        const char* lAc = (const char*)lA[t & 1];
        const char* lB1c = (const char*)lB1[t & 1];
        const char* lB3c = (const char*)lB3[t & 1];

        short8 b1f[2], b3f[2];                           // current-kk B frags
        auto ldA4 = [&](short8 af[4], int mh, int kk) {
#pragma unroll
            for (int m = 0; m < 4; ++m) {
                const int ra = wr * 128 + mh * 64 + m * 16 + llo;
                af[m] = *(const short8*)(lAc + ra * 128 + (((kk * 4 + lhi) ^ (ra & 7)) << 4));
            }
        };
        auto ldBk = [&](int kk) {
#pragma unroll
            for (int n = 0; n < 2; ++n) {
                const int rb = wc * 32 + n * 16 + llo;
                const int so = (((kk * 4 + lhi) ^ (rb & 7)) << 4);
                b1f[n] = *(const short8*)(lB1c + rb * 128 + so);
                b3f[n] = *(const short8*)(lB3c + rb * 128 + so);
            }
        };
        auto mfma_p = [&](short8 af[4], int mh) {
#pragma unroll
            for (int m = 0; m < 4; ++m)
#pragma unroll
                for (int n = 0; n < 2; ++n) {
                    acc1[mh * 4 + m][n] = __builtin_amdgcn_mfma_f32_16x16x32_bf16(af[m], b1f[n], acc1[mh * 4 + m][n], 0, 0, 0);
                    acc3[mh * 4 + m][n] = __builtin_amdgcn_mfma_f32_16x16x32_bf16(af[m], b3f[n], acc3[mh * 4 + m][n], 0, 0, 0);
                }
        };

        short8 af[4];
        // P1: (mh0, kk0); stage A(t+1)
        ldA4(af, 0, 0); ldBk(0);
        if (more) stageA(t + 1);
        phase_pre(); mfma_p(af, 0); phase_post();
        // P2: (mh1, kk0); stage B(t+1)
        ldA4(af, 1, 0);
        if (more) stageB(t + 1);
        phase_pre(); mfma_p(af, 1); phase_post();
        // P3: (mh0, kk1)
        ldA4(af, 0, 1); ldBk(1);
        phase_pre(); mfma_p(af, 0); phase_post();
        // P4: (mh1, kk1)
        ldA4(af, 1, 1);
        phase_pre(); mfma_p(af, 1); phase_post();

        if (more) { wait_vmcnt<0>(); hard_barrier(); }
    }

    // epilogue: silu(c1) * c3, wave-local
#pragma unroll
    for (int m = 0; m < 8; ++m) {
        const int rbase = row0 + wr * 128 + m * 16 + lhi * 4;
#pragma unroll
        for (int n = 0; n < 2; ++n) {
            const int c = col0 + wc * 32 + n * 16 + llo;
#pragma unroll
            for (int r = 0; r < 4; ++r) {
                const size_t idx = (size_t)(rbase + r) * N + c;
                outp[idx] = f2bf(siluf(acc1[m][n][r]) * acc3[m][n][r]);
            }
        }
    }
}

// ---------------- 128x64 bf16 GEMM, 2-phase fine interleave, distance-1 dbuf (N=1024) ----------------
// ROW-major block order: A-slab L2-resident (right for K-large/N-small: w2).
__global__ __launch_bounds__(256) void gemm_btc(
    const bf16* __restrict__ A, const bf16* __restrict__ BT,
    float* __restrict__ outp, const float* __restrict__ resid,
    int M, int N, int K)
{
    __shared__ __align__(16) bf16 lA[2][128 * 64];
    __shared__ __align__(16) bf16 lB[2][64 * 64];
    const int tid = threadIdx.x;
    const int wid = tid >> 6, lane = tid & 63;
    const int lhi = lane >> 4, llo = lane & 15;
    const int ntx = N >> 6;
    const int bid = xcd_swz((int)blockIdx.x, (int)gridDim.x);
    const int bx = bid % ntx, by = bid / ntx;            // row-major
    const int row0 = by << 7, col0 = bx << 6;
    const int wr = wid >> 1, wc = wid & 1;               // 2M x 2N
    const int wbase = wid << 6;

    auto stage_tile = [&](const bf16* src, int r0, int k0, char* ldsbase, int nit) {
        for (int it = 0; it < nit; ++it) {
            const int p = it * 256 + wbase + lane;
            const int r = p >> 3, pc = p & 7;
            const int lc = pc ^ (r & 7);
            load_lds16(src + (size_t)(r0 + r) * K + k0 + lc * 8,
                       ldsbase + (size_t)(it * 256 + wbase) * 16);
        }
    };
    auto stageT = [&](int t) {
        stage_tile(A, row0, t << 6, (char*)lA[t & 1], 4);
        stage_tile(BT, col0, t << 6, (char*)lB[t & 1], 2);
    };

    f32x4 acc[4][2] = {};

    stageT(0);
    wait_vmcnt<0>();
    hard_barrier();

    const int KT = K >> 6;
    for (int t = 0; t < KT; ++t) {
        const bool more = (t + 1 < KT);
        const int buf = t & 1;
        const char* lAc = (const char*)lA[buf];
        const char* lBc = (const char*)lB[buf];

        short8 af[4], bfr[2];
        auto ldA = [&](int kk) {
#pragma unroll
            for (int m = 0; m < 4; ++m) {
                const int ra = wr * 64 + m * 16 + llo;
                af[m] = *(const short8*)(lAc + ra * 128 + (((kk * 4 + lhi) ^ (ra & 7)) << 4));
            }
        };
        auto ldB = [&](int kk) {
#pragma unroll
            for (int n = 0; n < 2; ++n) {
                const int rb = wc * 32 + n * 16 + llo;
                bfr[n] = *(const short8*)(lBc + rb * 128 + (((kk * 4 + lhi) ^ (rb & 7)) << 4));
            }
        };
        auto mfma8 = [&]() {
#pragma unroll
            for (int m = 0; m < 4; ++m)
#pragma unroll
                for (int n = 0; n < 2; ++n)
                    acc[m][n] = __builtin_amdgcn_mfma_f32_16x16x32_bf16(af[m], bfr[n], acc[m][n], 0, 0, 0);
        };

        // P1: kk0; stage T_{t+1} into buf^1
        ldA(0); ldB(0);
        if (more) stageT(t + 1);
        phase_pre(); mfma8(); phase_post();
        // P2: kk1
        ldA(1); ldB(1);
        phase_pre(); mfma8(); phase_post();

        if (more) { wait_vmcnt<0>(); hard_barrier(); }   // T_{t+1} landed
    }

#pragma unroll
    for (int m = 0; m < 4; ++m) {
        const int rbase = row0 + wr * 64 + m * 16 + lhi * 4;
#pragma unroll
        for (int n = 0; n < 2; ++n) {
            const int c = col0 + wc * 32 + n * 16 + llo;
#pragma unroll
            for (int r = 0; r < 4; ++r) {
                const size_t idx = (size_t)(rbase + r) * N + c;
                outp[idx] = resid[idx] + acc[m][n][r];
            }
        }
    }
}

// ---------------- V transpose: qkuv v-quarter [B][L][H*64] -> v_t [B*H][64][L] ----------------
__global__ __launch_bounds__(256) void v_trans(const bf16* __restrict__ qkuv, bf16* __restrict__ v_t)
{
    __shared__ bf16 t[64][65];
    const int bh = blockIdx.y;         // b*16+h
    const int b = bh >> 4, h = bh & 15;
    const int l0 = blockIdx.x << 6;
    const int tx = threadIdx.x, ty = threadIdx.y;
#pragma unroll
    for (int i = ty; i < 64; i += 4)
        t[i][tx] = qkuv[(size_t)(b * 2048 + l0 + i) * 4096 + 2048 + h * 64 + tx];
    __syncthreads();
#pragma unroll
    for (int i = ty; i < 64; i += 4)
        v_t[(size_t)(bh * 64 + i) * 2048 + l0 + tx] = t[tx][i];
}

// ---------------- fused silu-attention + head-LN*u (KVBLK=128, LPT grid) ----------------
// 512 threads = 8 waves, each wave owns 16 q rows of a 128-row q-tile.
// LPT dispatch: qt = 15 - (bid>>5), bh = bid&31 -> heavy blocks dispatched first.
__global__ __launch_bounds__(512) void attn_kernel(
    const bf16* __restrict__ qkuv, const bf16* __restrict__ v_t,
    const float* __restrict__ nag, const float* __restrict__ nab,
    bf16* __restrict__ au)
{
    __shared__ __align__(16) bf16 lK[2][128 * 64];
    __shared__ __align__(16) bf16 lV[2][64 * 128];
    const int tid = threadIdx.x;
    const int wid = tid >> 6, lane = tid & 63;
    const int lhi = lane >> 4, llo = lane & 15;
    const int bid = (int)blockIdx.x;
    const int qt = 15 - (bid >> 5);                       // heavy blocks dispatched first
    const int bh = bid & 31;
    const int b = bh >> 4, h = bh & 15;
    const int q0 = qt << 7;
    const bf16* Qb = qkuv + (size_t)b * 2048 * 4096 + h * 64;
    const bf16* Kb = Qb + 1024;
    const bf16* Ub = Qb + 3072;
    const bf16* Vb = v_t + (size_t)bh * 64 * 2048;
    const int wbase = wid << 6;

    auto stage = [&](int kt_s, int buf) {
        const int koff = kt_s << 7;
        char* lKc = (char*)lK[buf];
        char* lVc = (char*)lV[buf];
#pragma unroll
        for (int it = 0; it < 2; ++it) {
            const int p = it * 512 + wbase + lane;
            const int r = p >> 3, pc = p & 7;
            const int lc = pc ^ (r & 7);
            load_lds16(Kb + (size_t)(koff + r) * 4096 + lc * 8, lKc + (it * 512 + wbase) * 16);
        }
#pragma unroll
        for (int it = 0; it < 2; ++it) {
            const int p = it * 512 + wbase + lane;
            const int d = p >> 4, pc = p & 15;
            const int lc = pc ^ (d & 15);
            load_lds16(Vb + (size_t)d * 2048 + koff + lc * 8, lVc + (it * 512 + wbase) * 16);
        }
    };

    // hoist Q B-frags: q = wid*16 + llo, dk = kk*32 + lhi*8
    short8 qb[2];
#pragma unroll
    for (int kk = 0; kk < 2; ++kk)
        qb[kk] = *(const short8*)(Qb + (size_t)(q0 + wid * 16 + llo) * 4096 + kk * 32 + lhi * 8);

    f32x4 acc2[4] = {};

    stage(0, 0);  // prologue prefetch

    for (int kt = 0; kt <= qt; ++kt) {
        const int cur = kt & 1;
        drain_and_sync();                      // staged buf[cur] visible to all waves
        if (kt < qt) stage(kt + 1, cur ^ 1);   // prefetch next tile into other buffer
        const char* lKc = (const char*)lK[cur];
        const char* lVc = (const char*)lV[cur];

        const bool diag = (kt == qt);
#pragma unroll
        for (int m = 0; m < 8; ++m) {
            if (diag && m > wid) break;                    // fully above diagonal
            const int rK = m * 16 + llo;
            const int sw = rK & 7;
            short8 ak0 = *(const short8*)(lKc + rK * 128 + ((lhi ^ sw) << 4));
            short8 ak1 = *(const short8*)(lKc + rK * 128 + (((4 + lhi) ^ sw) << 4));
            f32x4 s = {};
            s = __builtin_amdgcn_mfma_f32_16x16x32_bf16(ak0, qb[0], s, 0, 0, 0);
            s = __builtin_amdgcn_mfma_f32_16x16x32_bf16(ak1, qb[1], s, 0, 0, 0);
            const bool mask = diag && (m == wid);
            bfv4 a16;
#pragma unroll
            for (int r = 0; r < 4; ++r) {
                float xx = s[r] * 0.125f;
                xx = xx * __builtin_amdgcn_rcpf(1.f + __expf(-xx));
                if (mask && (lhi * 4 + r > llo)) xx = 0.f;
                a16[r] = (short)f2bf_bits(xx);
            }
#pragma unroll
            for (int dcol = 0; dcol < 4; ++dcol) {
                const int d = dcol * 16 + llo;
                const int lcV = m * 2 + (lhi >> 1);
                bfv4 bv = *(const bfv4*)(lVc + d * 256 + ((lcV ^ llo) << 4) + (lhi & 1) * 8);
                acc2[dcol] = mfma16(a16, bv, acc2[dcol]);
            }
        }
    }

    // ---- epilogue: LN(d=64) * u ----
#pragma unroll
    for (int r = 0; r < 4; ++r) {
        float vv[4];
        float s = 0.f, ss = 0.f;
#pragma unroll
        for (int dc = 0; dc < 4; ++dc) { vv[dc] = acc2[dc][r]; s += vv[dc]; ss += vv[dc] * vv[dc]; }
#pragma unroll
        for (int o = 1; o < 16; o <<= 1) { s += __shfl_xor(s, o); ss += __shfl_xor(ss, o); }
        const float mu = s * (1.f / 64.f);
        const float rstd = rsqrtf(ss * (1.f / 64.f) - mu * mu + LN_EPS);
        const int q = wid * 16 + lhi * 4 + r;
        const size_t grow = q0 + q;
#pragma unroll
        for (int dc = 0; dc < 4; ++dc) {
            const int c = dc * 16 + llo;
            const float nv = (vv[dc] - mu) * rstd * nag[c] + nab[c];
            const float uu = bf2f(Ub[grow * 4096 + c]);
            au[(size_t)(b * 2048 + grow) * 1024 + h * 64 + c] = f2bf(nv * uu);
        }
    }
}

// ---------------- host launch ----------------
extern "C" void kernel_launch(void* const* d_in, const int* in_sizes, int n_in,
                              void* d_out, int out_size, void* d_ws, size_t ws_size,
                              hipStream_t stream)
{
    const float* x      = (const float*)d_in[0];
    // d_in[1] = attn_mask (tril causal; applied analytically)
    const float* w_qkuv = (const float*)d_in[2];
    const float* w_out  = (const float*)d_in[3];
    const float* w1     = (const float*)d_in[4];
    const float* w2     = (const float*)d_in[5];
    const float* w3     = (const float*)d_in[6];
    const float* ln1g   = (const float*)d_in[7];
    const float* ln1b   = (const float*)d_in[8];
    const float* ln2g   = (const float*)d_in[9];
    const float* ln2b   = (const float*)d_in[10];
    const float* nag    = (const float*)d_in[11];
    const float* nab    = (const float*)d_in[12];
    float* out = (float*)d_out;

    char* ws = (char*)d_ws;
    size_t off = 0;
    auto alloc = [&](size_t bytes) { void* p = ws + off; off += (bytes + 255) & ~(size_t)255; return p; };
    const size_t M = 4096;  // B*L
    bf16* wqkuvT = (bf16*)alloc(4096ull * 1024 * 2);
    bf16* woutT  = (bf16*)alloc(1024ull * 1024 * 2);
    bf16* w1T    = (bf16*)alloc(4096ull * 1024 * 2);
    bf16* w3T    = (bf16*)alloc(4096ull * 1024 * 2);
    bf16* w2T    = (bf16*)alloc(1024ull * 4096 * 2);
    bf16* xn     = (bf16*)alloc(M * 1024 * 2);
    bf16* qkuv   = (bf16*)alloc(M * 4096 * 2);
    bf16* vt     = (bf16*)alloc(32ull * 64 * 2048 * 2);
    bf16* aub    = (bf16*)alloc(M * 1024 * 2);
    float* x2    = (float*)alloc(M * 1024 * 4);
    bf16* xn2    = (bf16*)alloc(M * 1024 * 2);
    bf16* h1     = (bf16*)alloc(M * 4096 * 2);
    (void)ws_size; (void)in_sizes; (void)n_in; (void)out_size;

    dim3 tb(32, 8);
    prep_all<<<dim3(21504), tb, 0, stream>>>(w_qkuv, w1, w3, w2, w_out,
                                             wqkuvT, w1T, w3T, w2T, woutT,
                                             x, ln1g, ln1b, xn);

    gemm8<0><<<dim3((M / 256) * (4096 / 256)), 512, 0, stream>>>(xn, wqkuvT, qkuv, nullptr, M, 4096, 1024);

    v_trans<<<dim3(2048 / 64, 32), dim3(64, 4), 0, stream>>>(qkuv, vt);

    attn_kernel<<<dim3(512), 512, 0, stream>>>(qkuv, vt, nag, nab, aub);

    gemm_btc<<<dim3((M / 128) * (1024 / 64)), 256, 0, stream>>>(aub, woutT, x2, x, M, 1024, 1024);

    ln_cast<<<M, 256, 0, stream>>>(x2, ln2g, ln2b, xn2);

    gemm_w13_8<<<dim3((M / 256) * (4096 / 128)), 512, 0, stream>>>(xn2, w1T, w3T, h1, M, 4096, 1024);

    gemm_btc<<<dim3((M / 128) * (1024 / 64)), 256, 0, stream>>>(h1, w2T, out, x2, M, 1024, 4096);
}

// Round 24
// 267.187 us; speedup vs baseline: 1.0858x; 1.0011x over previous
//
#include <hip/hip_runtime.h>
#include <hip/hip_bf16.h>

typedef __hip_bfloat16 bf16;
typedef __attribute__((ext_vector_type(8))) short short8;
typedef __attribute__((ext_vector_type(4))) short bfv4;
typedef __attribute__((ext_vector_type(4))) float f32x4;
typedef __attribute__((ext_vector_type(4))) unsigned short us4;

#define LN_EPS 1e-5f

__device__ __forceinline__ float siluf(float x) { return x / (1.f + __expf(-x)); }
__device__ __forceinline__ unsigned short f2bf_bits(float f) {
    bf16 h = __float2bfloat16(f);
    return *reinterpret_cast<unsigned short*>(&h);
}
__device__ __forceinline__ bf16 f2bf(float f) { return __float2bfloat16(f); }
__device__ __forceinline__ float bf2f(bf16 h) { return __bfloat162float(h); }

// async global->LDS, 16B per lane. LDS dest must be wave-uniform base (+lane*16 implicit).
__device__ __forceinline__ void load_lds16(const void* g, void* l) {
    __builtin_amdgcn_global_load_lds((const __attribute__((address_space(1))) void*)g,
                                     (__attribute__((address_space(3))) void*)l, 16, 0, 0);
}

__device__ __forceinline__ f32x4 mfma16(bfv4 a, bfv4 b, f32x4 c) {
    return __builtin_amdgcn_mfma_f32_16x16x16bf16_1k(a, b, c, 0, 0, 0);
}

// explicit RAW drain for global_load_lds before a barrier (rule-#18 class hazard)
__device__ __forceinline__ void drain_and_sync() {
    asm volatile("s_waitcnt vmcnt(0)" ::: "memory");
    __builtin_amdgcn_sched_barrier(0);
    __syncthreads();
}

// counted vmcnt wait (literal), fenced
template <int N>
__device__ __forceinline__ void wait_vmcnt() {
    asm volatile("s_waitcnt vmcnt(%0)" :: "n"(N) : "memory");
}
__device__ __forceinline__ void hard_barrier() {
    __builtin_amdgcn_sched_barrier(0);
    __builtin_amdgcn_s_barrier();
    __builtin_amdgcn_sched_barrier(0);
}

// fine-phase sync: rendezvous, then wait own ds_reads, then high-prio MFMA
__device__ __forceinline__ void phase_pre() {
    __builtin_amdgcn_sched_barrier(0);
    __builtin_amdgcn_s_barrier();
    asm volatile("s_waitcnt lgkmcnt(0)" ::: "memory");
    __builtin_amdgcn_sched_barrier(0);
    __builtin_amdgcn_s_setprio(1);
}
__device__ __forceinline__ void phase_post() {
    __builtin_amdgcn_s_setprio(0);
    __builtin_amdgcn_sched_barrier(0);
    __builtin_amdgcn_s_barrier();
    __builtin_amdgcn_sched_barrier(0);
}
// merged phase_post + K-tile boundary: single barrier with own-wave vmcnt(0) drain.
// Equivalent to {phase_post(); wait_vmcnt<0>(); hard_barrier()} — every wave drains its
// staging loads before the rendezvous, so staged T_{t+1} is visible afterwards.
__device__ __forceinline__ void phase_post_drain() {
    __builtin_amdgcn_s_setprio(0);
    __builtin_amdgcn_sched_barrier(0);
    asm volatile("s_waitcnt vmcnt(0)" ::: "memory");
    __builtin_amdgcn_sched_barrier(0);
    __builtin_amdgcn_s_barrier();
    __builtin_amdgcn_sched_barrier(0);
}

// XCD-chunked bijective block swizzle (requires nwg % 8 == 0)
__device__ __forceinline__ int xcd_swz(int bid, int nwg) {
    return (bid & 7) * (nwg >> 3) + (bid >> 3);
}

// ---------------- prep: five weight transposes + LN1 in ONE launch (flat grid) ----------------
// ranges: [0,12288) z0-2 = w_qkuv/w1/w3 (K=1024,N=4096); [12288,16384) w2 (K=4096,N=1024);
//         [16384,17408) w_out (K=1024,N=1024); [17408,21504) LN rows of x -> xn
__global__ __launch_bounds__(256) void prep_all(
    const float* __restrict__ s0, const float* __restrict__ s1, const float* __restrict__ s2,
    const float* __restrict__ s3, const float* __restrict__ s4,
    bf16* __restrict__ d0, bf16* __restrict__ d1, bf16* __restrict__ d2,
    bf16* __restrict__ d3, bf16* __restrict__ d4,
    const float* __restrict__ x, const float* __restrict__ g, const float* __restrict__ be,
    bf16* __restrict__ xout)
{
    __shared__ float t[32][33];
    __shared__ float red[10];
    const int bid = (int)blockIdx.x;
    const int tx = threadIdx.x, ty = threadIdx.y;

    if (bid >= 17408) {
        // ---- LayerNorm row (D=1024) -> bf16 ----
        const int row = bid - 17408;
        const int tid = ty * 32 + tx;
        const float4 v = ((const float4*)(x + (size_t)row * 1024))[tid];
        float s = v.x + v.y + v.z + v.w;
        float ss = v.x * v.x + v.y * v.y + v.z * v.z + v.w * v.w;
#pragma unroll
        for (int o = 32; o; o >>= 1) { s += __shfl_down(s, o); ss += __shfl_down(ss, o); }
        const int wid = tid >> 6, lane = tid & 63;
        if (lane == 0) { red[wid] = s; red[4 + wid] = ss; }
        __syncthreads();
        if (tid == 0) {
            float S = red[0] + red[1] + red[2] + red[3];
            float SS = red[4] + red[5] + red[6] + red[7];
            float mu = S * (1.f / 1024.f);
            red[8] = mu;
            red[9] = rsqrtf(SS * (1.f / 1024.f) - mu * mu + LN_EPS);
        }
        __syncthreads();
        const float mu = red[8], rstd = red[9];
        const float4 gg = ((const float4*)g)[tid];
        const float4 bb = ((const float4*)be)[tid];
        us4 o;
        o[0] = f2bf_bits((v.x - mu) * rstd * gg.x + bb.x);
        o[1] = f2bf_bits((v.y - mu) * rstd * gg.y + bb.y);
        o[2] = f2bf_bits((v.z - mu) * rstd * gg.z + bb.z);
        o[3] = f2bf_bits((v.w - mu) * rstd * gg.w + bb.w);
        ((us4*)(xout + (size_t)row * 1024))[tid] = o;
        return;
    }

    // ---- weight transpose+cast: fp32 [K][N] -> bf16 [N][K] ----
    const float* src; bf16* dst; int K, N, nb, kb;
    if (bid < 12288) {
        const int z = bid >> 12, idx = bid & 4095;
        src = (z == 0) ? s0 : (z == 1) ? s1 : s2;
        dst = (z == 0) ? d0 : (z == 1) ? d1 : d2;
        K = 1024; N = 4096;
        nb = (idx & 127) << 5; kb = (idx >> 7) << 5;
    } else if (bid < 16384) {
        const int idx = bid - 12288;
        src = s3; dst = d3; K = 4096; N = 1024;
        nb = (idx & 31) << 5; kb = (idx >> 5) << 5;
    } else {
        const int idx = bid - 16384;
        src = s4; dst = d4; K = 1024; N = 1024;
        nb = (idx & 31) << 5; kb = (idx >> 5) << 5;
    }
#pragma unroll
    for (int i = ty; i < 32; i += 8) t[i][tx] = src[(size_t)(kb + i) * N + nb + tx];
    __syncthreads();
#pragma unroll
    for (int i = ty; i < 32; i += 8) dst[(size_t)(nb + i) * K + kb + tx] = f2bf(t[tx][i]);
}

// ---------------- LayerNorm fp32 row (D=1024) -> bf16 (standalone, for LN2) ----------------
__global__ __launch_bounds__(256) void ln_cast(
    const float* __restrict__ x, const float* __restrict__ g, const float* __restrict__ be,
    bf16* __restrict__ out)
{
    const int row = blockIdx.x, tid = threadIdx.x;
    const float4 v = ((const float4*)(x + (size_t)row * 1024))[tid];
    float s = v.x + v.y + v.z + v.w;
    float ss = v.x * v.x + v.y * v.y + v.z * v.z + v.w * v.w;
#pragma unroll
    for (int o = 32; o; o >>= 1) { s += __shfl_down(s, o); ss += __shfl_down(ss, o); }
    __shared__ float red[10];
    const int wid = tid >> 6, lane = tid & 63;
    if (lane == 0) { red[wid] = s; red[4 + wid] = ss; }
    __syncthreads();
    if (tid == 0) {
        float S = red[0] + red[1] + red[2] + red[3];
        float SS = red[4] + red[5] + red[6] + red[7];
        float mu = S * (1.f / 1024.f);
        red[8] = mu;
        red[9] = rsqrtf(SS * (1.f / 1024.f) - mu * mu + LN_EPS);
    }
    __syncthreads();
    const float mu = red[8], rstd = red[9];
    const float4 gg = ((const float4*)g)[tid];
    const float4 bb = ((const float4*)be)[tid];
    us4 o;
    o[0] = f2bf_bits((v.x - mu) * rstd * gg.x + bb.x);
    o[1] = f2bf_bits((v.y - mu) * rstd * gg.y + bb.y);
    o[2] = f2bf_bits((v.z - mu) * rstd * gg.z + bb.z);
    o[3] = f2bf_bits((v.w - mu) * rstd * gg.w + bb.w);
    ((us4*)(out + (size_t)row * 1024))[tid] = o;
}

// ---------------- 256x256 bf16 GEMM, 4-phase fine interleave, distance-1 dbuf ----------------
// Column-major block order (B-panels L2-resident; A reused across bx).
// EPI: 0 = bf16 silu(acc)
template <int EPI>
__global__ __launch_bounds__(512, 2) void gemm8(
    const bf16* __restrict__ A, const bf16* __restrict__ BT,
    bf16* __restrict__ outp, const bf16* __restrict__ mulsrc,
    int M, int N, int K)
{
    __shared__ __align__(16) bf16 lds[2][2][256 * 64];   // [buf][A=0/B=1][row*64+col]
    const int tid = threadIdx.x;
    const int wid = tid >> 6, lane = tid & 63;
    const int lhi = lane >> 4, llo = lane & 15;
    const int nby = M >> 8;
    const int bid = xcd_swz((int)blockIdx.x, (int)gridDim.x);
    const int by = bid % nby, bx = bid / nby;            // column-major
    const int row0 = by << 8, col0 = bx << 8;
    const int wr = wid >> 2, wc = wid & 3;               // 2M x 4N
    const int wbase = wid << 6;

    auto stage_tile = [&](const bf16* src, int r0, int k0, char* ldsbase) {
#pragma unroll
        for (int it = 0; it < 4; ++it) {
            const int p = it * 512 + wbase + lane;       // physical 16B-chunk index
            const int r = p >> 3, pc = p & 7;
            const int lc = pc ^ (r & 7);                 // logical chunk this slot holds
            load_lds16(src + (size_t)(r0 + r) * K + k0 + lc * 8,
                       ldsbase + (size_t)(it * 512 + wbase) * 16);
        }
    };
    auto stageA = [&](int t) { stage_tile(A, row0, t << 6, (char*)lds[t & 1][0]); };
    auto stageB = [&](int t) { stage_tile(BT, col0, t << 6, (char*)lds[t & 1][1]); };

    f32x4 acc[8][4] = {};

    // prologue: T0 only
    stageA(0); stageB(0);
    wait_vmcnt<0>();
    hard_barrier();

    const int KT = K >> 6;
    for (int t = 0; t < KT; ++t) {
        const bool more = (t + 1 < KT);
        const char* lAc = (const char*)lds[t & 1][0];
        const char* lBc = (const char*)lds[t & 1][1];

        short8 a0[2][4], a1[2][4], b0[2][2], b1[2][2];   // [kk][frag]
        auto ldA = [&](short8 af[2][4], int mh) {
#pragma unroll
            for (int kk = 0; kk < 2; ++kk)
#pragma unroll
                for (int m = 0; m < 4; ++m) {
                    const int ra = wr * 128 + mh * 64 + m * 16 + llo;
                    af[kk][m] = *(const short8*)(lAc + ra * 128 + (((kk * 4 + lhi) ^ (ra & 7)) << 4));
                }
        };
        auto ldB = [&](short8 bf_[2][2], int nh) {
#pragma unroll
            for (int kk = 0; kk < 2; ++kk)
#pragma unroll
                for (int n = 0; n < 2; ++n) {
                    const int rb = wc * 64 + nh * 32 + n * 16 + llo;
                    bf_[kk][n] = *(const short8*)(lBc + rb * 128 + (((kk * 4 + lhi) ^ (rb & 7)) << 4));
                }
        };
        auto mfma_q = [&](int mh, int nh, short8 af[2][4], short8 bf_[2][2]) {
#pragma unroll
            for (int kk = 0; kk < 2; ++kk)
#pragma unroll
                for (int m = 0; m < 4; ++m)
#pragma unroll
                    for (int n = 0; n < 2; ++n)
                        acc[mh * 4 + m][nh * 2 + n] =
                            __builtin_amdgcn_mfma_f32_16x16x32_bf16(af[kk][m], bf_[kk][n], acc[mh * 4 + m][nh * 2 + n], 0, 0, 0);
        };

        // P1: quadrant (0,0); stage A(t+1)
        ldA(a0, 0); ldB(b0, 0);
        if (more) stageA(t + 1);
        phase_pre(); mfma_q(0, 0, a0, b0); phase_post();
        // P2: quadrant (0,1); stage B(t+1)
        ldB(b1, 1);
        if (more) stageB(t + 1);
        phase_pre(); mfma_q(0, 1, a0, b1); phase_post();
        // P3: quadrant (1,1)
        ldA(a1, 1);
        phase_pre(); mfma_q(1, 1, a1, b1); phase_post();
        // P4: quadrant (1,0); merged boundary (drains staging, single barrier)
        phase_pre(); mfma_q(1, 0, a1, b0);
        if (more) phase_post_drain();
        else      phase_post();
    }

#pragma unroll
    for (int m = 0; m < 8; ++m) {
        const int rbase = row0 + wr * 128 + m * 16 + lhi * 4;
#pragma unroll
        for (int n = 0; n < 4; ++n) {
            const int c = col0 + wc * 64 + n * 16 + llo;
#pragma unroll
            for (int r = 0; r < 4; ++r) {
                const size_t idx = (size_t)(rbase + r) * N + c;
                const float v = acc[m][n][r];
                if constexpr (EPI == 0) outp[idx] = f2bf(siluf(v));
                else                    outp[idx] = f2bf(v * bf2f(mulsrc[idx]));
            }
        }
    }
}

// ---------------- fused FFN: h1 = silu(A@W1) * (A@W3), 4-phase fine interleave ----------------
// Column-major block order: B1+B3 panels (2 MB) L2-resident.
__global__ __launch_bounds__(512, 2) void gemm_w13_8(
    const bf16* __restrict__ A, const bf16* __restrict__ B1T, const bf16* __restrict__ B3T,
    bf16* __restrict__ outp, int M, int N, int K)
{
    __shared__ __align__(16) bf16 lA[2][256 * 64];
    __shared__ __align__(16) bf16 lB1[2][128 * 64];
    __shared__ __align__(16) bf16 lB3[2][128 * 64];
    const int tid = threadIdx.x;
    const int wid = tid >> 6, lane = tid & 63;
    const int lhi = lane >> 4, llo = lane & 15;
    const int nby = M >> 8;
    const int bid = xcd_swz((int)blockIdx.x, (int)gridDim.x);
    const int by = bid % nby, bx = bid / nby;            // column-major
    const int row0 = by << 8, col0 = bx << 7;
    const int wr = wid >> 2, wc = wid & 3;               // 2M x 4N
    const int wbase = wid << 6;

    auto stage_rows = [&](const bf16* src, int r0, int k0, char* ldsbase, int nit) {
        for (int it = 0; it < nit; ++it) {
            const int p = it * 512 + wbase + lane;
            const int r = p >> 3, pc = p & 7;
            const int lc = pc ^ (r & 7);
            load_lds16(src + (size_t)(r0 + r) * K + k0 + lc * 8,
                       ldsbase + (size_t)(it * 512 + wbase) * 16);
        }
    };
    auto stageA = [&](int t) { stage_rows(A, row0, t << 6, (char*)lA[t & 1], 4); };
    auto stageB = [&](int t) {
        stage_rows(B1T, col0, t << 6, (char*)lB1[t & 1], 2);
        stage_rows(B3T, col0, t << 6, (char*)lB3[t & 1], 2);
    };

    f32x4 acc1[8][2] = {}, acc3[8][2] = {};

    stageA(0); stageB(0);
    wait_vmcnt<0>();
    hard_barrier();

    const int KT = K >> 6;
    for (int t = 0; t < KT; ++t) {
        const bool more = (t + 1 < KT);
        const char* lAc = (const char*)lA[t & 1];
        const char* lB1c = (const char*)lB1[t & 1];
        const char* lB3c = (const char*)lB3[t & 1];

        short8 b1f[2], b3f[2];                           // current-kk B frags
        auto ldA4 = [&](short8 af[4], int mh, int kk) {
#pragma unroll
            for (int m = 0; m < 4; ++m) {
                const int ra = wr * 128 + mh * 64 + m * 16 + llo;
                af[m] = *(const short8*)(lAc + ra * 128 + (((kk * 4 + lhi) ^ (ra & 7)) << 4));
            }
        };
        auto ldBk = [&](int kk) {
#pragma unroll
            for (int n = 0; n < 2; ++n) {
                const int rb = wc * 32 + n * 16 + llo;
                const int so = (((kk * 4 + lhi) ^ (rb & 7)) << 4);
                b1f[n] = *(const short8*)(lB1c + rb * 128 + so);
                b3f[n] = *(const short8*)(lB3c + rb * 128 + so);
            }
        };
        auto mfma_p = [&](short8 af[4], int mh) {
#pragma unroll
            for (int m = 0; m < 4; ++m)
#pragma unroll
                for (int n = 0; n < 2; ++n) {
                    acc1[mh * 4 + m][n] = __builtin_amdgcn_mfma_f32_16x16x32_bf16(af[m], b1f[n], acc1[mh * 4 + m][n], 0, 0, 0);
                    acc3[mh * 4 + m][n] = __builtin_amdgcn_mfma_f32_16x16x32_bf16(af[m], b3f[n], acc3[mh * 4 + m][n], 0, 0, 0);
                }
        };

        short8 af[4];
        // P1: (mh0, kk0); stage A(t+1)
        ldA4(af, 0, 0); ldBk(0);
        if (more) stageA(t + 1);
        phase_pre(); mfma_p(af, 0); phase_post();
        // P2: (mh1, kk0); stage B(t+1)
        ldA4(af, 1, 0);
        if (more) stageB(t + 1);
        phase_pre(); mfma_p(af, 1); phase_post();
        // P3: (mh0, kk1)
        ldA4(af, 0, 1); ldBk(1);
        phase_pre(); mfma_p(af, 0); phase_post();
        // P4: (mh1, kk1); merged boundary
        ldA4(af, 1, 1);
        phase_pre(); mfma_p(af, 1);
        if (more) phase_post_drain();
        else      phase_post();
    }

    // epilogue: silu(c1) * c3, wave-local
#pragma unroll
    for (int m = 0; m < 8; ++m) {
        const int rbase = row0 + wr * 128 + m * 16 + lhi * 4;
#pragma unroll
        for (int n = 0; n < 2; ++n) {
            const int c = col0 + wc * 32 + n * 16 + llo;
#pragma unroll
            for (int r = 0; r < 4; ++r) {
                const size_t idx = (size_t)(rbase + r) * N + c;
                outp[idx] = f2bf(siluf(acc1[m][n][r]) * acc3[m][n][r]);
            }
        }
    }
}

// ---------------- 128x64 bf16 GEMM, 2-phase fine interleave, distance-1 dbuf (N=1024) ----------------
// ROW-major block order: A-slab L2-resident (right for K-large/N-small: w2).
__global__ __launch_bounds__(256) void gemm_btc(
    const bf16* __restrict__ A, const bf16* __restrict__ BT,
    float* __restrict__ outp, const float* __restrict__ resid,
    int M, int N, int K)
{
    __shared__ __align__(16) bf16 lA[2][128 * 64];
    __shared__ __align__(16) bf16 lB[2][64 * 64];
    const int tid = threadIdx.x;
    const int wid = tid >> 6, lane = tid & 63;
    const int lhi = lane >> 4, llo = lane & 15;
    const int ntx = N >> 6;
    const int bid = xcd_swz((int)blockIdx.x, (int)gridDim.x);
    const int bx = bid % ntx, by = bid / ntx;            // row-major
    const int row0 = by << 7, col0 = bx << 6;
    const int wr = wid >> 1, wc = wid & 1;               // 2M x 2N
    const int wbase = wid << 6;

    auto stage_tile = [&](const bf16* src, int r0, int k0, char* ldsbase, int nit) {
        for (int it = 0; it < nit; ++it) {
            const int p = it * 256 + wbase + lane;
            const int r = p >> 3, pc = p & 7;
            const int lc = pc ^ (r & 7);
            load_lds16(src + (size_t)(r0 + r) * K + k0 + lc * 8,
                       ldsbase + (size_t)(it * 256 + wbase) * 16);
        }
    };
    auto stageT = [&](int t) {
        stage_tile(A, row0, t << 6, (char*)lA[t & 1], 4);
        stage_tile(BT, col0, t << 6, (char*)lB[t & 1], 2);
    };

    f32x4 acc[4][2] = {};

    stageT(0);
    wait_vmcnt<0>();
    hard_barrier();

    const int KT = K >> 6;
    for (int t = 0; t < KT; ++t) {
        const bool more = (t + 1 < KT);
        const int buf = t & 1;
        const char* lAc = (const char*)lA[buf];
        const char* lBc = (const char*)lB[buf];

        short8 af[4], bfr[2];
        auto ldA = [&](int kk) {
#pragma unroll
            for (int m = 0; m < 4; ++m) {
                const int ra = wr * 64 + m * 16 + llo;
                af[m] = *(const short8*)(lAc + ra * 128 + (((kk * 4 + lhi) ^ (ra & 7)) << 4));
            }
        };
        auto ldB = [&](int kk) {
#pragma unroll
            for (int n = 0; n < 2; ++n) {
                const int rb = wc * 32 + n * 16 + llo;
                bfr[n] = *(const short8*)(lBc + rb * 128 + (((kk * 4 + lhi) ^ (rb & 7)) << 4));
            }
        };
        auto mfma8 = [&]() {
#pragma unroll
            for (int m = 0; m < 4; ++m)
#pragma unroll
                for (int n = 0; n < 2; ++n)
                    acc[m][n] = __builtin_amdgcn_mfma_f32_16x16x32_bf16(af[m], bfr[n], acc[m][n], 0, 0, 0);
        };

        // P1: kk0; stage T_{t+1} into buf^1
        ldA(0); ldB(0);
        if (more) stageT(t + 1);
        phase_pre(); mfma8(); phase_post();
        // P2: kk1; merged boundary
        ldA(1); ldB(1);
        phase_pre(); mfma8();
        if (more) phase_post_drain();
        else      phase_post();
    }

#pragma unroll
    for (int m = 0; m < 4; ++m) {
        const int rbase = row0 + wr * 64 + m * 16 + lhi * 4;
#pragma unroll
        for (int n = 0; n < 2; ++n) {
            const int c = col0 + wc * 32 + n * 16 + llo;
#pragma unroll
            for (int r = 0; r < 4; ++r) {
                const size_t idx = (size_t)(rbase + r) * N + c;
                outp[idx] = resid[idx] + acc[m][n][r];
            }
        }
    }
}

// ---------------- V transpose: qkuv v-quarter [B][L][H*64] -> v_t [B*H][64][L] ----------------
__global__ __launch_bounds__(256) void v_trans(const bf16* __restrict__ qkuv, bf16* __restrict__ v_t)
{
    __shared__ bf16 t[64][65];
    const int bh = blockIdx.y;         // b*16+h
    const int b = bh >> 4, h = bh & 15;
    const int l0 = blockIdx.x << 6;
    const int tx = threadIdx.x, ty = threadIdx.y;
#pragma unroll
    for (int i = ty; i < 64; i += 4)
        t[i][tx] = qkuv[(size_t)(b * 2048 + l0 + i) * 4096 + 2048 + h * 64 + tx];
    __syncthreads();
#pragma unroll
    for (int i = ty; i < 64; i += 4)
        v_t[(size_t)(bh * 64 + i) * 2048 + l0 + tx] = t[tx][i];
}

// ---------------- fused silu-attention + head-LN*u (KVBLK=128, LPT grid) ----------------
// 512 threads = 8 waves, each wave owns 16 q rows of a 128-row q-tile.
// LPT dispatch: qt = 15 - (bid>>5), bh = bid&31 -> heavy blocks dispatched first.
__global__ __launch_bounds__(512) void attn_kernel(
    const bf16* __restrict__ qkuv, const bf16* __restrict__ v_t,
    const float* __restrict__ nag, const float* __restrict__ nab,
    bf16* __restrict__ au)
{
    __shared__ __align__(16) bf16 lK[2][128 * 64];
    __shared__ __align__(16) bf16 lV[2][64 * 128];
    const int tid = threadIdx.x;
    const int wid = tid >> 6, lane = tid & 63;
    const int lhi = lane >> 4, llo = lane & 15;
    const int bid = (int)blockIdx.x;
    const int qt = 15 - (bid >> 5);                       // heavy blocks dispatched first
    const int bh = bid & 31;
    const int b = bh >> 4, h = bh & 15;
    const int q0 = qt << 7;
    const bf16* Qb = qkuv + (size_t)b * 2048 * 4096 + h * 64;
    const bf16* Kb = Qb + 1024;
    const bf16* Ub = Qb + 3072;
    const bf16* Vb = v_t + (size_t)bh * 64 * 2048;
    const int wbase = wid << 6;

    auto stage = [&](int kt_s, int buf) {
        const int koff = kt_s << 7;
        char* lKc = (char*)lK[buf];
        char* lVc = (char*)lV[buf];
#pragma unroll
        for (int it = 0; it < 2; ++it) {
            const int p = it * 512 + wbase + lane;
            const int r = p >> 3, pc = p & 7;
            const int lc = pc ^ (r & 7);
            load_lds16(Kb + (size_t)(koff + r) * 4096 + lc * 8, lKc + (it * 512 + wbase) * 16);
        }
#pragma unroll
        for (int it = 0; it < 2; ++it) {
            const int p = it * 512 + wbase + lane;
            const int d = p >> 4, pc = p & 15;
            const int lc = pc ^ (d & 15);
            load_lds16(Vb + (size_t)d * 2048 + koff + lc * 8, lVc + (it * 512 + wbase) * 16);
        }
    };

    // hoist Q B-frags: q = wid*16 + llo, dk = kk*32 + lhi*8
    short8 qb[2];
#pragma unroll
    for (int kk = 0; kk < 2; ++kk)
        qb[kk] = *(const short8*)(Qb + (size_t)(q0 + wid * 16 + llo) * 4096 + kk * 32 + lhi * 8);

    f32x4 acc2[4] = {};

    stage(0, 0);  // prologue prefetch

    for (int kt = 0; kt <= qt; ++kt) {
        const int cur = kt & 1;
        drain_and_sync();                      // staged buf[cur] visible to all waves
        if (kt < qt) stage(kt + 1, cur ^ 1);   // prefetch next tile into other buffer
        const char* lKc = (const char*)lK[cur];
        const char* lVc = (const char*)lV[cur];

        const bool diag = (kt == qt);
#pragma unroll
        for (int m = 0; m < 8; ++m) {
            if (diag && m > wid) break;                    // fully above diagonal
            const int rK = m * 16 + llo;
            const int sw = rK & 7;
            short8 ak0 = *(const short8*)(lKc + rK * 128 + ((lhi ^ sw) << 4));
            short8 ak1 = *(const short8*)(lKc + rK * 128 + (((4 + lhi) ^ sw) << 4));
            f32x4 s = {};
            s = __builtin_amdgcn_mfma_f32_16x16x32_bf16(ak0, qb[0], s, 0, 0, 0);
            s = __builtin_amdgcn_mfma_f32_16x16x32_bf16(ak1, qb[1], s, 0, 0, 0);
            const bool mask = diag && (m == wid);
            bfv4 a16;
#pragma unroll
            for (int r = 0; r < 4; ++r) {
                float xx = s[r] * 0.125f;
                xx = xx * __builtin_amdgcn_rcpf(1.f + __expf(-xx));
                if (mask && (lhi * 4 + r > llo)) xx = 0.f;
                a16[r] = (short)f2bf_bits(xx);
            }
#pragma unroll
            for (int dcol = 0; dcol < 4; ++dcol) {
                const int d = dcol * 16 + llo;
                const int lcV = m * 2 + (lhi >> 1);
                bfv4 bv = *(const bfv4*)(lVc + d * 256 + ((lcV ^ llo) << 4) + (lhi & 1) * 8);
                acc2[dcol] = mfma16(a16, bv, acc2[dcol]);
            }
        }
    }

    // ---- epilogue: LN(d=64) * u ----
#pragma unroll
    for (int r = 0; r < 4; ++r) {
        float vv[4];
        float s = 0.f, ss = 0.f;
#pragma unroll
        for (int dc = 0; dc < 4; ++dc) { vv[dc] = acc2[dc][r]; s += vv[dc]; ss += vv[dc] * vv[dc]; }
#pragma unroll
        for (int o = 1; o < 16; o <<= 1) { s += __shfl_xor(s, o); ss += __shfl_xor(ss, o); }
        const float mu = s * (1.f / 64.f);
        const float rstd = rsqrtf(ss * (1.f / 64.f) - mu * mu + LN_EPS);
        const int q = wid * 16 + lhi * 4 + r;
        const size_t grow = q0 + q;
#pragma unroll
        for (int dc = 0; dc < 4; ++dc) {
            const int c = dc * 16 + llo;
            const float nv = (vv[dc] - mu) * rstd * nag[c] + nab[c];
            const float uu = bf2f(Ub[grow * 4096 + c]);
            au[(size_t)(b * 2048 + grow) * 1024 + h * 64 + c] = f2bf(nv * uu);
        }
    }
}

// ---------------- host launch ----------------
extern "C" void kernel_launch(void* const* d_in, const int* in_sizes, int n_in,
                              void* d_out, int out_size, void* d_ws, size_t ws_size,
                              hipStream_t stream)
{
    const float* x      = (const float*)d_in[0];
    // d_in[1] = attn_mask (tril causal; applied analytically)
    const float* w_qkuv = (const float*)d_in[2];
    const float* w_out  = (const float*)d_in[3];
    const float* w1     = (const float*)d_in[4];
    const float* w2     = (const float*)d_in[5];
    const float* w3     = (const float*)d_in[6];
    const float* ln1g   = (const float*)d_in[7];
    const float* ln1b   = (const float*)d_in[8];
    const float* ln2g   = (const float*)d_in[9];
    const float* ln2b   = (const float*)d_in[10];
    const float* nag    = (const float*)d_in[11];
    const float* nab    = (const float*)d_in[12];
    float* out = (float*)d_out;

    char* ws = (char*)d_ws;
    size_t off = 0;
    auto alloc = [&](size_t bytes) { void* p = ws + off; off += (bytes + 255) & ~(size_t)255; return p; };
    const size_t M = 4096;  // B*L
    bf16* wqkuvT = (bf16*)alloc(4096ull * 1024 * 2);
    bf16* woutT  = (bf16*)alloc(1024ull * 1024 * 2);
    bf16* w1T    = (bf16*)alloc(4096ull * 1024 * 2);
    bf16* w3T    = (bf16*)alloc(4096ull * 1024 * 2);
    bf16* w2T    = (bf16*)alloc(1024ull * 4096 * 2);
    bf16* xn     = (bf16*)alloc(M * 1024 * 2);
    bf16* qkuv   = (bf16*)alloc(M * 4096 * 2);
    bf16* vt     = (bf16*)alloc(32ull * 64 * 2048 * 2);
    bf16* aub    = (bf16*)alloc(M * 1024 * 2);
    float* x2    = (float*)alloc(M * 1024 * 4);
    bf16* xn2    = (bf16*)alloc(M * 1024 * 2);
    bf16* h1     = (bf16*)alloc(M * 4096 * 2);
    (void)ws_size; (void)in_sizes; (void)n_in; (void)out_size;

    dim3 tb(32, 8);
    prep_all<<<dim3(21504), tb, 0, stream>>>(w_qkuv, w1, w3, w2, w_out,
                                             wqkuvT, w1T, w3T, w2T, woutT,
                                             x, ln1g, ln1b, xn);

    gemm8<0><<<dim3((M / 256) * (4096 / 256)), 512, 0, stream>>>(xn, wqkuvT, qkuv, nullptr, M, 4096, 1024);

    v_trans<<<dim3(2048 / 64, 32), dim3(64, 4), 0, stream>>>(qkuv, vt);

    attn_kernel<<<dim3(512), 512, 0, stream>>>(qkuv, vt, nag, nab, aub);

    gemm_btc<<<dim3((M / 128) * (1024 / 64)), 256, 0, stream>>>(aub, woutT, x2, x, M, 1024, 1024);

    ln_cast<<<M, 256, 0, stream>>>(x2, ln2g, ln2b, xn2);

    gemm_w13_8<<<dim3((M / 256) * (4096 / 128)), 512, 0, stream>>>(xn2, w1T, w3T, h1, M, 4096, 1024);

    gemm_btc<<<dim3((M / 128) * (1024 / 64)), 256, 0, stream>>>(h1, w2T, out, x2, M, 1024, 4096);
}

// Round 25
// 266.567 us; speedup vs baseline: 1.0883x; 1.0023x over previous
//
#include <hip/hip_runtime.h>
#include <hip/hip_bf16.h>

typedef __hip_bfloat16 bf16;
typedef __attribute__((ext_vector_type(8))) short short8;
typedef __attribute__((ext_vector_type(4))) short bfv4;
typedef __attribute__((ext_vector_type(4))) float f32x4;
typedef __attribute__((ext_vector_type(4))) unsigned short us4;

#define LN_EPS 1e-5f

__device__ __forceinline__ float siluf(float x) { return x / (1.f + __expf(-x)); }
__device__ __forceinline__ unsigned short f2bf_bits(float f) {
    bf16 h = __float2bfloat16(f);
    return *reinterpret_cast<unsigned short*>(&h);
}
__device__ __forceinline__ bf16 f2bf(float f) { return __float2bfloat16(f); }
__device__ __forceinline__ float bf2f(bf16 h) { return __bfloat162float(h); }

// async global->LDS, 16B per lane. LDS dest must be wave-uniform base (+lane*16 implicit).
__device__ __forceinline__ void load_lds16(const void* g, void* l) {
    __builtin_amdgcn_global_load_lds((const __attribute__((address_space(1))) void*)g,
                                     (__attribute__((address_space(3))) void*)l, 16, 0, 0);
}

__device__ __forceinline__ f32x4 mfma16(bfv4 a, bfv4 b, f32x4 c) {
    return __builtin_amdgcn_mfma_f32_16x16x16bf16_1k(a, b, c, 0, 0, 0);
}

// explicit RAW drain for global_load_lds before a barrier (rule-#18 class hazard)
__device__ __forceinline__ void drain_and_sync() {
    asm volatile("s_waitcnt vmcnt(0)" ::: "memory");
    __builtin_amdgcn_sched_barrier(0);
    __syncthreads();
}

// counted vmcnt wait (literal), fenced
template <int N>
__device__ __forceinline__ void wait_vmcnt() {
    asm volatile("s_waitcnt vmcnt(%0)" :: "n"(N) : "memory");
}
__device__ __forceinline__ void hard_barrier() {
    __builtin_amdgcn_sched_barrier(0);
    __builtin_amdgcn_s_barrier();
    __builtin_amdgcn_sched_barrier(0);
}

// fine-phase sync: rendezvous, then wait own ds_reads, then high-prio MFMA
__device__ __forceinline__ void phase_pre() {
    __builtin_amdgcn_sched_barrier(0);
    __builtin_amdgcn_s_barrier();
    asm volatile("s_waitcnt lgkmcnt(0)" ::: "memory");
    __builtin_amdgcn_sched_barrier(0);
    __builtin_amdgcn_s_setprio(1);
}
__device__ __forceinline__ void phase_post() {
    __builtin_amdgcn_s_setprio(0);
    __builtin_amdgcn_sched_barrier(0);
    __builtin_amdgcn_s_barrier();
    __builtin_amdgcn_sched_barrier(0);
}
// merged phase_post + K-tile boundary: single barrier with own-wave vmcnt(0) drain.
__device__ __forceinline__ void phase_post_drain() {
    __builtin_amdgcn_s_setprio(0);
    __builtin_amdgcn_sched_barrier(0);
    asm volatile("s_waitcnt vmcnt(0)" ::: "memory");
    __builtin_amdgcn_sched_barrier(0);
    __builtin_amdgcn_s_barrier();
    __builtin_amdgcn_sched_barrier(0);
}

// XCD-chunked bijective block swizzle (requires nwg % 8 == 0)
__device__ __forceinline__ int xcd_swz(int bid, int nwg) {
    return (bid & 7) * (nwg >> 3) + (bid >> 3);
}

// ---------------- prep: five weight transposes + LN1 in ONE launch (flat grid) ----------------
// ranges: [0,12288) z0-2 = w_qkuv/w1/w3 (K=1024,N=4096); [12288,16384) w2 (K=4096,N=1024);
//         [16384,17408) w_out (K=1024,N=1024); [17408,21504) LN rows of x -> xn
__global__ __launch_bounds__(256) void prep_all(
    const float* __restrict__ s0, const float* __restrict__ s1, const float* __restrict__ s2,
    const float* __restrict__ s3, const float* __restrict__ s4,
    bf16* __restrict__ d0, bf16* __restrict__ d1, bf16* __restrict__ d2,
    bf16* __restrict__ d3, bf16* __restrict__ d4,
    const float* __restrict__ x, const float* __restrict__ g, const float* __restrict__ be,
    bf16* __restrict__ xout)
{
    __shared__ float t[32][33];
    __shared__ float red[10];
    const int bid = (int)blockIdx.x;
    const int tx = threadIdx.x, ty = threadIdx.y;

    if (bid >= 17408) {
        // ---- LayerNorm row (D=1024) -> bf16 ----
        const int row = bid - 17408;
        const int tid = ty * 32 + tx;
        const float4 v = ((const float4*)(x + (size_t)row * 1024))[tid];
        float s = v.x + v.y + v.z + v.w;
        float ss = v.x * v.x + v.y * v.y + v.z * v.z + v.w * v.w;
#pragma unroll
        for (int o = 32; o; o >>= 1) { s += __shfl_down(s, o); ss += __shfl_down(ss, o); }
        const int wid = tid >> 6, lane = tid & 63;
        if (lane == 0) { red[wid] = s; red[4 + wid] = ss; }
        __syncthreads();
        if (tid == 0) {
            float S = red[0] + red[1] + red[2] + red[3];
            float SS = red[4] + red[5] + red[6] + red[7];
            float mu = S * (1.f / 1024.f);
            red[8] = mu;
            red[9] = rsqrtf(SS * (1.f / 1024.f) - mu * mu + LN_EPS);
        }
        __syncthreads();
        const float mu = red[8], rstd = red[9];
        const float4 gg = ((const float4*)g)[tid];
        const float4 bb = ((const float4*)be)[tid];
        us4 o;
        o[0] = f2bf_bits((v.x - mu) * rstd * gg.x + bb.x);
        o[1] = f2bf_bits((v.y - mu) * rstd * gg.y + bb.y);
        o[2] = f2bf_bits((v.z - mu) * rstd * gg.z + bb.z);
        o[3] = f2bf_bits((v.w - mu) * rstd * gg.w + bb.w);
        ((us4*)(xout + (size_t)row * 1024))[tid] = o;
        return;
    }

    // ---- weight transpose+cast: fp32 [K][N] -> bf16 [N][K] ----
    const float* src; bf16* dst; int K, N, nb, kb;
    if (bid < 12288) {
        const int z = bid >> 12, idx = bid & 4095;
        src = (z == 0) ? s0 : (z == 1) ? s1 : s2;
        dst = (z == 0) ? d0 : (z == 1) ? d1 : d2;
        K = 1024; N = 4096;
        nb = (idx & 127) << 5; kb = (idx >> 7) << 5;
    } else if (bid < 16384) {
        const int idx = bid - 12288;
        src = s3; dst = d3; K = 4096; N = 1024;
        nb = (idx & 31) << 5; kb = (idx >> 5) << 5;
    } else {
        const int idx = bid - 16384;
        src = s4; dst = d4; K = 1024; N = 1024;
        nb = (idx & 31) << 5; kb = (idx >> 5) << 5;
    }
#pragma unroll
    for (int i = ty; i < 32; i += 8) t[i][tx] = src[(size_t)(kb + i) * N + nb + tx];
    __syncthreads();
#pragma unroll
    for (int i = ty; i < 32; i += 8) dst[(size_t)(nb + i) * K + kb + tx] = f2bf(t[tx][i]);
}

// ---------------- LayerNorm fp32 row (D=1024) -> bf16 (standalone, for LN2) ----------------
__global__ __launch_bounds__(256) void ln_cast(
    const float* __restrict__ x, const float* __restrict__ g, const float* __restrict__ be,
    bf16* __restrict__ out)
{
    const int row = blockIdx.x, tid = threadIdx.x;
    const float4 v = ((const float4*)(x + (size_t)row * 1024))[tid];
    float s = v.x + v.y + v.z + v.w;
    float ss = v.x * v.x + v.y * v.y + v.z * v.z + v.w * v.w;
#pragma unroll
    for (int o = 32; o; o >>= 1) { s += __shfl_down(s, o); ss += __shfl_down(ss, o); }
    __shared__ float red[10];
    const int wid = tid >> 6, lane = tid & 63;
    if (lane == 0) { red[wid] = s; red[4 + wid] = ss; }
    __syncthreads();
    if (tid == 0) {
        float S = red[0] + red[1] + red[2] + red[3];
        float SS = red[4] + red[5] + red[6] + red[7];
        float mu = S * (1.f / 1024.f);
        red[8] = mu;
        red[9] = rsqrtf(SS * (1.f / 1024.f) - mu * mu + LN_EPS);
    }
    __syncthreads();
    const float mu = red[8], rstd = red[9];
    const float4 gg = ((const float4*)g)[tid];
    const float4 bb = ((const float4*)be)[tid];
    us4 o;
    o[0] = f2bf_bits((v.x - mu) * rstd * gg.x + bb.x);
    o[1] = f2bf_bits((v.y - mu) * rstd * gg.y + bb.y);
    o[2] = f2bf_bits((v.z - mu) * rstd * gg.z + bb.z);
    o[3] = f2bf_bits((v.w - mu) * rstd * gg.w + bb.w);
    ((us4*)(out + (size_t)row * 1024))[tid] = o;
}

// ---------------- 256x256 bf16 GEMM (qkuv), 4-phase fine interleave, distance-1 dbuf ----------------
// Column-major block order. Epilogue: bf16 silu(acc) -> qkuv, PLUS fused V-transpose:
// for cols in [2048,3072), the 4 packed rows of acc[m][n] are 4 consecutive l in
// vt[(b*1024 + (c-2048))*2048 + l] -> one aligned 8B us4 store. Replaces v_trans.
__global__ __launch_bounds__(512, 2) void gemm8(
    const bf16* __restrict__ A, const bf16* __restrict__ BT,
    bf16* __restrict__ outp, bf16* __restrict__ vtp,
    int M, int N, int K)
{
    __shared__ __align__(16) bf16 lds[2][2][256 * 64];   // [buf][A=0/B=1][row*64+col]
    const int tid = threadIdx.x;
    const int wid = tid >> 6, lane = tid & 63;
    const int lhi = lane >> 4, llo = lane & 15;
    const int nby = M >> 8;
    const int bid = xcd_swz((int)blockIdx.x, (int)gridDim.x);
    const int by = bid % nby, bx = bid / nby;            // column-major
    const int row0 = by << 8, col0 = bx << 8;
    const int wr = wid >> 2, wc = wid & 3;               // 2M x 4N
    const int wbase = wid << 6;

    auto stage_tile = [&](const bf16* src, int r0, int k0, char* ldsbase) {
#pragma unroll
        for (int it = 0; it < 4; ++it) {
            const int p = it * 512 + wbase + lane;       // physical 16B-chunk index
            const int r = p >> 3, pc = p & 7;
            const int lc = pc ^ (r & 7);                 // logical chunk this slot holds
            load_lds16(src + (size_t)(r0 + r) * K + k0 + lc * 8,
                       ldsbase + (size_t)(it * 512 + wbase) * 16);
        }
    };
    auto stageA = [&](int t) { stage_tile(A, row0, t << 6, (char*)lds[t & 1][0]); };
    auto stageB = [&](int t) { stage_tile(BT, col0, t << 6, (char*)lds[t & 1][1]); };

    f32x4 acc[8][4] = {};

    // prologue: T0 only
    stageA(0); stageB(0);
    wait_vmcnt<0>();
    hard_barrier();

    const int KT = K >> 6;
    for (int t = 0; t < KT; ++t) {
        const bool more = (t + 1 < KT);
        const char* lAc = (const char*)lds[t & 1][0];
        const char* lBc = (const char*)lds[t & 1][1];

        short8 a0[2][4], a1[2][4], b0[2][2], b1[2][2];   // [kk][frag]
        auto ldA = [&](short8 af[2][4], int mh) {
#pragma unroll
            for (int kk = 0; kk < 2; ++kk)
#pragma unroll
                for (int m = 0; m < 4; ++m) {
                    const int ra = wr * 128 + mh * 64 + m * 16 + llo;
                    af[kk][m] = *(const short8*)(lAc + ra * 128 + (((kk * 4 + lhi) ^ (ra & 7)) << 4));
                }
        };
        auto ldB = [&](short8 bf_[2][2], int nh) {
#pragma unroll
            for (int kk = 0; kk < 2; ++kk)
#pragma unroll
                for (int n = 0; n < 2; ++n) {
                    const int rb = wc * 64 + nh * 32 + n * 16 + llo;
                    bf_[kk][n] = *(const short8*)(lBc + rb * 128 + (((kk * 4 + lhi) ^ (rb & 7)) << 4));
                }
        };
        auto mfma_q = [&](int mh, int nh, short8 af[2][4], short8 bf_[2][2]) {
#pragma unroll
            for (int kk = 0; kk < 2; ++kk)
#pragma unroll
                for (int m = 0; m < 4; ++m)
#pragma unroll
                    for (int n = 0; n < 2; ++n)
                        acc[mh * 4 + m][nh * 2 + n] =
                            __builtin_amdgcn_mfma_f32_16x16x32_bf16(af[kk][m], bf_[kk][n], acc[mh * 4 + m][nh * 2 + n], 0, 0, 0);
        };

        // P1: quadrant (0,0); stage A(t+1)
        ldA(a0, 0); ldB(b0, 0);
        if (more) stageA(t + 1);
        phase_pre(); mfma_q(0, 0, a0, b0); phase_post();
        // P2: quadrant (0,1); stage B(t+1)
        ldB(b1, 1);
        if (more) stageB(t + 1);
        phase_pre(); mfma_q(0, 1, a0, b1); phase_post();
        // P3: quadrant (1,1)
        ldA(a1, 1);
        phase_pre(); mfma_q(1, 1, a1, b1); phase_post();
        // P4: quadrant (1,0); merged boundary (drains staging, single barrier)
        phase_pre(); mfma_q(1, 0, a1, b0);
        if (more) phase_post_drain();
        else      phase_post();
    }

#pragma unroll
    for (int m = 0; m < 8; ++m) {
        const int rbase = row0 + wr * 128 + m * 16 + lhi * 4;
#pragma unroll
        for (int n = 0; n < 4; ++n) {
            const int c = col0 + wc * 64 + n * 16 + llo;
            us4 pack;
#pragma unroll
            for (int r = 0; r < 4; ++r) {
                const size_t idx = (size_t)(rbase + r) * N + c;
                const unsigned short bits = f2bf_bits(siluf(acc[m][n][r]));
                pack[r] = bits;
                ((unsigned short*)outp)[idx] = bits;
            }
            // fused V-transpose: rows rbase..rbase+3 are 4 consecutive l (rbase 4-aligned,
            // b-boundary 2048 is 4-aligned -> same b for all 4)
            if (c >= 2048 && c < 3072) {
                const int b = rbase >> 11;           // grow / 2048
                const int l0v = rbase & 2047;
                const int hd = c - 2048;             // h*64 + d
                *(us4*)((unsigned short*)vtp + ((size_t)(b * 1024 + hd) * 2048 + l0v)) = pack;
            }
        }
    }
}

// ---------------- fused FFN: h1 = silu(A@W1) * (A@W3), 4-phase fine interleave ----------------
// Column-major block order: B1+B3 panels (2 MB) L2-resident.
__global__ __launch_bounds__(512, 2) void gemm_w13_8(
    const bf16* __restrict__ A, const bf16* __restrict__ B1T, const bf16* __restrict__ B3T,
    bf16* __restrict__ outp, int M, int N, int K)
{
    __shared__ __align__(16) bf16 lA[2][256 * 64];
    __shared__ __align__(16) bf16 lB1[2][128 * 64];
    __shared__ __align__(16) bf16 lB3[2][128 * 64];
    const int tid = threadIdx.x;
    const int wid = tid >> 6, lane = tid & 63;
    const int lhi = lane >> 4, llo = lane & 15;
    const int nby = M >> 8;
    const int bid = xcd_swz((int)blockIdx.x, (int)gridDim.x);
    const int by = bid % nby, bx = bid / nby;            // column-major
    const int row0 = by << 8, col0 = bx << 7;
    const int wr = wid >> 2, wc = wid & 3;               // 2M x 4N
    const int wbase = wid << 6;

    auto stage_rows = [&](const bf16* src, int r0, int k0, char* ldsbase, int nit) {
        for (int it = 0; it < nit; ++it) {
            const int p = it * 512 + wbase + lane;
            const int r = p >> 3, pc = p & 7;
            const int lc = pc ^ (r & 7);
            load_lds16(src + (size_t)(r0 + r) * K + k0 + lc * 8,
                       ldsbase + (size_t)(it * 512 + wbase) * 16);
        }
    };
    auto stageA = [&](int t) { stage_rows(A, row0, t << 6, (char*)lA[t & 1], 4); };
    auto stageB = [&](int t) {
        stage_rows(B1T, col0, t << 6, (char*)lB1[t & 1], 2);
        stage_rows(B3T, col0, t << 6, (char*)lB3[t & 1], 2);
    };

    f32x4 acc1[8][2] = {}, acc3[8][2] = {};

    stageA(0); stageB(0);
    wait_vmcnt<0>();
    hard_barrier();

    const int KT = K >> 6;
    for (int t = 0; t < KT; ++t) {
        const bool more = (t + 1 < KT);
        const char* lAc = (const char*)lA[t & 1];
        const char* lB1c = (const char*)lB1[t & 1];
        const char* lB3c = (const char*)lB3[t & 1];

        short8 b1f[2], b3f[2];                           // current-kk B frags
        auto ldA4 = [&](short8 af[4], int mh, int kk) {
#pragma unroll
            for (int m = 0; m < 4; ++m) {
                const int ra = wr * 128 + mh * 64 + m * 16 + llo;
                af[m] = *(const short8*)(lAc + ra * 128 + (((kk * 4 + lhi) ^ (ra & 7)) << 4));
            }
        };
        auto ldBk = [&](int kk) {
#pragma unroll
            for (int n = 0; n < 2; ++n) {
                const int rb = wc * 32 + n * 16 + llo;
                const int so = (((kk * 4 + lhi) ^ (rb & 7)) << 4);
                b1f[n] = *(const short8*)(lB1c + rb * 128 + so);
                b3f[n] = *(const short8*)(lB3c + rb * 128 + so);
            }
        };
        auto mfma_p = [&](short8 af[4], int mh) {
#pragma unroll
            for (int m = 0; m < 4; ++m)
#pragma unroll
                for (int n = 0; n < 2; ++n) {
                    acc1[mh * 4 + m][n] = __builtin_amdgcn_mfma_f32_16x16x32_bf16(af[m], b1f[n], acc1[mh * 4 + m][n], 0, 0, 0);
                    acc3[mh * 4 + m][n] = __builtin_amdgcn_mfma_f32_16x16x32_bf16(af[m], b3f[n], acc3[mh * 4 + m][n], 0, 0, 0);
                }
        };

        short8 af[4];
        // P1: (mh0, kk0); stage A(t+1)
        ldA4(af, 0, 0); ldBk(0);
        if (more) stageA(t + 1);
        phase_pre(); mfma_p(af, 0); phase_post();
        // P2: (mh1, kk0); stage B(t+1)
        ldA4(af, 1, 0);
        if (more) stageB(t + 1);
        phase_pre(); mfma_p(af, 1); phase_post();
        // P3: (mh0, kk1)
        ldA4(af, 0, 1); ldBk(1);
        phase_pre(); mfma_p(af, 0); phase_post();
        // P4: (mh1, kk1); merged boundary
        ldA4(af, 1, 1);
        phase_pre(); mfma_p(af, 1);
        if (more) phase_post_drain();
        else      phase_post();
    }

    // epilogue: silu(c1) * c3, wave-local
#pragma unroll
    for (int m = 0; m < 8; ++m) {
        const int rbase = row0 + wr * 128 + m * 16 + lhi * 4;
#pragma unroll
        for (int n = 0; n < 2; ++n) {
            const int c = col0 + wc * 32 + n * 16 + llo;
#pragma unroll
            for (int r = 0; r < 4; ++r) {
                const size_t idx = (size_t)(rbase + r) * N + c;
                outp[idx] = f2bf(siluf(acc1[m][n][r]) * acc3[m][n][r]);
            }
        }
    }
}

// ---------------- 128x64 bf16 GEMM, 2-phase fine interleave, distance-1 dbuf (N=1024) ----------------
// ROW-major block order: A-slab L2-resident (right for K-large/N-small: w2).
__global__ __launch_bounds__(256) void gemm_btc(
    const bf16* __restrict__ A, const bf16* __restrict__ BT,
    float* __restrict__ outp, const float* __restrict__ resid,
    int M, int N, int K)
{
    __shared__ __align__(16) bf16 lA[2][128 * 64];
    __shared__ __align__(16) bf16 lB[2][64 * 64];
    const int tid = threadIdx.x;
    const int wid = tid >> 6, lane = tid & 63;
    const int lhi = lane >> 4, llo = lane & 15;
    const int ntx = N >> 6;
    const int bid = xcd_swz((int)blockIdx.x, (int)gridDim.x);
    const int bx = bid % ntx, by = bid / ntx;            // row-major
    const int row0 = by << 7, col0 = bx << 6;
    const int wr = wid >> 1, wc = wid & 1;               // 2M x 2N
    const int wbase = wid << 6;

    auto stage_tile = [&](const bf16* src, int r0, int k0, char* ldsbase, int nit) {
        for (int it = 0; it < nit; ++it) {
            const int p = it * 256 + wbase + lane;
            const int r = p >> 3, pc = p & 7;
            const int lc = pc ^ (r & 7);
            load_lds16(src + (size_t)(r0 + r) * K + k0 + lc * 8,
                       ldsbase + (size_t)(it * 256 + wbase) * 16);
        }
    };
    auto stageT = [&](int t) {
        stage_tile(A, row0, t << 6, (char*)lA[t & 1], 4);
        stage_tile(BT, col0, t << 6, (char*)lB[t & 1], 2);
    };

    f32x4 acc[4][2] = {};

    stageT(0);
    wait_vmcnt<0>();
    hard_barrier();

    const int KT = K >> 6;
    for (int t = 0; t < KT; ++t) {
        const bool more = (t + 1 < KT);
        const int buf = t & 1;
        const char* lAc = (const char*)lA[buf];
        const char* lBc = (const char*)lB[buf];

        short8 af[4], bfr[2];
        auto ldA = [&](int kk) {
#pragma unroll
            for (int m = 0; m < 4; ++m) {
                const int ra = wr * 64 + m * 16 + llo;
                af[m] = *(const short8*)(lAc + ra * 128 + (((kk * 4 + lhi) ^ (ra & 7)) << 4));
            }
        };
        auto ldB = [&](int kk) {
#pragma unroll
            for (int n = 0; n < 2; ++n) {
                const int rb = wc * 32 + n * 16 + llo;
                bfr[n] = *(const short8*)(lBc + rb * 128 + (((kk * 4 + lhi) ^ (rb & 7)) << 4));
            }
        };
        auto mfma8 = [&]() {
#pragma unroll
            for (int m = 0; m < 4; ++m)
#pragma unroll
                for (int n = 0; n < 2; ++n)
                    acc[m][n] = __builtin_amdgcn_mfma_f32_16x16x32_bf16(af[m], bfr[n], acc[m][n], 0, 0, 0);
        };

        // P1: kk0; stage T_{t+1} into buf^1
        ldA(0); ldB(0);
        if (more) stageT(t + 1);
        phase_pre(); mfma8(); phase_post();
        // P2: kk1; merged boundary
        ldA(1); ldB(1);
        phase_pre(); mfma8();
        if (more) phase_post_drain();
        else      phase_post();
    }

#pragma unroll
    for (int m = 0; m < 4; ++m) {
        const int rbase = row0 + wr * 64 + m * 16 + lhi * 4;
#pragma unroll
        for (int n = 0; n < 2; ++n) {
            const int c = col0 + wc * 32 + n * 16 + llo;
#pragma unroll
            for (int r = 0; r < 4; ++r) {
                const size_t idx = (size_t)(rbase + r) * N + c;
                outp[idx] = resid[idx] + acc[m][n][r];
            }
        }
    }
}

// ---------------- fused silu-attention + head-LN*u (KVBLK=128, LPT grid) ----------------
// 512 threads = 8 waves, each wave owns 16 q rows of a 128-row q-tile.
// LPT dispatch: qt = 15 - (bid>>5), bh = bid&31 -> heavy blocks dispatched first.
__global__ __launch_bounds__(512) void attn_kernel(
    const bf16* __restrict__ qkuv, const bf16* __restrict__ v_t,
    const float* __restrict__ nag, const float* __restrict__ nab,
    bf16* __restrict__ au)
{
    __shared__ __align__(16) bf16 lK[2][128 * 64];
    __shared__ __align__(16) bf16 lV[2][64 * 128];
    const int tid = threadIdx.x;
    const int wid = tid >> 6, lane = tid & 63;
    const int lhi = lane >> 4, llo = lane & 15;
    const int bid = (int)blockIdx.x;
    const int qt = 15 - (bid >> 5);                       // heavy blocks dispatched first
    const int bh = bid & 31;
    const int b = bh >> 4, h = bh & 15;
    const int q0 = qt << 7;
    const bf16* Qb = qkuv + (size_t)b * 2048 * 4096 + h * 64;
    const bf16* Kb = Qb + 1024;
    const bf16* Ub = Qb + 3072;
    const bf16* Vb = v_t + (size_t)bh * 64 * 2048;
    const int wbase = wid << 6;

    auto stage = [&](int kt_s, int buf) {
        const int koff = kt_s << 7;
        char* lKc = (char*)lK[buf];
        char* lVc = (char*)lV[buf];
#pragma unroll
        for (int it = 0; it < 2; ++it) {
            const int p = it * 512 + wbase + lane;
            const int r = p >> 3, pc = p & 7;
            const int lc = pc ^ (r & 7);
            load_lds16(Kb + (size_t)(koff + r) * 4096 + lc * 8, lKc + (it * 512 + wbase) * 16);
        }
#pragma unroll
        for (int it = 0; it < 2; ++it) {
            const int p = it * 512 + wbase + lane;
            const int d = p >> 4, pc = p & 15;
            const int lc = pc ^ (d & 15);
            load_lds16(Vb + (size_t)d * 2048 + koff + lc * 8, lVc + (it * 512 + wbase) * 16);
        }
    };

    // hoist Q B-frags: q = wid*16 + llo, dk = kk*32 + lhi*8
    short8 qb[2];
#pragma unroll
    for (int kk = 0; kk < 2; ++kk)
        qb[kk] = *(const short8*)(Qb + (size_t)(q0 + wid * 16 + llo) * 4096 + kk * 32 + lhi * 8);

    f32x4 acc2[4] = {};

    stage(0, 0);  // prologue prefetch

    for (int kt = 0; kt <= qt; ++kt) {
        const int cur = kt & 1;
        drain_and_sync();                      // staged buf[cur] visible to all waves
        if (kt < qt) stage(kt + 1, cur ^ 1);   // prefetch next tile into other buffer
        const char* lKc = (const char*)lK[cur];
        const char* lVc = (const char*)lV[cur];

        const bool diag = (kt == qt);
#pragma unroll
        for (int m = 0; m < 8; ++m) {
            if (diag && m > wid) break;                    // fully above diagonal
            const int rK = m * 16 + llo;
            const int sw = rK & 7;
            short8 ak0 = *(const short8*)(lKc + rK * 128 + ((lhi ^ sw) << 4));
            short8 ak1 = *(const short8*)(lKc + rK * 128 + (((4 + lhi) ^ sw) << 4));
            f32x4 s = {};
            s = __builtin_amdgcn_mfma_f32_16x16x32_bf16(ak0, qb[0], s, 0, 0, 0);
            s = __builtin_amdgcn_mfma_f32_16x16x32_bf16(ak1, qb[1], s, 0, 0, 0);
            const bool mask = diag && (m == wid);
            bfv4 a16;
#pragma unroll
            for (int r = 0; r < 4; ++r) {
                float xx = s[r] * 0.125f;
                xx = xx * __builtin_amdgcn_rcpf(1.f + __expf(-xx));
                if (mask && (lhi * 4 + r > llo)) xx = 0.f;
                a16[r] = (short)f2bf_bits(xx);
            }
#pragma unroll
            for (int dcol = 0; dcol < 4; ++dcol) {
                const int d = dcol * 16 + llo;
                const int lcV = m * 2 + (lhi >> 1);
                bfv4 bv = *(const bfv4*)(lVc + d * 256 + ((lcV ^ llo) << 4) + (lhi & 1) * 8);
                acc2[dcol] = mfma16(a16, bv, acc2[dcol]);
            }
        }
    }

    // ---- epilogue: LN(d=64) * u ----
#pragma unroll
    for (int r = 0; r < 4; ++r) {
        float vv[4];
        float s = 0.f, ss = 0.f;
#pragma unroll
        for (int dc = 0; dc < 4; ++dc) { vv[dc] = acc2[dc][r]; s += vv[dc]; ss += vv[dc] * vv[dc]; }
#pragma unroll
        for (int o = 1; o < 16; o <<= 1) { s += __shfl_xor(s, o); ss += __shfl_xor(ss, o); }
        const float mu = s * (1.f / 64.f);
        const float rstd = rsqrtf(ss * (1.f / 64.f) - mu * mu + LN_EPS);
        const int q = wid * 16 + lhi * 4 + r;
        const size_t grow = q0 + q;
#pragma unroll
        for (int dc = 0; dc < 4; ++dc) {
            const int c = dc * 16 + llo;
            const float nv = (vv[dc] - mu) * rstd * nag[c] + nab[c];
            const float uu = bf2f(Ub[grow * 4096 + c]);
            au[(size_t)(b * 2048 + grow) * 1024 + h * 64 + c] = f2bf(nv * uu);
        }
    }
}

// ---------------- host launch ----------------
extern "C" void kernel_launch(void* const* d_in, const int* in_sizes, int n_in,
                              void* d_out, int out_size, void* d_ws, size_t ws_size,
                              hipStream_t stream)
{
    const float* x      = (const float*)d_in[0];
    // d_in[1] = attn_mask (tril causal; applied analytically)
    const float* w_qkuv = (const float*)d_in[2];
    const float* w_out  = (const float*)d_in[3];
    const float* w1     = (const float*)d_in[4];
    const float* w2     = (const float*)d_in[5];
    const float* w3     = (const float*)d_in[6];
    const float* ln1g   = (const float*)d_in[7];
    const float* ln1b   = (const float*)d_in[8];
    const float* ln2g   = (const float*)d_in[9];
    const float* ln2b   = (const float*)d_in[10];
    const float* nag    = (const float*)d_in[11];
    const float* nab    = (const float*)d_in[12];
    float* out = (float*)d_out;

    char* ws = (char*)d_ws;
    size_t off = 0;
    auto alloc = [&](size_t bytes) { void* p = ws + off; off += (bytes + 255) & ~(size_t)255; return p; };
    const size_t M = 4096;  // B*L
    bf16* wqkuvT = (bf16*)alloc(4096ull * 1024 * 2);
    bf16* woutT  = (bf16*)alloc(1024ull * 1024 * 2);
    bf16* w1T    = (bf16*)alloc(4096ull * 1024 * 2);
    bf16* w3T    = (bf16*)alloc(4096ull * 1024 * 2);
    bf16* w2T    = (bf16*)alloc(1024ull * 4096 * 2);
    bf16* xn     = (bf16*)alloc(M * 1024 * 2);
    bf16* qkuv   = (bf16*)alloc(M * 4096 * 2);
    bf16* vt     = (bf16*)alloc(32ull * 64 * 2048 * 2);
    bf16* aub    = (bf16*)alloc(M * 1024 * 2);
    float* x2    = (float*)alloc(M * 1024 * 4);
    bf16* xn2    = (bf16*)alloc(M * 1024 * 2);
    bf16* h1     = (bf16*)alloc(M * 4096 * 2);
    (void)ws_size; (void)in_sizes; (void)n_in; (void)out_size;

    dim3 tb(32, 8);
    prep_all<<<dim3(21504), tb, 0, stream>>>(w_qkuv, w1, w3, w2, w_out,
                                             wqkuvT, w1T, w3T, w2T, woutT,
                                             x, ln1g, ln1b, xn);

    gemm8<<<dim3((M / 256) * (4096 / 256)), 512, 0, stream>>>(xn, wqkuvT, qkuv, vt, M, 4096, 1024);

    attn_kernel<<<dim3(512), 512, 0, stream>>>(qkuv, vt, nag, nab, aub);

    gemm_btc<<<dim3((M / 128) * (1024 / 64)), 256, 0, stream>>>(aub, woutT, x2, x, M, 1024, 1024);

    ln_cast<<<M, 256, 0, stream>>>(x2, ln2g, ln2b, xn2);

    gemm_w13_8<<<dim3((M / 256) * (4096 / 128)), 512, 0, stream>>>(xn2, w1T, w3T, h1, M, 4096, 1024);

    gemm_btc<<<dim3((M / 128) * (1024 / 64)), 256, 0, stream>>>(h1, w2T, out, x2, M, 1024, 4096);
}